// Round 1
// baseline (894.902 us; speedup 1.0000x reference)
//
#include <hip/hip_runtime.h>

#define NN    2048
#define DIN   768
#define DOUT  1024
#define NH    8
#define HD    128
#define SCALEF 0.08838834764831845f
#define NEGF  (-1.0e9f)
#define EPSF  1e-5f

typedef __attribute__((ext_vector_type(4))) float f32x4;
typedef __attribute__((ext_vector_type(8))) short bf16x8;

// workspace layout (float-slot offsets)
#define OFF_O    0                         // 2,097,152 f32
#define OFF_YACC 2097152                   // 1,572,864 f32  (zero region = [0, 3670016))
#define OFF_Q    3670016                   // 2,097,152 bf16 [8][2048][128]
#define OFF_K    4718592
#define OFF_VB   5767168                   // 2,097,152 bf16 [2048][1024]
#define OFF_VT   6815744                   // 2,097,152 bf16 [8][128][2048]
#define OFF_XB   7864320                   // 1,572,864 bf16 [2048][768]
#define OFF_WT   8650752                   // 2,359,296 bf16 [3][1024][768]
#define OFF_GQ   9830400
#define OFF_GK   9846784
#define OFF_MX   9863168
#define OFF_INV  9879552

__device__ __forceinline__ short f2bf(float f) {
  union { float f; unsigned u; } v; v.f = f;
  unsigned r = v.u + 0x7FFF + ((v.u >> 16) & 1);
  return (short)(r >> 16);
}
__device__ __forceinline__ float bf2f(short s) {
  union { unsigned u; float f; } v; v.u = ((unsigned)(unsigned short)s) << 16;
  return v.f;
}

// ---------------- zero O + YACC ----------------
__global__ __launch_bounds__(256) void k_zero(float4* __restrict__ p) {
  p[(size_t)blockIdx.x * 256 + threadIdx.x] = float4{0.f, 0.f, 0.f, 0.f};
}

// ---------------- cast x -> bf16 ----------------
__global__ __launch_bounds__(256) void k_cast_x(const float* __restrict__ x,
                                                short* __restrict__ xb) {
  int idx = blockIdx.x * 256 + threadIdx.x;  // 393216 float4s
  float4 v = ((const float4*)x)[idx];
  union { short s[4]; float2 f; } u;
  u.s[0] = f2bf(v.x); u.s[1] = f2bf(v.y); u.s[2] = f2bf(v.z); u.s[3] = f2bf(v.w);
  ((float2*)xb)[idx] = u.f;
}

// ---------------- transpose+cast W[768][1024] -> Wt[z][1024][768] bf16 ----------------
__global__ __launch_bounds__(256) void k_w_cast_t(const float* __restrict__ wq,
                                                  const float* __restrict__ wk,
                                                  const float* __restrict__ wv,
                                                  short* __restrict__ Wt) {
  const int c0 = blockIdx.x * 64, k0 = blockIdx.y * 64, z = blockIdx.z;
  const float* Wm = (z == 0) ? wq : (z == 1) ? wk : wv;
  __shared__ float t[64][65];
  const int tid = threadIdx.x;
#pragma unroll
  for (int l = 0; l < 4; ++l) {
    int f = tid + l * 256;
    int r = f >> 4, c4 = (f & 15) * 4;
    *(float4*)&t[r][c4] = *(const float4*)(Wm + (size_t)(k0 + r) * DOUT + c0 + c4);
  }
  __syncthreads();
  int r2 = tid >> 2, q = tid & 3;
  union { short s[16]; float4 f[2]; } buf;
#pragma unroll
  for (int jj = 0; jj < 16; ++jj) buf.s[jj] = f2bf(t[q * 16 + jj][r2]);
  short* dst = Wt + (size_t)z * (1024 * 768) + (size_t)(c0 + r2) * 768 + k0 + q * 16;
  ((float4*)dst)[0] = buf.f[0];
  ((float4*)dst)[1] = buf.f[1];
}

// ---------------- QKV projection (bf16 MFMA): writes Qb/Kb [h][n][d], Vb [n][1024] ----------------
__global__ __launch_bounds__(256) void k_qkv(const short* __restrict__ xb,
                                             const short* __restrict__ Wt,
                                             const float* __restrict__ bq,
                                             const float* __restrict__ bk,
                                             const float* __restrict__ bv,
                                             short* __restrict__ Qb,
                                             short* __restrict__ Kb,
                                             short* __restrict__ Vb) {
  const int n0 = blockIdx.x * 128;  // 0..3071
  const int i0 = blockIdx.y * 128;
  const int mat = n0 >> 10;
  const int cl = n0 & 1023;
  const float* bias = (mat == 0) ? bq : (mat == 1) ? bk : bv;
  const short* Wm = Wt + (size_t)mat * (1024 * 768);
  const int tid = threadIdx.x, lane = tid & 63, wave = tid >> 6;
  const int ln = lane & 15, quad = lane >> 4, q8 = quad * 8;
  f32x4 acc[2][8];
#pragma unroll
  for (int a = 0; a < 2; ++a)
#pragma unroll
    for (int b = 0; b < 8; ++b) acc[a][b] = (f32x4){0.f, 0.f, 0.f, 0.f};
  const short* a0 = xb + (size_t)(i0 + 32 * wave + ln) * DIN + q8;
  const short* a1 = a0 + 16 * DIN;
  const short* bp = Wm + (size_t)(cl + ln) * DIN + q8;
  for (int ks = 0; ks < 24; ++ks) {
    bf16x8 A0 = *(const bf16x8*)(a0 + 32 * ks);
    bf16x8 A1 = *(const bf16x8*)(a1 + 32 * ks);
#pragma unroll
    for (int nt = 0; nt < 8; ++nt) {
      bf16x8 B = *(const bf16x8*)(bp + (size_t)nt * (16 * DIN) + 32 * ks);
      acc[0][nt] = __builtin_amdgcn_mfma_f32_16x16x32_bf16(A0, B, acc[0][nt], 0, 0, 0);
      acc[1][nt] = __builtin_amdgcn_mfma_f32_16x16x32_bf16(A1, B, acc[1][nt], 0, 0, 0);
    }
  }
#pragma unroll
  for (int rt = 0; rt < 2; ++rt)
#pragma unroll
    for (int nt = 0; nt < 8; ++nt) {
      int cg = cl + 16 * nt + ln;
      float bb = bias[cg];
#pragma unroll
      for (int reg = 0; reg < 4; ++reg) {
        int rr = i0 + 32 * wave + 16 * rt + quad * 4 + reg;
        short s = f2bf(acc[rt][nt][reg] + bb);
        if (mat == 2) {
          Vb[(size_t)rr * 1024 + cg] = s;
        } else {
          int h = cg >> 7, d = cg & 127;
          (mat == 0 ? Qb : Kb)[((size_t)h * NN + rr) * HD + d] = s;
        }
      }
    }
}

// ---------------- transpose Vb -> Vt[h][d][n] bf16 ----------------
__global__ __launch_bounds__(256) void k_v_t(const short* __restrict__ Vb,
                                             short* __restrict__ Vt) {
  const int i0 = blockIdx.x * 64, h = blockIdx.y;
  __shared__ __align__(16) short t[64][136];
  const int tid = threadIdx.x;
#pragma unroll
  for (int l = 0; l < 2; ++l) {
    int f = tid + l * 256;
    int r = f >> 3, c8 = (f & 7) * 16;
    const short* src = Vb + (size_t)(i0 + r) * 1024 + h * HD + c8;
    *(bf16x8*)&t[r][c8] = *(const bf16x8*)src;
    *(bf16x8*)&t[r][c8 + 8] = *(const bf16x8*)(src + 8);
  }
  __syncthreads();
  int d = tid >> 1, half = tid & 1;
  union { short s[32]; float4 f[4]; } buf;
#pragma unroll
  for (int ii = 0; ii < 32; ++ii) buf.s[ii] = t[32 * half + ii][d];
  short* dst = Vt + (size_t)h * (HD * NN) + (size_t)d * NN + i0 + 32 * half;
#pragma unroll
  for (int q = 0; q < 4; ++q) ((float4*)dst)[q] = buf.f[q];
}

// ---------------- gating from bf16 Q/K ----------------
__global__ __launch_bounds__(256) void k_gates(const short* __restrict__ Qb,
                                               const short* __restrict__ Kb,
                                               const float* __restrict__ gqw,
                                               const float* __restrict__ gqb,
                                               const float* __restrict__ gkw,
                                               const float* __restrict__ gkb,
                                               float* __restrict__ GQ,
                                               float* __restrict__ GK) {
  const int i = blockIdx.x;
  const int tid = threadIdx.x;
  float aq[NH] = {}, ak[NH] = {};
  for (int d = tid; d < DOUT; d += 256) {
    int h = d >> 7, dd = d & 127;
    float qv = bf2f(Qb[((size_t)h * NN + i) * HD + dd]);
    float kv = bf2f(Kb[((size_t)h * NN + i) * HD + dd]);
#pragma unroll
    for (int h2 = 0; h2 < NH; ++h2) {
      aq[h2] = fmaf(qv, gqw[d * NH + h2], aq[h2]);
      ak[h2] = fmaf(kv, gkw[d * NH + h2], ak[h2]);
    }
  }
  __shared__ float red8[NH][256];
#pragma unroll
  for (int h = 0; h < NH; ++h) red8[h][tid] = aq[h];
  __syncthreads();
  for (int s = 128; s > 0; s >>= 1) {
    if (tid < s) {
#pragma unroll
      for (int h = 0; h < NH; ++h) red8[h][tid] += red8[h][tid + s];
    }
    __syncthreads();
  }
  if (tid < NH) GQ[i * NH + tid] = tanhf(red8[tid][0] + gqb[tid]);
  __syncthreads();
#pragma unroll
  for (int h = 0; h < NH; ++h) red8[h][tid] = ak[h];
  __syncthreads();
  for (int s = 128; s > 0; s >>= 1) {
    if (tid < s) {
#pragma unroll
      for (int h = 0; h < NH; ++h) red8[h][tid] += red8[h][tid + s];
    }
    __syncthreads();
  }
  if (tid < NH) GK[i * NH + tid] = tanhf(red8[tid][0] + gkb[tid]);
}

// ---------------- fused scores + assemble (MFMA computes BOTH S and S^T tiles) -------
// attn[h,i,j] = S[h,i,j]*(1+gq[i,h]+gk[j,h]) + alpha*S[h,j,i] + beta*motif[h,j,i]
//              + sum_h2 S[h2,i,j]*W[h2,h]
// Trick: S[h,j,i] at output layout (i,j) is MFMA(A=K rows i, B=Q rows j) — no LDS
// transpose, no tile-pairing, no per-head barriers. motif[h,j,i] over reg is 4
// consecutive floats -> direct float4 load (64B/quad-group, fully coalesced).
__global__ __launch_bounds__(256) void k_sa(const short* __restrict__ Qb,
                                            const short* __restrict__ Kb,
                                            const int* __restrict__ batch,
                                            const float* __restrict__ motif,
                                            const float* __restrict__ GQ,
                                            const float* __restrict__ GK,
                                            const float* __restrict__ Wh,
                                            const float* __restrict__ alpha_p,
                                            const float* __restrict__ beta_p,
                                            float* __restrict__ ATTN) {
  const int i0 = blockIdx.y * 32, j0 = blockIdx.x * 32;
  const int tid = threadIdx.x, lane = tid & 63, wave = tid >> 6;
  const int wr = wave >> 1, wc = wave & 1;
  const int ln = lane & 15, quad = lane >> 4, q8 = quad * 8;
  __shared__ float sW[64];
  if (tid < 64) sW[tid] = Wh[tid];

  const int rowA = i0 + 16 * wr + ln;  // i-side rows (A operand / output rows)
  const int rowB = j0 + 16 * wc + ln;  // j-side rows (B operand / output cols)
  const int rA = 16 * wr + quad * 4;   // output row base within tile (+reg)
  const int cA = 16 * wc + ln;         // output col within tile

  f32x4 accS[NH], accT[NH];
#pragma unroll
  for (int h = 0; h < NH; ++h) {
    accS[h] = (f32x4){0.f, 0.f, 0.f, 0.f};
    accT[h] = (f32x4){0.f, 0.f, 0.f, 0.f};
  }
#pragma unroll
  for (int h = 0; h < NH; ++h) {
    const short* pQA = Qb + ((size_t)h * NN + rowA) * HD + q8;
    const short* pKB = Kb + ((size_t)h * NN + rowB) * HD + q8;
    const short* pKA = Kb + ((size_t)h * NN + rowA) * HD + q8;
    const short* pQB = Qb + ((size_t)h * NN + rowB) * HD + q8;
#pragma unroll
    for (int ks = 0; ks < 4; ++ks) {
      bf16x8 aS = *(const bf16x8*)(pQA + 32 * ks);
      bf16x8 bS = *(const bf16x8*)(pKB + 32 * ks);
      accS[h] = __builtin_amdgcn_mfma_f32_16x16x32_bf16(aS, bS, accS[h], 0, 0, 0);
      bf16x8 aT = *(const bf16x8*)(pKA + 32 * ks);
      bf16x8 bT = *(const bf16x8*)(pQB + 32 * ks);
      accT[h] = __builtin_amdgcn_mfma_f32_16x16x32_bf16(aT, bT, accT[h], 0, 0, 0);
    }
  }
  // mask + scale both (mask is symmetric: batch[i]==batch[j])
  const int4 bi4 = *(const int4*)(batch + i0 + rA);
  const int bj = batch[j0 + cA];
  const int bm[4] = {bi4.x, bi4.y, bi4.z, bi4.w};
#pragma unroll
  for (int reg = 0; reg < 4; ++reg) {
    const bool ok = (bm[reg] == bj);
#pragma unroll
    for (int h = 0; h < NH; ++h) {
      accS[h][reg] = ok ? accS[h][reg] * SCALEF : NEGF;
      accT[h][reg] = ok ? accT[h][reg] * SCALEF : NEGF;
    }
  }
  // per-thread gate preloads: gq rows i0+rA..+3 (32 consecutive f32), gk row j0+cA
  union { float f[32]; float4 v[8]; } gqu;
#pragma unroll
  for (int t = 0; t < 8; ++t)
    gqu.v[t] = *(const float4*)(GQ + (size_t)(i0 + rA) * NH + 4 * t);
  union { float f[8]; float4 v[2]; } gku;
#pragma unroll
  for (int t = 0; t < 2; ++t)
    gku.v[t] = *(const float4*)(GK + (size_t)(j0 + cA) * NH + 4 * t);
  const float alpha = alpha_p[0], beta = beta_p[0];
  __syncthreads();  // sW visible
#pragma unroll
  for (int h = 0; h < NH; ++h) {
    float w8[NH];
#pragma unroll
    for (int h2 = 0; h2 < NH; ++h2) w8[h2] = sW[h2 * NH + h];
    union { float f[4]; float4 v; } mo;
    mo.v = *(const float4*)(motif + ((size_t)h * NN + j0 + cA) * NN + i0 + rA);
#pragma unroll
    for (int reg = 0; reg < 4; ++reg) {
      float hm = 0.f;
#pragma unroll
      for (int h2 = 0; h2 < NH; ++h2) hm = fmaf(accS[h2][reg], w8[h2], hm);
      float o = accS[h][reg] * (1.f + gqu.f[reg * 8 + h] + gku.f[h]) +
                alpha * accT[h][reg] + beta * mo.f[reg] + hm;
      ATTN[((size_t)h * NN + i0 + rA + reg) * NN + j0 + cA] = o;
    }
  }
}

// ---------------- softmax stats per row ----------------
__global__ __launch_bounds__(256) void k_stats(const float* __restrict__ ATTN,
                                               float* __restrict__ MX,
                                               float* __restrict__ INVS) {
  const int row = blockIdx.x;
  const int tid = threadIdx.x;
  const float4* p = (const float4*)(ATTN + (size_t)row * NN);
  float4 a = p[tid], b = p[tid + 256];
  float m = fmaxf(fmaxf(fmaxf(a.x, a.y), fmaxf(a.z, a.w)),
                  fmaxf(fmaxf(b.x, b.y), fmaxf(b.z, b.w)));
  __shared__ float red[256];
  red[tid] = m; __syncthreads();
  for (int s = 128; s > 0; s >>= 1) {
    if (tid < s) red[tid] = fmaxf(red[tid], red[tid + s]);
    __syncthreads();
  }
  m = red[0];
  __syncthreads();
  float sum = expf(a.x - m) + expf(a.y - m) + expf(a.z - m) + expf(a.w - m) +
              expf(b.x - m) + expf(b.y - m) + expf(b.z - m) + expf(b.w - m);
  red[tid] = sum; __syncthreads();
  for (int s = 128; s > 0; s >>= 1) {
    if (tid < s) red[tid] += red[tid + s];
    __syncthreads();
  }
  if (tid == 0) {
    MX[row] = m;
    INVS[row] = 1.0f / red[0];
  }
}

// ---------------- P@V (bf16 MFMA, on-the-fly softmax, K-split 4 + atomics) ----------------
__global__ __launch_bounds__(256) void k_pv(const float* __restrict__ ATTN,
                                            const short* __restrict__ Vt,
                                            const float* __restrict__ MX,
                                            const float* __restrict__ INVS,
                                            float* __restrict__ O) {
  const int i0 = blockIdx.x * 64;
  const int j0 = blockIdx.y * 512;
  const int h = blockIdx.z;
  const int tid = threadIdx.x, lane = tid & 63, wave = tid >> 6;
  const int ln = lane & 15, quad = lane >> 4, q8 = quad * 8;
  __shared__ __align__(16) short Vl[2][128][40];
  const int row = i0 + 16 * wave + ln;
  const size_t rflat = (size_t)h * NN + row;
  const float mx = MX[rflat], inv = INVS[rflat];
  const float* arow = ATTN + rflat * NN;
  const short* vbase = Vt + (size_t)h * (HD * NN);
  f32x4 acc[8];
#pragma unroll
  for (int nt = 0; nt < 8; ++nt) acc[nt] = (f32x4){0.f, 0.f, 0.f, 0.f};
  // stage 128 d-rows x 32 j-cols: 2 threads per row, 16 shorts per thread
  const int vr = tid >> 1, vh = (tid & 1) * 16;
  *(bf16x8*)&Vl[0][vr][vh] = *(const bf16x8*)(vbase + (size_t)vr * NN + j0 + vh);
  *(bf16x8*)&Vl[0][vr][vh + 8] = *(const bf16x8*)(vbase + (size_t)vr * NN + j0 + vh + 8);
  __syncthreads();
  int buf = 0;
  for (int jk = j0; jk < j0 + 512; jk += 32, buf ^= 1) {
    if (jk + 32 < j0 + 512) {
      *(bf16x8*)&Vl[buf ^ 1][vr][vh] =
          *(const bf16x8*)(vbase + (size_t)vr * NN + jk + 32 + vh);
      *(bf16x8*)&Vl[buf ^ 1][vr][vh + 8] =
          *(const bf16x8*)(vbase + (size_t)vr * NN + jk + 32 + vh + 8);
    }
    float4 u1 = *(const float4*)(arow + jk + q8);
    float4 u2 = *(const float4*)(arow + jk + q8 + 4);
    bf16x8 a;
    a[0] = f2bf(__expf(u1.x - mx) * inv);
    a[1] = f2bf(__expf(u1.y - mx) * inv);
    a[2] = f2bf(__expf(u1.z - mx) * inv);
    a[3] = f2bf(__expf(u1.w - mx) * inv);
    a[4] = f2bf(__expf(u2.x - mx) * inv);
    a[5] = f2bf(__expf(u2.y - mx) * inv);
    a[6] = f2bf(__expf(u2.z - mx) * inv);
    a[7] = f2bf(__expf(u2.w - mx) * inv);
#pragma unroll
    for (int nt = 0; nt < 8; ++nt) {
      bf16x8 b = *(const bf16x8*)&Vl[buf][16 * nt + ln][q8];
      acc[nt] = __builtin_amdgcn_mfma_f32_16x16x32_bf16(a, b, acc[nt], 0, 0, 0);
    }
    __syncthreads();
  }
#pragma unroll
  for (int nt = 0; nt < 8; ++nt)
#pragma unroll
    for (int reg = 0; reg < 4; ++reg) {
      int rr = i0 + 16 * wave + quad * 4 + reg;
      atomicAdd(&O[(size_t)rr * DOUT + h * HD + 16 * nt + ln], acc[nt][reg]);
    }
}

// ---------------- out-proj SGEMM f32 (K-split + atomics) ----------------
__device__ __forceinline__ void mm_inner16(const float (*As)[132],
                                           const float (*Bs)[132],
                                           float (&acc)[8][8], int tx, int ty) {
#pragma unroll
  for (int k = 0; k < 16; ++k) {
    float a[8], b[8];
    *(float4*)&a[0] = *(const float4*)&As[k][ty * 8];
    *(float4*)&a[4] = *(const float4*)&As[k][ty * 8 + 4];
    *(float4*)&b[0] = *(const float4*)&Bs[k][tx * 8];
    *(float4*)&b[4] = *(const float4*)&Bs[k][tx * 8 + 4];
#pragma unroll
    for (int m = 0; m < 8; ++m)
#pragma unroll
      for (int n = 0; n < 8; ++n)
        acc[m][n] = fmaf(a[m], b[n], acc[m][n]);
  }
}

__global__ __launch_bounds__(256) void k_outproj(const float* __restrict__ O,
                                                 const float* __restrict__ wo,
                                                 float* __restrict__ YACC) {
  const int n0 = blockIdx.x * 128;
  const int i0 = blockIdx.y * 128;
  const int kbase = blockIdx.z * 256;
  __shared__ __align__(16) float As[16][132];
  __shared__ __align__(16) float Bs[16][132];
  const int tid = threadIdx.x;
  const int tx = tid & 15, ty = tid >> 4;
  float acc[8][8] = {};
  for (int k0 = kbase; k0 < kbase + 256; k0 += 16) {
#pragma unroll
    for (int l = 0; l < 2; ++l) {
      int f = tid + l * 256;
      int row = f >> 2, kc = (f & 3) * 4;
      float4 va = *(const float4*)(O + (size_t)(i0 + row) * DOUT + k0 + kc);
      As[kc + 0][row] = va.x; As[kc + 1][row] = va.y;
      As[kc + 2][row] = va.z; As[kc + 3][row] = va.w;
      int kr = f >> 5, c4 = (f & 31) * 4;
      float4 vb = *(const float4*)(wo + (size_t)(k0 + kr) * DIN + n0 + c4);
      *(float4*)&Bs[kr][c4] = vb;
    }
    __syncthreads();
    mm_inner16(As, Bs, acc, tx, ty);
    __syncthreads();
  }
#pragma unroll
  for (int m = 0; m < 8; ++m)
#pragma unroll
    for (int n = 0; n < 8; ++n)
      atomicAdd(&YACC[(size_t)(i0 + ty * 8 + m) * DIN + n0 + tx * 8 + n], acc[m][n]);
}

// ---------------- bias + residual + LayerNorm ----------------
__global__ __launch_bounds__(256) void k_ln(const float* __restrict__ YACC,
                                            const float* __restrict__ x,
                                            const float* __restrict__ wo_b,
                                            const float* __restrict__ g,
                                            const float* __restrict__ b,
                                            float* __restrict__ y) {
  const int i = blockIdx.x;
  const int tid = threadIdx.x;
  float v[3];
#pragma unroll
  for (int t = 0; t < 3; ++t) {
    int cc = tid + t * 256;
    v[t] = YACC[(size_t)i * DIN + cc] + wo_b[cc] + x[(size_t)i * DIN + cc];
  }
  __shared__ float red[256];
  red[tid] = v[0] + v[1] + v[2];
  __syncthreads();
  for (int s = 128; s > 0; s >>= 1) {
    if (tid < s) red[tid] += red[tid + s];
    __syncthreads();
  }
  const float mu = red[0] * (1.0f / DIN);
  __syncthreads();
  float q = 0.f;
#pragma unroll
  for (int t = 0; t < 3; ++t) {
    float d = v[t] - mu;
    q += d * d;
  }
  red[tid] = q;
  __syncthreads();
  for (int s = 128; s > 0; s >>= 1) {
    if (tid < s) red[tid] += red[tid + s];
    __syncthreads();
  }
  const float rs = rsqrtf(red[0] * (1.0f / DIN) + EPSF);
#pragma unroll
  for (int t = 0; t < 3; ++t) {
    int cc = tid + t * 256;
    y[(size_t)i * DIN + cc] = (v[t] - mu) * rs * g[cc] + b[cc];
  }
}

extern "C" void kernel_launch(void* const* d_in, const int* in_sizes, int n_in,
                              void* d_out, int out_size, void* d_ws, size_t ws_size,
                              hipStream_t stream) {
  (void)in_sizes; (void)n_in; (void)out_size; (void)ws_size;
  const float* x       = (const float*)d_in[0];
  const int*   batch   = (const int*)d_in[1];
  const float* motif   = (const float*)d_in[2];
  const float* wq_w    = (const float*)d_in[3];
  const float* wq_b    = (const float*)d_in[4];
  const float* wk_w    = (const float*)d_in[5];
  const float* wk_b    = (const float*)d_in[6];
  const float* wv_w    = (const float*)d_in[7];
  const float* wv_b    = (const float*)d_in[8];
  const float* wo_w    = (const float*)d_in[9];
  const float* wo_b    = (const float*)d_in[10];
  const float* ln_g    = (const float*)d_in[11];
  const float* ln_b    = (const float*)d_in[12];
  const float* alpha_p = (const float*)d_in[13];
  const float* beta_p  = (const float*)d_in[14];
  const float* gq_w    = (const float*)d_in[15];
  const float* gq_b    = (const float*)d_in[16];
  const float* gk_w    = (const float*)d_in[17];
  const float* gk_b    = (const float*)d_in[18];
  const float* headW   = (const float*)d_in[19];

  float* y    = (float*)d_out;
  float* ATTN = (float*)d_out + (size_t)NN * DIN;
  float* ws   = (float*)d_ws;
  float* O    = ws + OFF_O;
  float* YACC = ws + OFF_YACC;
  short* Qb   = (short*)(ws + OFF_Q);
  short* Kb   = (short*)(ws + OFF_K);
  short* Vb   = (short*)(ws + OFF_VB);
  short* Vt   = (short*)(ws + OFF_VT);
  short* xb   = (short*)(ws + OFF_XB);
  short* Wt   = (short*)(ws + OFF_WT);
  float* GQ   = ws + OFF_GQ;
  float* GK   = ws + OFF_GK;
  float* MX   = ws + OFF_MX;
  float* INV  = ws + OFF_INV;

  k_zero<<<3584, 256, 0, stream>>>((float4*)(ws + OFF_O));
  k_cast_x<<<1536, 256, 0, stream>>>(x, xb);
  k_w_cast_t<<<dim3(16, 12, 3), 256, 0, stream>>>(wq_w, wk_w, wv_w, Wt);
  k_qkv<<<dim3(24, 16), 256, 0, stream>>>(xb, Wt, wq_b, wk_b, wv_b, Qb, Kb, Vb);
  k_v_t<<<dim3(32, 8), 256, 0, stream>>>(Vb, Vt);
  k_gates<<<NN, 256, 0, stream>>>(Qb, Kb, gq_w, gq_b, gk_w, gk_b, GQ, GK);
  k_sa<<<dim3(64, 64), 256, 0, stream>>>(Qb, Kb, batch, motif, GQ, GK, headW,
                                         alpha_p, beta_p, ATTN);
  k_stats<<<NH * NN, 256, 0, stream>>>(ATTN, MX, INV);
  k_pv<<<dim3(32, 4, NH), 256, 0, stream>>>(ATTN, Vt, MX, INV, O);
  k_outproj<<<dim3(6, 16, 4), 256, 0, stream>>>(O, wo_w, YACC);
  k_ln<<<NN, 256, 0, stream>>>(YACC, x, wo_b, ln_g, ln_b, y);
}

// Round 2
// 866.591 us; speedup vs baseline: 1.0327x; 1.0327x over previous
//
#include <hip/hip_runtime.h>

#define NN    2048
#define DIN   768
#define DOUT  1024
#define NH    8
#define HD    128
#define SCALEF 0.08838834764831845f
#define NEGF  (-1.0e9f)
#define EPSF  1e-5f
#define EXPSHIFT 16.0f

typedef __attribute__((ext_vector_type(4))) float f32x4;
typedef __attribute__((ext_vector_type(8))) short bf16x8;

// workspace layout (float-slot offsets)
#define OFF_O    0                         // 2,097,152 f32
#define OFF_YACC 2097152                   // 1,572,864 f32
#define OFF_SUM  3670016                   // 16,384 f32   (zero region = [0, 3686400))
#define OFF_Q    3686400                   // bf16 [8][2048][128] = 1,048,576 f32 slots
#define OFF_K    4734976
#define OFF_VB   5783552                   // bf16 [2048][1024]
#define OFF_VT   6832128                   // bf16 [8][128][2048]
#define OFF_XB   7880704                   // bf16 [2048][768] = 786,432 f32 slots
#define OFF_WT   8667136                   // bf16 [3][1024][768] = 1,179,648 f32 slots
#define OFF_GQ   9846784
#define OFF_GK   9863168

__device__ __forceinline__ short f2bf(float f) {
  union { float f; unsigned u; } v; v.f = f;
  unsigned r = v.u + 0x7FFF + ((v.u >> 16) & 1);
  return (short)(r >> 16);
}
__device__ __forceinline__ float bf2f(short s) {
  union { unsigned u; float f; } v; v.u = ((unsigned)(unsigned short)s) << 16;
  return v.f;
}

// ---------------- zero O + YACC + SUM ----------------
__global__ __launch_bounds__(256) void k_zero(float4* __restrict__ p) {
  p[(size_t)blockIdx.x * 256 + threadIdx.x] = float4{0.f, 0.f, 0.f, 0.f};
}

// ---------------- cast x -> bf16 ----------------
__global__ __launch_bounds__(256) void k_cast_x(const float* __restrict__ x,
                                                short* __restrict__ xb) {
  int idx = blockIdx.x * 256 + threadIdx.x;  // 393216 float4s
  float4 v = ((const float4*)x)[idx];
  union { short s[4]; float2 f; } u;
  u.s[0] = f2bf(v.x); u.s[1] = f2bf(v.y); u.s[2] = f2bf(v.z); u.s[3] = f2bf(v.w);
  ((float2*)xb)[idx] = u.f;
}

// ---------------- transpose+cast W[768][1024] -> Wt[z][1024][768] bf16 ----------------
__global__ __launch_bounds__(256) void k_w_cast_t(const float* __restrict__ wq,
                                                  const float* __restrict__ wk,
                                                  const float* __restrict__ wv,
                                                  short* __restrict__ Wt) {
  const int c0 = blockIdx.x * 64, k0 = blockIdx.y * 64, z = blockIdx.z;
  const float* Wm = (z == 0) ? wq : (z == 1) ? wk : wv;
  __shared__ float t[64][65];
  const int tid = threadIdx.x;
#pragma unroll
  for (int l = 0; l < 4; ++l) {
    int f = tid + l * 256;
    int r = f >> 4, c4 = (f & 15) * 4;
    *(float4*)&t[r][c4] = *(const float4*)(Wm + (size_t)(k0 + r) * DOUT + c0 + c4);
  }
  __syncthreads();
  int r2 = tid >> 2, q = tid & 3;
  union { short s[16]; float4 f[2]; } buf;
#pragma unroll
  for (int jj = 0; jj < 16; ++jj) buf.s[jj] = f2bf(t[q * 16 + jj][r2]);
  short* dst = Wt + (size_t)z * (1024 * 768) + (size_t)(c0 + r2) * 768 + k0 + q * 16;
  ((float4*)dst)[0] = buf.f[0];
  ((float4*)dst)[1] = buf.f[1];
}

// ---------------- QKV projection (bf16 MFMA): writes Qb/Kb [h][n][d], Vb [n][1024] ----------------
__global__ __launch_bounds__(256) void k_qkv(const short* __restrict__ xb,
                                             const short* __restrict__ Wt,
                                             const float* __restrict__ bq,
                                             const float* __restrict__ bk,
                                             const float* __restrict__ bv,
                                             short* __restrict__ Qb,
                                             short* __restrict__ Kb,
                                             short* __restrict__ Vb) {
  const int n0 = blockIdx.x * 128;  // 0..3071
  const int i0 = blockIdx.y * 128;
  const int mat = n0 >> 10;
  const int cl = n0 & 1023;
  const float* bias = (mat == 0) ? bq : (mat == 1) ? bk : bv;
  const short* Wm = Wt + (size_t)mat * (1024 * 768);
  const int tid = threadIdx.x, lane = tid & 63, wave = tid >> 6;
  const int ln = lane & 15, quad = lane >> 4, q8 = quad * 8;
  f32x4 acc[2][8];
#pragma unroll
  for (int a = 0; a < 2; ++a)
#pragma unroll
    for (int b = 0; b < 8; ++b) acc[a][b] = (f32x4){0.f, 0.f, 0.f, 0.f};
  const short* a0 = xb + (size_t)(i0 + 32 * wave + ln) * DIN + q8;
  const short* a1 = a0 + 16 * DIN;
  const short* bp = Wm + (size_t)(cl + ln) * DIN + q8;
  for (int ks = 0; ks < 24; ++ks) {
    bf16x8 A0 = *(const bf16x8*)(a0 + 32 * ks);
    bf16x8 A1 = *(const bf16x8*)(a1 + 32 * ks);
#pragma unroll
    for (int nt = 0; nt < 8; ++nt) {
      bf16x8 B = *(const bf16x8*)(bp + (size_t)nt * (16 * DIN) + 32 * ks);
      acc[0][nt] = __builtin_amdgcn_mfma_f32_16x16x32_bf16(A0, B, acc[0][nt], 0, 0, 0);
      acc[1][nt] = __builtin_amdgcn_mfma_f32_16x16x32_bf16(A1, B, acc[1][nt], 0, 0, 0);
    }
  }
#pragma unroll
  for (int rt = 0; rt < 2; ++rt)
#pragma unroll
    for (int nt = 0; nt < 8; ++nt) {
      int cg = cl + 16 * nt + ln;
      float bb = bias[cg];
#pragma unroll
      for (int reg = 0; reg < 4; ++reg) {
        int rr = i0 + 32 * wave + 16 * rt + quad * 4 + reg;
        short s = f2bf(acc[rt][nt][reg] + bb);
        if (mat == 2) {
          Vb[(size_t)rr * 1024 + cg] = s;
        } else {
          int h = cg >> 7, d = cg & 127;
          (mat == 0 ? Qb : Kb)[((size_t)h * NN + rr) * HD + d] = s;
        }
      }
    }
}

// ---------------- transpose Vb -> Vt[h][d][n] bf16 ----------------
__global__ __launch_bounds__(256) void k_v_t(const short* __restrict__ Vb,
                                             short* __restrict__ Vt) {
  const int i0 = blockIdx.x * 64, h = blockIdx.y;
  __shared__ __align__(16) short t[64][136];
  const int tid = threadIdx.x;
#pragma unroll
  for (int l = 0; l < 2; ++l) {
    int f = tid + l * 256;
    int r = f >> 3, c8 = (f & 7) * 16;
    const short* src = Vb + (size_t)(i0 + r) * 1024 + h * HD + c8;
    *(bf16x8*)&t[r][c8] = *(const bf16x8*)src;
    *(bf16x8*)&t[r][c8 + 8] = *(const bf16x8*)(src + 8);
  }
  __syncthreads();
  int d = tid >> 1, half = tid & 1;
  union { short s[32]; float4 f[4]; } buf;
#pragma unroll
  for (int ii = 0; ii < 32; ++ii) buf.s[ii] = t[32 * half + ii][d];
  short* dst = Vt + (size_t)h * (HD * NN) + (size_t)d * NN + i0 + 32 * half;
#pragma unroll
  for (int q = 0; q < 4; ++q) ((float4*)dst)[q] = buf.f[q];
}

// ---------------- gating from bf16 Q/K ----------------
__global__ __launch_bounds__(256) void k_gates(const short* __restrict__ Qb,
                                               const short* __restrict__ Kb,
                                               const float* __restrict__ gqw,
                                               const float* __restrict__ gqb,
                                               const float* __restrict__ gkw,
                                               const float* __restrict__ gkb,
                                               float* __restrict__ GQ,
                                               float* __restrict__ GK) {
  const int i = blockIdx.x;
  const int tid = threadIdx.x;
  float aq[NH] = {}, ak[NH] = {};
  for (int d = tid; d < DOUT; d += 256) {
    int h = d >> 7, dd = d & 127;
    float qv = bf2f(Qb[((size_t)h * NN + i) * HD + dd]);
    float kv = bf2f(Kb[((size_t)h * NN + i) * HD + dd]);
#pragma unroll
    for (int h2 = 0; h2 < NH; ++h2) {
      aq[h2] = fmaf(qv, gqw[d * NH + h2], aq[h2]);
      ak[h2] = fmaf(kv, gkw[d * NH + h2], ak[h2]);
    }
  }
  __shared__ float red8[NH][256];
#pragma unroll
  for (int h = 0; h < NH; ++h) red8[h][tid] = aq[h];
  __syncthreads();
  for (int s = 128; s > 0; s >>= 1) {
    if (tid < s) {
#pragma unroll
      for (int h = 0; h < NH; ++h) red8[h][tid] += red8[h][tid + s];
    }
    __syncthreads();
  }
  if (tid < NH) GQ[i * NH + tid] = tanhf(red8[tid][0] + gqb[tid]);
  __syncthreads();
#pragma unroll
  for (int h = 0; h < NH; ++h) red8[h][tid] = ak[h];
  __syncthreads();
  for (int s = 128; s > 0; s >>= 1) {
    if (tid < s) {
#pragma unroll
      for (int h = 0; h < NH; ++h) red8[h][tid] += red8[h][tid + s];
    }
    __syncthreads();
  }
  if (tid < NH) GK[i * NH + tid] = tanhf(red8[tid][0] + gkb[tid]);
}

// ---------------- fused scores + assemble ----------------
// attn[h,i,j] = S[h,i,j]*(1+gq[i,h]+gk[j,h]) + alpha*S[h,j,i] + beta*motif[h,j,i]
//              + sum_h2 S[h2,i,j]*W[h2,h]
// S^T tile computed JUST-IN-TIME per head (mfma(K_i, Q_j)) to keep only 32 acc
// VGPRs live through the main loop -> compiler can pipeline loads. Motif rows
// prefetched as 8 independent float4 loads. launch_bounds(256,4) -> <=128 VGPR.
__global__ __launch_bounds__(256, 4) void k_sa(const short* __restrict__ Qb,
                                               const short* __restrict__ Kb,
                                               const int* __restrict__ batch,
                                               const float* __restrict__ motif,
                                               const float* __restrict__ GQ,
                                               const float* __restrict__ GK,
                                               const float* __restrict__ Wh,
                                               const float* __restrict__ alpha_p,
                                               const float* __restrict__ beta_p,
                                               float* __restrict__ ATTN) {
  const int i0 = blockIdx.y * 32, j0 = blockIdx.x * 32;
  const int tid = threadIdx.x, lane = tid & 63, wave = tid >> 6;
  const int wr = wave >> 1, wc = wave & 1;
  const int ln = lane & 15, quad = lane >> 4, q8 = quad * 8;
  __shared__ float sW[64];
  if (tid < 64) sW[tid] = Wh[tid];

  const int rowA = i0 + 16 * wr + ln;  // i-side rows
  const int rowB = j0 + 16 * wc + ln;  // j-side rows
  const int rA = 16 * wr + quad * 4;   // output row base within tile (+reg)
  const int cA = 16 * wc + ln;         // output col within tile

  // prefetch motif^T: motif[h][j0+cA][i0+rA..+3] — 8 independent HBM loads
  union { float4 v; float f[4]; } mo[NH];
#pragma unroll
  for (int h = 0; h < NH; ++h)
    mo[h].v = *(const float4*)(motif + ((size_t)h * NN + j0 + cA) * NN + i0 + rA);

  f32x4 accS[NH];
#pragma unroll
  for (int h = 0; h < NH; ++h) accS[h] = (f32x4){0.f, 0.f, 0.f, 0.f};
#pragma unroll
  for (int h = 0; h < NH; ++h) {
    const short* pQA = Qb + ((size_t)h * NN + rowA) * HD + q8;
    const short* pKB = Kb + ((size_t)h * NN + rowB) * HD + q8;
#pragma unroll
    for (int ks = 0; ks < 4; ++ks) {
      bf16x8 a = *(const bf16x8*)(pQA + 32 * ks);
      bf16x8 b = *(const bf16x8*)(pKB + 32 * ks);
      accS[h] = __builtin_amdgcn_mfma_f32_16x16x32_bf16(a, b, accS[h], 0, 0, 0);
    }
  }
  // mask + scale S (mask symmetric: batch[i]==batch[j])
  const int4 bi4 = *(const int4*)(batch + i0 + rA);
  const int bj = batch[j0 + cA];
  int okm[4];
  okm[0] = (bi4.x == bj); okm[1] = (bi4.y == bj);
  okm[2] = (bi4.z == bj); okm[3] = (bi4.w == bj);
#pragma unroll
  for (int reg = 0; reg < 4; ++reg)
#pragma unroll
    for (int h = 0; h < NH; ++h)
      accS[h][reg] = okm[reg] ? accS[h][reg] * SCALEF : NEGF;

  // gate preloads: gq rows i0+rA..+3 (32 consecutive f32), gk row j0+cA
  union { float f[32]; float4 v[8]; } gqu;
#pragma unroll
  for (int t = 0; t < 8; ++t)
    gqu.v[t] = *(const float4*)(GQ + (size_t)(i0 + rA) * NH + 4 * t);
  union { float f[8]; float4 v[2]; } gku;
#pragma unroll
  for (int t = 0; t < 2; ++t)
    gku.v[t] = *(const float4*)(GK + (size_t)(j0 + cA) * NH + 4 * t);
  const float alpha = alpha_p[0], beta = beta_p[0];
  __syncthreads();  // sW visible
#pragma unroll
  for (int h = 0; h < NH; ++h) {
    // transposed tile for this head, just-in-time: S[h,j,i] = mfma(K_i, Q_j)
    f32x4 t = (f32x4){0.f, 0.f, 0.f, 0.f};
    const short* pKA = Kb + ((size_t)h * NN + rowA) * HD + q8;
    const short* pQB = Qb + ((size_t)h * NN + rowB) * HD + q8;
#pragma unroll
    for (int ks = 0; ks < 4; ++ks) {
      bf16x8 a = *(const bf16x8*)(pKA + 32 * ks);
      bf16x8 b = *(const bf16x8*)(pQB + 32 * ks);
      t = __builtin_amdgcn_mfma_f32_16x16x32_bf16(a, b, t, 0, 0, 0);
    }
    float w8[NH];
#pragma unroll
    for (int h2 = 0; h2 < NH; ++h2) w8[h2] = sW[h2 * NH + h];
#pragma unroll
    for (int reg = 0; reg < 4; ++reg) {
      float tv = okm[reg] ? t[reg] * SCALEF : NEGF;
      float hm = 0.f;
#pragma unroll
      for (int h2 = 0; h2 < NH; ++h2) hm = fmaf(accS[h2][reg], w8[h2], hm);
      float o = accS[h][reg] * (1.f + gqu.f[reg * 8 + h] + gku.f[h]) +
                alpha * tv + beta * mo[h].f[reg] + hm;
      ATTN[((size_t)h * NN + i0 + rA + reg) * NN + j0 + cA] = o;
    }
  }
}

// ---------------- P@V (bf16 MFMA, constant-shift softmax, K-split 4 + atomics) --------
// probs = exp(x-16)/sum(exp(x-16)): shift-invariant softmax, no stats pass needed.
// Accumulates unnormalized O; per-row sums atomically into SUM; k_outproj divides.
__global__ __launch_bounds__(256) void k_pv(const float* __restrict__ ATTN,
                                            const short* __restrict__ Vt,
                                            float* __restrict__ O,
                                            float* __restrict__ SUM) {
  const int i0 = blockIdx.x * 64;
  const int j0 = blockIdx.y * 512;
  const int h = blockIdx.z;
  const int tid = threadIdx.x, lane = tid & 63, wave = tid >> 6;
  const int ln = lane & 15, quad = lane >> 4, q8 = quad * 8;
  __shared__ __align__(16) short Vl[2][128][40];
  const int row = i0 + 16 * wave + ln;
  const size_t rflat = (size_t)h * NN + row;
  const float* arow = ATTN + rflat * NN;
  const short* vbase = Vt + (size_t)h * (HD * NN);
  f32x4 acc[8];
#pragma unroll
  for (int nt = 0; nt < 8; ++nt) acc[nt] = (f32x4){0.f, 0.f, 0.f, 0.f};
  // prefetch first ATTN chunk
  float4 u1 = *(const float4*)(arow + j0 + q8);
  float4 u2 = *(const float4*)(arow + j0 + q8 + 4);
  float rowsum = 0.f;
  // stage 128 d-rows x 32 j-cols: 2 threads per row, 16 shorts per thread
  const int vr = tid >> 1, vh = (tid & 1) * 16;
  *(bf16x8*)&Vl[0][vr][vh] = *(const bf16x8*)(vbase + (size_t)vr * NN + j0 + vh);
  *(bf16x8*)&Vl[0][vr][vh + 8] = *(const bf16x8*)(vbase + (size_t)vr * NN + j0 + vh + 8);
  __syncthreads();
  int buf = 0;
  for (int jk = j0; jk < j0 + 512; jk += 32, buf ^= 1) {
    const bool more = (jk + 32 < j0 + 512);
    if (more) {
      *(bf16x8*)&Vl[buf ^ 1][vr][vh] =
          *(const bf16x8*)(vbase + (size_t)vr * NN + jk + 32 + vh);
      *(bf16x8*)&Vl[buf ^ 1][vr][vh + 8] =
          *(const bf16x8*)(vbase + (size_t)vr * NN + jk + 32 + vh + 8);
    }
    float4 c1 = u1, c2 = u2;
    if (more) {  // prefetch next ATTN chunk under this step's compute
      u1 = *(const float4*)(arow + jk + 32 + q8);
      u2 = *(const float4*)(arow + jk + 32 + q8 + 4);
    }
    float p0 = __expf(c1.x - EXPSHIFT), p1 = __expf(c1.y - EXPSHIFT);
    float p2 = __expf(c1.z - EXPSHIFT), p3 = __expf(c1.w - EXPSHIFT);
    float p4 = __expf(c2.x - EXPSHIFT), p5 = __expf(c2.y - EXPSHIFT);
    float p6 = __expf(c2.z - EXPSHIFT), p7 = __expf(c2.w - EXPSHIFT);
    rowsum += ((p0 + p1) + (p2 + p3)) + ((p4 + p5) + (p6 + p7));
    bf16x8 a;
    a[0] = f2bf(p0); a[1] = f2bf(p1); a[2] = f2bf(p2); a[3] = f2bf(p3);
    a[4] = f2bf(p4); a[5] = f2bf(p5); a[6] = f2bf(p6); a[7] = f2bf(p7);
#pragma unroll
    for (int nt = 0; nt < 8; ++nt) {
      bf16x8 b = *(const bf16x8*)&Vl[buf][16 * nt + ln][q8];
      acc[nt] = __builtin_amdgcn_mfma_f32_16x16x32_bf16(a, b, acc[nt], 0, 0, 0);
    }
    __syncthreads();
  }
  // per-row sum: reduce across the 4 quads sharing this row
  rowsum += __shfl_xor(rowsum, 16);
  rowsum += __shfl_xor(rowsum, 32);
  if (lane < 16) atomicAdd(&SUM[rflat], rowsum);
#pragma unroll
  for (int nt = 0; nt < 8; ++nt)
#pragma unroll
    for (int reg = 0; reg < 4; ++reg) {
      int rr = i0 + 16 * wave + quad * 4 + reg;
      atomicAdd(&O[(size_t)rr * DOUT + h * HD + 16 * nt + ln], acc[nt][reg]);
    }
}

// ---------------- out-proj SGEMM f32 (K-split + atomics, softmax-normalizing) --------
__device__ __forceinline__ void mm_inner16(const float (*As)[132],
                                           const float (*Bs)[132],
                                           float (&acc)[8][8], int tx, int ty) {
#pragma unroll
  for (int k = 0; k < 16; ++k) {
    float a[8], b[8];
    *(float4*)&a[0] = *(const float4*)&As[k][ty * 8];
    *(float4*)&a[4] = *(const float4*)&As[k][ty * 8 + 4];
    *(float4*)&b[0] = *(const float4*)&Bs[k][tx * 8];
    *(float4*)&b[4] = *(const float4*)&Bs[k][tx * 8 + 4];
#pragma unroll
    for (int m = 0; m < 8; ++m)
#pragma unroll
      for (int n = 0; n < 8; ++n)
        acc[m][n] = fmaf(a[m], b[n], acc[m][n]);
  }
}

__global__ __launch_bounds__(256) void k_outproj(const float* __restrict__ O,
                                                 const float* __restrict__ wo,
                                                 const float* __restrict__ SUM,
                                                 float* __restrict__ YACC) {
  const int n0 = blockIdx.x * 128;
  const int i0 = blockIdx.y * 128;
  const int kbase = blockIdx.z * 256;
  __shared__ __align__(16) float As[16][132];
  __shared__ __align__(16) float Bs[16][132];
  const int tid = threadIdx.x;
  const int tx = tid & 15, ty = tid >> 4;
  float acc[8][8] = {};
  for (int k0 = kbase; k0 < kbase + 256; k0 += 16) {
#pragma unroll
    for (int l = 0; l < 2; ++l) {
      int f = tid + l * 256;
      int row = f >> 2, kc = (f & 3) * 4;
      float4 va = *(const float4*)(O + (size_t)(i0 + row) * DOUT + k0 + kc);
      float sc = 1.0f / SUM[(size_t)((k0 + kc) >> 7) * NN + i0 + row];
      As[kc + 0][row] = va.x * sc; As[kc + 1][row] = va.y * sc;
      As[kc + 2][row] = va.z * sc; As[kc + 3][row] = va.w * sc;
      int kr = f >> 5, c4 = (f & 31) * 4;
      float4 vb = *(const float4*)(wo + (size_t)(k0 + kr) * DIN + n0 + c4);
      *(float4*)&Bs[kr][c4] = vb;
    }
    __syncthreads();
    mm_inner16(As, Bs, acc, tx, ty);
    __syncthreads();
  }
#pragma unroll
  for (int m = 0; m < 8; ++m)
#pragma unroll
    for (int n = 0; n < 8; ++n)
      atomicAdd(&YACC[(size_t)(i0 + ty * 8 + m) * DIN + n0 + tx * 8 + n], acc[m][n]);
}

// ---------------- bias + residual + LayerNorm ----------------
__global__ __launch_bounds__(256) void k_ln(const float* __restrict__ YACC,
                                            const float* __restrict__ x,
                                            const float* __restrict__ wo_b,
                                            const float* __restrict__ g,
                                            const float* __restrict__ b,
                                            float* __restrict__ y) {
  const int i = blockIdx.x;
  const int tid = threadIdx.x;
  float v[3];
#pragma unroll
  for (int t = 0; t < 3; ++t) {
    int cc = tid + t * 256;
    v[t] = YACC[(size_t)i * DIN + cc] + wo_b[cc] + x[(size_t)i * DIN + cc];
  }
  __shared__ float red[256];
  red[tid] = v[0] + v[1] + v[2];
  __syncthreads();
  for (int s = 128; s > 0; s >>= 1) {
    if (tid < s) red[tid] += red[tid + s];
    __syncthreads();
  }
  const float mu = red[0] * (1.0f / DIN);
  __syncthreads();
  float q = 0.f;
#pragma unroll
  for (int t = 0; t < 3; ++t) {
    float d = v[t] - mu;
    q += d * d;
  }
  red[tid] = q;
  __syncthreads();
  for (int s = 128; s > 0; s >>= 1) {
    if (tid < s) red[tid] += red[tid + s];
    __syncthreads();
  }
  const float rs = rsqrtf(red[0] * (1.0f / DIN) + EPSF);
#pragma unroll
  for (int t = 0; t < 3; ++t) {
    int cc = tid + t * 256;
    y[(size_t)i * DIN + cc] = (v[t] - mu) * rs * g[cc] + b[cc];
  }
}

extern "C" void kernel_launch(void* const* d_in, const int* in_sizes, int n_in,
                              void* d_out, int out_size, void* d_ws, size_t ws_size,
                              hipStream_t stream) {
  (void)in_sizes; (void)n_in; (void)out_size; (void)ws_size;
  const float* x       = (const float*)d_in[0];
  const int*   batch   = (const int*)d_in[1];
  const float* motif   = (const float*)d_in[2];
  const float* wq_w    = (const float*)d_in[3];
  const float* wq_b    = (const float*)d_in[4];
  const float* wk_w    = (const float*)d_in[5];
  const float* wk_b    = (const float*)d_in[6];
  const float* wv_w    = (const float*)d_in[7];
  const float* wv_b    = (const float*)d_in[8];
  const float* wo_w    = (const float*)d_in[9];
  const float* wo_b    = (const float*)d_in[10];
  const float* ln_g    = (const float*)d_in[11];
  const float* ln_b    = (const float*)d_in[12];
  const float* alpha_p = (const float*)d_in[13];
  const float* beta_p  = (const float*)d_in[14];
  const float* gq_w    = (const float*)d_in[15];
  const float* gq_b    = (const float*)d_in[16];
  const float* gk_w    = (const float*)d_in[17];
  const float* gk_b    = (const float*)d_in[18];
  const float* headW   = (const float*)d_in[19];

  float* y    = (float*)d_out;
  float* ATTN = (float*)d_out + (size_t)NN * DIN;
  float* ws   = (float*)d_ws;
  float* O    = ws + OFF_O;
  float* YACC = ws + OFF_YACC;
  float* SUM  = ws + OFF_SUM;
  short* Qb   = (short*)(ws + OFF_Q);
  short* Kb   = (short*)(ws + OFF_K);
  short* Vb   = (short*)(ws + OFF_VB);
  short* Vt   = (short*)(ws + OFF_VT);
  short* xb   = (short*)(ws + OFF_XB);
  short* Wt   = (short*)(ws + OFF_WT);
  float* GQ   = ws + OFF_GQ;
  float* GK   = ws + OFF_GK;

  k_zero<<<3600, 256, 0, stream>>>((float4*)(ws + OFF_O));
  k_cast_x<<<1536, 256, 0, stream>>>(x, xb);
  k_w_cast_t<<<dim3(16, 12, 3), 256, 0, stream>>>(wq_w, wk_w, wv_w, Wt);
  k_qkv<<<dim3(24, 16), 256, 0, stream>>>(xb, Wt, wq_b, wk_b, wv_b, Qb, Kb, Vb);
  k_v_t<<<dim3(32, 8), 256, 0, stream>>>(Vb, Vt);
  k_gates<<<NN, 256, 0, stream>>>(Qb, Kb, gq_w, gq_b, gk_w, gk_b, GQ, GK);
  k_sa<<<dim3(64, 64), 256, 0, stream>>>(Qb, Kb, batch, motif, GQ, GK, headW,
                                         alpha_p, beta_p, ATTN);
  k_pv<<<dim3(32, 4, NH), 256, 0, stream>>>(ATTN, Vt, O, SUM);
  k_outproj<<<dim3(6, 16, 4), 256, 0, stream>>>(O, wo_w, SUM, YACC);
  k_ln<<<NN, 256, 0, stream>>>(YACC, x, wo_b, ln_g, ln_b, y);
}

// Round 3
// 825.070 us; speedup vs baseline: 1.0846x; 1.0503x over previous
//
#include <hip/hip_runtime.h>

#define NN    2048
#define DIN   768
#define DOUT  1024
#define NH    8
#define HD    128
#define SCALEF 0.08838834764831845f
#define NEGF  (-1.0e9f)
#define EPSF  1e-5f
#define EXPSHIFT 16.0f

typedef __attribute__((ext_vector_type(4))) float f32x4;
typedef __attribute__((ext_vector_type(8))) short bf16x8;

// workspace layout (float-slot offsets)
#define OFF_O    0                         // 2,097,152 f32
#define OFF_YACC 2097152                   // 1,572,864 f32
#define OFF_SUM  3670016                   // 16,384 f32   (zero region = [0, 3686400))
#define OFF_Q    3686400                   // bf16 [8][2048][128] = 1,048,576 f32 slots
#define OFF_K    4734976
#define OFF_VB   5783552                   // bf16 [2048][1024]
#define OFF_VT   6832128                   // bf16 [8][128][2048]
#define OFF_XB   7880704                   // bf16 [2048][768] = 786,432 f32 slots
#define OFF_WT   8667136                   // bf16 [3][1024][768] = 1,179,648 f32 slots
#define OFF_GQ   9846784
#define OFF_GK   9863168

__device__ __forceinline__ short f2bf(float f) {
  union { float f; unsigned u; } v; v.f = f;
  unsigned r = v.u + 0x7FFF + ((v.u >> 16) & 1);
  return (short)(r >> 16);
}
__device__ __forceinline__ float bf2f(short s) {
  union { unsigned u; float f; } v; v.u = ((unsigned)(unsigned short)s) << 16;
  return v.f;
}

// ---------------- zero O + YACC + SUM ----------------
__global__ __launch_bounds__(256) void k_zero(float4* __restrict__ p) {
  p[(size_t)blockIdx.x * 256 + threadIdx.x] = float4{0.f, 0.f, 0.f, 0.f};
}

// ---------------- cast x -> bf16 ----------------
__global__ __launch_bounds__(256) void k_cast_x(const float* __restrict__ x,
                                                short* __restrict__ xb) {
  int idx = blockIdx.x * 256 + threadIdx.x;  // 393216 float4s
  float4 v = ((const float4*)x)[idx];
  union { short s[4]; float2 f; } u;
  u.s[0] = f2bf(v.x); u.s[1] = f2bf(v.y); u.s[2] = f2bf(v.z); u.s[3] = f2bf(v.w);
  ((float2*)xb)[idx] = u.f;
}

// ---------------- transpose+cast W[768][1024] -> Wt[z][1024][768] bf16 ----------------
__global__ __launch_bounds__(256) void k_w_cast_t(const float* __restrict__ wq,
                                                  const float* __restrict__ wk,
                                                  const float* __restrict__ wv,
                                                  short* __restrict__ Wt) {
  const int c0 = blockIdx.x * 64, k0 = blockIdx.y * 64, z = blockIdx.z;
  const float* Wm = (z == 0) ? wq : (z == 1) ? wk : wv;
  __shared__ float t[64][65];
  const int tid = threadIdx.x;
#pragma unroll
  for (int l = 0; l < 4; ++l) {
    int f = tid + l * 256;
    int r = f >> 4, c4 = (f & 15) * 4;
    *(float4*)&t[r][c4] = *(const float4*)(Wm + (size_t)(k0 + r) * DOUT + c0 + c4);
  }
  __syncthreads();
  int r2 = tid >> 2, q = tid & 3;
  union { short s[16]; float4 f[2]; } buf;
#pragma unroll
  for (int jj = 0; jj < 16; ++jj) buf.s[jj] = f2bf(t[q * 16 + jj][r2]);
  short* dst = Wt + (size_t)z * (1024 * 768) + (size_t)(c0 + r2) * 768 + k0 + q * 16;
  ((float4*)dst)[0] = buf.f[0];
  ((float4*)dst)[1] = buf.f[1];
}

// ---------------- QKV projection (bf16 MFMA): writes Qb/Kb [h][n][d], Vb [n][1024] ----------------
__global__ __launch_bounds__(256) void k_qkv(const short* __restrict__ xb,
                                             const short* __restrict__ Wt,
                                             const float* __restrict__ bq,
                                             const float* __restrict__ bk,
                                             const float* __restrict__ bv,
                                             short* __restrict__ Qb,
                                             short* __restrict__ Kb,
                                             short* __restrict__ Vb) {
  const int n0 = blockIdx.x * 128;  // 0..3071
  const int i0 = blockIdx.y * 128;
  const int mat = n0 >> 10;
  const int cl = n0 & 1023;
  const float* bias = (mat == 0) ? bq : (mat == 1) ? bk : bv;
  const short* Wm = Wt + (size_t)mat * (1024 * 768);
  const int tid = threadIdx.x, lane = tid & 63, wave = tid >> 6;
  const int ln = lane & 15, quad = lane >> 4, q8 = quad * 8;
  f32x4 acc[2][8];
#pragma unroll
  for (int a = 0; a < 2; ++a)
#pragma unroll
    for (int b = 0; b < 8; ++b) acc[a][b] = (f32x4){0.f, 0.f, 0.f, 0.f};
  const short* a0 = xb + (size_t)(i0 + 32 * wave + ln) * DIN + q8;
  const short* a1 = a0 + 16 * DIN;
  const short* bp = Wm + (size_t)(cl + ln) * DIN + q8;
  for (int ks = 0; ks < 24; ++ks) {
    bf16x8 A0 = *(const bf16x8*)(a0 + 32 * ks);
    bf16x8 A1 = *(const bf16x8*)(a1 + 32 * ks);
#pragma unroll
    for (int nt = 0; nt < 8; ++nt) {
      bf16x8 B = *(const bf16x8*)(bp + (size_t)nt * (16 * DIN) + 32 * ks);
      acc[0][nt] = __builtin_amdgcn_mfma_f32_16x16x32_bf16(A0, B, acc[0][nt], 0, 0, 0);
      acc[1][nt] = __builtin_amdgcn_mfma_f32_16x16x32_bf16(A1, B, acc[1][nt], 0, 0, 0);
    }
  }
#pragma unroll
  for (int rt = 0; rt < 2; ++rt)
#pragma unroll
    for (int nt = 0; nt < 8; ++nt) {
      int cg = cl + 16 * nt + ln;
      float bb = bias[cg];
#pragma unroll
      for (int reg = 0; reg < 4; ++reg) {
        int rr = i0 + 32 * wave + 16 * rt + quad * 4 + reg;
        short s = f2bf(acc[rt][nt][reg] + bb);
        if (mat == 2) {
          Vb[(size_t)rr * 1024 + cg] = s;
        } else {
          int h = cg >> 7, d = cg & 127;
          (mat == 0 ? Qb : Kb)[((size_t)h * NN + rr) * HD + d] = s;
        }
      }
    }
}

// ---------------- transpose Vb -> Vt[h][d][n] bf16 ----------------
__global__ __launch_bounds__(256) void k_v_t(const short* __restrict__ Vb,
                                             short* __restrict__ Vt) {
  const int i0 = blockIdx.x * 64, h = blockIdx.y;
  __shared__ __align__(16) short t[64][136];
  const int tid = threadIdx.x;
#pragma unroll
  for (int l = 0; l < 2; ++l) {
    int f = tid + l * 256;
    int r = f >> 3, c8 = (f & 7) * 16;
    const short* src = Vb + (size_t)(i0 + r) * 1024 + h * HD + c8;
    *(bf16x8*)&t[r][c8] = *(const bf16x8*)src;
    *(bf16x8*)&t[r][c8 + 8] = *(const bf16x8*)(src + 8);
  }
  __syncthreads();
  int d = tid >> 1, half = tid & 1;
  union { short s[32]; float4 f[4]; } buf;
#pragma unroll
  for (int ii = 0; ii < 32; ++ii) buf.s[ii] = t[32 * half + ii][d];
  short* dst = Vt + (size_t)h * (HD * NN) + (size_t)d * NN + i0 + 32 * half;
#pragma unroll
  for (int q = 0; q < 4; ++q) ((float4*)dst)[q] = buf.f[q];
}

// ---------------- gating from bf16 Q/K ----------------
__global__ __launch_bounds__(256) void k_gates(const short* __restrict__ Qb,
                                               const short* __restrict__ Kb,
                                               const float* __restrict__ gqw,
                                               const float* __restrict__ gqb,
                                               const float* __restrict__ gkw,
                                               const float* __restrict__ gkb,
                                               float* __restrict__ GQ,
                                               float* __restrict__ GK) {
  const int i = blockIdx.x;
  const int tid = threadIdx.x;
  float aq[NH] = {}, ak[NH] = {};
  for (int d = tid; d < DOUT; d += 256) {
    int h = d >> 7, dd = d & 127;
    float qv = bf2f(Qb[((size_t)h * NN + i) * HD + dd]);
    float kv = bf2f(Kb[((size_t)h * NN + i) * HD + dd]);
#pragma unroll
    for (int h2 = 0; h2 < NH; ++h2) {
      aq[h2] = fmaf(qv, gqw[d * NH + h2], aq[h2]);
      ak[h2] = fmaf(kv, gkw[d * NH + h2], ak[h2]);
    }
  }
  __shared__ float red8[NH][256];
#pragma unroll
  for (int h = 0; h < NH; ++h) red8[h][tid] = aq[h];
  __syncthreads();
  for (int s = 128; s > 0; s >>= 1) {
    if (tid < s) {
#pragma unroll
      for (int h = 0; h < NH; ++h) red8[h][tid] += red8[h][tid + s];
    }
    __syncthreads();
  }
  if (tid < NH) GQ[i * NH + tid] = tanhf(red8[tid][0] + gqb[tid]);
  __syncthreads();
#pragma unroll
  for (int h = 0; h < NH; ++h) red8[h][tid] = ak[h];
  __syncthreads();
  for (int s = 128; s > 0; s >>= 1) {
    if (tid < s) {
#pragma unroll
      for (int h = 0; h < NH; ++h) red8[h][tid] += red8[h][tid + s];
    }
    __syncthreads();
  }
  if (tid < NH) GK[i * NH + tid] = tanhf(red8[tid][0] + gkb[tid]);
}

// ---------------- fused scores + assemble (LDS-centric epilogue) ----------------
// attn[h,i,j] = S[h,i,j]*(1+gq[i,h]+gk[j,h]) + alpha*S[h,j,i] + beta*motif[h,j,i]
//              + sum_h2 S[h2,i,j]*W[h2,h]
// - motif^T tile staged to LDS (XOR-swizzled float4 slots: bank-balanced staging
//   writes AND epilogue reads); epilogue has ZERO global loads.
// - output staged through oL[32][36] so every global store is a full 128B line
//   (kills R1's 2.1x write amplification + RMW fetches).
// - S^T via JIT mfma(K_i, Q_j), interleaved per-head with S for L1 reuse.
// - XCD patch swizzle: 16x16 block patches -> Q/K working set (~4MB) per XCD L2.
__global__ __launch_bounds__(256, 4) void k_sa(const short* __restrict__ Qb,
                                               const short* __restrict__ Kb,
                                               const int* __restrict__ batch,
                                               const float* __restrict__ motif,
                                               const float* __restrict__ GQ,
                                               const float* __restrict__ GK,
                                               const float* __restrict__ Wh,
                                               const float* __restrict__ alpha_p,
                                               const float* __restrict__ beta_p,
                                               float* __restrict__ ATTN) {
  // ---- XCD patch swizzle: dispatch id -> (bx,by) so each XCD works a 16x16 patch
  const unsigned gid = blockIdx.y * gridDim.x + blockIdx.x;   // dispatch-linear
  const unsigned xcd = gid & 7, idx = gid >> 3;               // idx in [0,512)
  const unsigned P = xcd + 8 * (idx >> 8);                    // patch id [0,16)
  const unsigned r256 = idx & 255;
  const unsigned bx = 16 * (P & 3) + (r256 & 15);
  const unsigned by = 16 * (P >> 2) + (r256 >> 4);
  const int i0 = by * 32, j0 = bx * 32;

  const int tid = threadIdx.x, lane = tid & 63, wave = tid >> 6;
  const int wr = wave >> 1, wc = wave & 1;
  const int ln = lane & 15, quad = lane >> 4, q8 = quad * 8;

  __shared__ float moL[NH][32][32];   // motif^T, XOR-swizzled float4 slots
  __shared__ float oL[32][36];        // output transpose stage
  __shared__ float gqL[32][12], gkL[32][12];
  __shared__ float sW[64];

  const int rA = 16 * wr + quad * 4;   // output row base within tile (+reg)
  const int cA = 16 * wc + ln;         // output col within tile
  const int rowA = i0 + 16 * wr + ln;  // i-side rows (MFMA operand rows)
  const int rowB = j0 + 16 * wc + ln;  // j-side rows

  // ---- issue staging loads early (motif: 8 full-line rows per wave, swizzled) ----
  const int srow = tid >> 3, sslot = tid & 7;
  const int gslot = sslot ^ (srow & 7);   // XOR swizzle: LDS phys slot sslot holds
                                          // global slot gslot of row srow
  float4 mo_stage[NH];
#pragma unroll
  for (int p = 0; p < NH; ++p)
    mo_stage[p] =
        *(const float4*)(motif + ((size_t)p * NN + j0 + srow) * NN + i0 + gslot * 4);
  if (tid < 64) {
    const int half = tid >> 5, r = tid & 31;
    const float* src = (half ? GK : GQ) + (size_t)((half ? j0 : i0) + r) * NH;
    float4 a = *(const float4*)src;
    float4 b = *(const float4*)(src + 4);
    float* dst = half ? &gkL[r][0] : &gqL[r][0];
    *(float4*)dst = a;
    *(float4*)(dst + 4) = b;
    sW[tid] = Wh[tid];
  }
  const int4 bi4 = *(const int4*)(batch + i0 + rA);
  const int bj = batch[j0 + cA];
  const float alpha = alpha_p[0], beta = beta_p[0];

  // ---- S and S^T fragments, interleaved per head (L1 reuse of Q/K rows) ----
  f32x4 accS[NH], accT[NH];
#pragma unroll
  for (int h = 0; h < NH; ++h) {
    accS[h] = (f32x4){0.f, 0.f, 0.f, 0.f};
    accT[h] = (f32x4){0.f, 0.f, 0.f, 0.f};
  }
#pragma unroll
  for (int h = 0; h < NH; ++h) {
    const short* pQA = Qb + ((size_t)h * NN + rowA) * HD + q8;
    const short* pKB = Kb + ((size_t)h * NN + rowB) * HD + q8;
    const short* pKA = Kb + ((size_t)h * NN + rowA) * HD + q8;
    const short* pQB = Qb + ((size_t)h * NN + rowB) * HD + q8;
#pragma unroll
    for (int ks = 0; ks < 4; ++ks) {
      bf16x8 aS = *(const bf16x8*)(pQA + 32 * ks);
      bf16x8 bS = *(const bf16x8*)(pKB + 32 * ks);
      accS[h] = __builtin_amdgcn_mfma_f32_16x16x32_bf16(aS, bS, accS[h], 0, 0, 0);
      bf16x8 aT = *(const bf16x8*)(pKA + 32 * ks);
      bf16x8 bT = *(const bf16x8*)(pQB + 32 * ks);
      accT[h] = __builtin_amdgcn_mfma_f32_16x16x32_bf16(aT, bT, accT[h], 0, 0, 0);
    }
  }
  // mask + scale S (mask symmetric: batch[i]==batch[j])
  int okm[4];
  okm[0] = (bi4.x == bj); okm[1] = (bi4.y == bj);
  okm[2] = (bi4.z == bj); okm[3] = (bi4.w == bj);
#pragma unroll
  for (int reg = 0; reg < 4; ++reg)
#pragma unroll
    for (int h = 0; h < NH; ++h)
      accS[h][reg] = okm[reg] ? accS[h][reg] * SCALEF : NEGF;

  // ---- commit motif to LDS, make all staging visible ----
#pragma unroll
  for (int p = 0; p < NH; ++p)
    *(float4*)&moL[p][srow][sslot * 4] = mo_stage[p];
  __syncthreads();

  // ---- per-head epilogue: pure LDS/ALU, full-line stores ----
  const int orow = tid >> 3, oslot = tid & 7;
  const int mophys = (((rA >> 2) ^ (cA & 7)) << 2);  // swizzled float4 slot offset
#pragma unroll
  for (int h = 0; h < NH; ++h) {
    float w8[NH];
#pragma unroll
    for (int h2 = 0; h2 < NH; ++h2) w8[h2] = sW[h2 * NH + h];
    union { float4 v; float f[4]; } mo4;
    mo4.v = *(const float4*)&moL[h][cA][mophys];
    const float gkj = gkL[cA][h];
    if (h) __syncthreads();  // prior head's oL reads complete
#pragma unroll
    for (int reg = 0; reg < 4; ++reg) {
      float tv = okm[reg] ? accT[h][reg] * SCALEF : NEGF;
      float hm = 0.f;
#pragma unroll
      for (int h2 = 0; h2 < NH; ++h2) hm = fmaf(accS[h2][reg], w8[h2], hm);
      float o = accS[h][reg] * (1.f + gqL[rA + reg][h] + gkj) +
                alpha * tv + beta * mo4.f[reg] + hm;
      oL[rA + reg][cA] = o;
    }
    __syncthreads();
    float4 ov = *(const float4*)&oL[orow][oslot * 4];
    *(float4*)(ATTN + ((size_t)h * NN + i0 + orow) * NN + j0 + oslot * 4) = ov;
  }
}

// ---------------- P@V (bf16 MFMA, constant-shift softmax, K-split 4 + atomics) --------
// probs = exp(x-16)/sum(exp(x-16)): shift-invariant softmax, no stats pass needed.
// Accumulates unnormalized O; per-row sums atomically into SUM; k_outproj divides.
__global__ __launch_bounds__(256) void k_pv(const float* __restrict__ ATTN,
                                            const short* __restrict__ Vt,
                                            float* __restrict__ O,
                                            float* __restrict__ SUM) {
  const int i0 = blockIdx.x * 64;
  const int j0 = blockIdx.y * 512;
  const int h = blockIdx.z;
  const int tid = threadIdx.x, lane = tid & 63, wave = tid >> 6;
  const int ln = lane & 15, quad = lane >> 4, q8 = quad * 8;
  __shared__ __align__(16) short Vl[2][128][40];
  const int row = i0 + 16 * wave + ln;
  const size_t rflat = (size_t)h * NN + row;
  const float* arow = ATTN + rflat * NN;
  const short* vbase = Vt + (size_t)h * (HD * NN);
  f32x4 acc[8];
#pragma unroll
  for (int nt = 0; nt < 8; ++nt) acc[nt] = (f32x4){0.f, 0.f, 0.f, 0.f};
  // prefetch first ATTN chunk
  float4 u1 = *(const float4*)(arow + j0 + q8);
  float4 u2 = *(const float4*)(arow + j0 + q8 + 4);
  float rowsum = 0.f;
  // stage 128 d-rows x 32 j-cols: 2 threads per row, 16 shorts per thread
  const int vr = tid >> 1, vh = (tid & 1) * 16;
  *(bf16x8*)&Vl[0][vr][vh] = *(const bf16x8*)(vbase + (size_t)vr * NN + j0 + vh);
  *(bf16x8*)&Vl[0][vr][vh + 8] = *(const bf16x8*)(vbase + (size_t)vr * NN + j0 + vh + 8);
  __syncthreads();
  int buf = 0;
  for (int jk = j0; jk < j0 + 512; jk += 32, buf ^= 1) {
    const bool more = (jk + 32 < j0 + 512);
    if (more) {
      *(bf16x8*)&Vl[buf ^ 1][vr][vh] =
          *(const bf16x8*)(vbase + (size_t)vr * NN + jk + 32 + vh);
      *(bf16x8*)&Vl[buf ^ 1][vr][vh + 8] =
          *(const bf16x8*)(vbase + (size_t)vr * NN + jk + 32 + vh + 8);
    }
    float4 c1 = u1, c2 = u2;
    if (more) {  // prefetch next ATTN chunk under this step's compute
      u1 = *(const float4*)(arow + jk + 32 + q8);
      u2 = *(const float4*)(arow + jk + 32 + q8 + 4);
    }
    float p0 = __expf(c1.x - EXPSHIFT), p1 = __expf(c1.y - EXPSHIFT);
    float p2 = __expf(c1.z - EXPSHIFT), p3 = __expf(c1.w - EXPSHIFT);
    float p4 = __expf(c2.x - EXPSHIFT), p5 = __expf(c2.y - EXPSHIFT);
    float p6 = __expf(c2.z - EXPSHIFT), p7 = __expf(c2.w - EXPSHIFT);
    rowsum += ((p0 + p1) + (p2 + p3)) + ((p4 + p5) + (p6 + p7));
    bf16x8 a;
    a[0] = f2bf(p0); a[1] = f2bf(p1); a[2] = f2bf(p2); a[3] = f2bf(p3);
    a[4] = f2bf(p4); a[5] = f2bf(p5); a[6] = f2bf(p6); a[7] = f2bf(p7);
#pragma unroll
    for (int nt = 0; nt < 8; ++nt) {
      bf16x8 b = *(const bf16x8*)&Vl[buf][16 * nt + ln][q8];
      acc[nt] = __builtin_amdgcn_mfma_f32_16x16x32_bf16(a, b, acc[nt], 0, 0, 0);
    }
    __syncthreads();
  }
  // per-row sum: reduce across the 4 quads sharing this row
  rowsum += __shfl_xor(rowsum, 16);
  rowsum += __shfl_xor(rowsum, 32);
  if (lane < 16) atomicAdd(&SUM[rflat], rowsum);
#pragma unroll
  for (int nt = 0; nt < 8; ++nt)
#pragma unroll
    for (int reg = 0; reg < 4; ++reg) {
      int rr = i0 + 16 * wave + quad * 4 + reg;
      atomicAdd(&O[(size_t)rr * DOUT + h * HD + 16 * nt + ln], acc[nt][reg]);
    }
}

// ---------------- out-proj SGEMM f32 (K-split + atomics, softmax-normalizing) --------
__device__ __forceinline__ void mm_inner16(const float (*As)[132],
                                           const float (*Bs)[132],
                                           float (&acc)[8][8], int tx, int ty) {
#pragma unroll
  for (int k = 0; k < 16; ++k) {
    float a[8], b[8];
    *(float4*)&a[0] = *(const float4*)&As[k][ty * 8];
    *(float4*)&a[4] = *(const float4*)&As[k][ty * 8 + 4];
    *(float4*)&b[0] = *(const float4*)&Bs[k][tx * 8];
    *(float4*)&b[4] = *(const float4*)&Bs[k][tx * 8 + 4];
#pragma unroll
    for (int m = 0; m < 8; ++m)
#pragma unroll
      for (int n = 0; n < 8; ++n)
        acc[m][n] = fmaf(a[m], b[n], acc[m][n]);
  }
}

__global__ __launch_bounds__(256) void k_outproj(const float* __restrict__ O,
                                                 const float* __restrict__ wo,
                                                 const float* __restrict__ SUM,
                                                 float* __restrict__ YACC) {
  const int n0 = blockIdx.x * 128;
  const int i0 = blockIdx.y * 128;
  const int kbase = blockIdx.z * 256;
  __shared__ __align__(16) float As[16][132];
  __shared__ __align__(16) float Bs[16][132];
  const int tid = threadIdx.x;
  const int tx = tid & 15, ty = tid >> 4;
  float acc[8][8] = {};
  for (int k0 = kbase; k0 < kbase + 256; k0 += 16) {
#pragma unroll
    for (int l = 0; l < 2; ++l) {
      int f = tid + l * 256;
      int row = f >> 2, kc = (f & 3) * 4;
      float4 va = *(const float4*)(O + (size_t)(i0 + row) * DOUT + k0 + kc);
      float sc = 1.0f / SUM[(size_t)((k0 + kc) >> 7) * NN + i0 + row];
      As[kc + 0][row] = va.x * sc; As[kc + 1][row] = va.y * sc;
      As[kc + 2][row] = va.z * sc; As[kc + 3][row] = va.w * sc;
      int kr = f >> 5, c4 = (f & 31) * 4;
      float4 vb = *(const float4*)(wo + (size_t)(k0 + kr) * DIN + n0 + c4);
      *(float4*)&Bs[kr][c4] = vb;
    }
    __syncthreads();
    mm_inner16(As, Bs, acc, tx, ty);
    __syncthreads();
  }
#pragma unroll
  for (int m = 0; m < 8; ++m)
#pragma unroll
    for (int n = 0; n < 8; ++n)
      atomicAdd(&YACC[(size_t)(i0 + ty * 8 + m) * DIN + n0 + tx * 8 + n], acc[m][n]);
}

// ---------------- bias + residual + LayerNorm ----------------
__global__ __launch_bounds__(256) void k_ln(const float* __restrict__ YACC,
                                            const float* __restrict__ x,
                                            const float* __restrict__ wo_b,
                                            const float* __restrict__ g,
                                            const float* __restrict__ b,
                                            float* __restrict__ y) {
  const int i = blockIdx.x;
  const int tid = threadIdx.x;
  float v[3];
#pragma unroll
  for (int t = 0; t < 3; ++t) {
    int cc = tid + t * 256;
    v[t] = YACC[(size_t)i * DIN + cc] + wo_b[cc] + x[(size_t)i * DIN + cc];
  }
  __shared__ float red[256];
  red[tid] = v[0] + v[1] + v[2];
  __syncthreads();
  for (int s = 128; s > 0; s >>= 1) {
    if (tid < s) red[tid] += red[tid + s];
    __syncthreads();
  }
  const float mu = red[0] * (1.0f / DIN);
  __syncthreads();
  float q = 0.f;
#pragma unroll
  for (int t = 0; t < 3; ++t) {
    float d = v[t] - mu;
    q += d * d;
  }
  red[tid] = q;
  __syncthreads();
  for (int s = 128; s > 0; s >>= 1) {
    if (tid < s) red[tid] += red[tid + s];
    __syncthreads();
  }
  const float rs = rsqrtf(red[0] * (1.0f / DIN) + EPSF);
#pragma unroll
  for (int t = 0; t < 3; ++t) {
    int cc = tid + t * 256;
    y[(size_t)i * DIN + cc] = (v[t] - mu) * rs * g[cc] + b[cc];
  }
}

extern "C" void kernel_launch(void* const* d_in, const int* in_sizes, int n_in,
                              void* d_out, int out_size, void* d_ws, size_t ws_size,
                              hipStream_t stream) {
  (void)in_sizes; (void)n_in; (void)out_size; (void)ws_size;
  const float* x       = (const float*)d_in[0];
  const int*   batch   = (const int*)d_in[1];
  const float* motif   = (const float*)d_in[2];
  const float* wq_w    = (const float*)d_in[3];
  const float* wq_b    = (const float*)d_in[4];
  const float* wk_w    = (const float*)d_in[5];
  const float* wk_b    = (const float*)d_in[6];
  const float* wv_w    = (const float*)d_in[7];
  const float* wv_b    = (const float*)d_in[8];
  const float* wo_w    = (const float*)d_in[9];
  const float* wo_b    = (const float*)d_in[10];
  const float* ln_g    = (const float*)d_in[11];
  const float* ln_b    = (const float*)d_in[12];
  const float* alpha_p = (const float*)d_in[13];
  const float* beta_p  = (const float*)d_in[14];
  const float* gq_w    = (const float*)d_in[15];
  const float* gq_b    = (const float*)d_in[16];
  const float* gk_w    = (const float*)d_in[17];
  const float* gk_b    = (const float*)d_in[18];
  const float* headW   = (const float*)d_in[19];

  float* y    = (float*)d_out;
  float* ATTN = (float*)d_out + (size_t)NN * DIN;
  float* ws   = (float*)d_ws;
  float* O    = ws + OFF_O;
  float* YACC = ws + OFF_YACC;
  float* SUM  = ws + OFF_SUM;
  short* Qb   = (short*)(ws + OFF_Q);
  short* Kb   = (short*)(ws + OFF_K);
  short* Vb   = (short*)(ws + OFF_VB);
  short* Vt   = (short*)(ws + OFF_VT);
  short* xb   = (short*)(ws + OFF_XB);
  short* Wt   = (short*)(ws + OFF_WT);
  float* GQ   = ws + OFF_GQ;
  float* GK   = ws + OFF_GK;

  k_zero<<<3600, 256, 0, stream>>>((float4*)(ws + OFF_O));
  k_cast_x<<<1536, 256, 0, stream>>>(x, xb);
  k_w_cast_t<<<dim3(16, 12, 3), 256, 0, stream>>>(wq_w, wk_w, wv_w, Wt);
  k_qkv<<<dim3(24, 16), 256, 0, stream>>>(xb, Wt, wq_b, wk_b, wv_b, Qb, Kb, Vb);
  k_v_t<<<dim3(32, 8), 256, 0, stream>>>(Vb, Vt);
  k_gates<<<NN, 256, 0, stream>>>(Qb, Kb, gq_w, gq_b, gk_w, gk_b, GQ, GK);
  k_sa<<<dim3(64, 64), 256, 0, stream>>>(Qb, Kb, batch, motif, GQ, GK, headW,
                                         alpha_p, beta_p, ATTN);
  k_pv<<<dim3(32, 4, NH), 256, 0, stream>>>(ATTN, Vt, O, SUM);
  k_outproj<<<dim3(6, 16, 4), 256, 0, stream>>>(O, wo_w, SUM, YACC);
  k_ln<<<NN, 256, 0, stream>>>(YACC, x, wo_b, ln_g, ln_b, y);
}

// Round 4
// 721.453 us; speedup vs baseline: 1.2404x; 1.1436x over previous
//
#include <hip/hip_runtime.h>

#define NN    2048
#define DIN   768
#define DOUT  1024
#define NH    8
#define HD    128
#define SCALEF 0.08838834764831845f
#define NEGF  (-1.0e9f)
#define EPSF  1e-5f
#define EXPSHIFT 16.0f

typedef __attribute__((ext_vector_type(4))) float f32x4;
typedef __attribute__((ext_vector_type(8))) short bf16x8;

// workspace layout (float-slot offsets)
#define OFF_O    0                         // 2,097,152 f32
#define OFF_YACC 2097152                   // 1,572,864 f32
#define OFF_SUM  3670016                   // 16,384 f32   (zero region = [0, 3686400))
#define OFF_Q    3686400                   // bf16 [8][2048][128] = 1,048,576 f32 slots
#define OFF_K    4734976
#define OFF_VB   5783552                   // bf16 [2048][1024]
#define OFF_VT   6832128                   // bf16 [8][128][2048]
#define OFF_XB   7880704                   // bf16 [2048][768] = 786,432 f32 slots
#define OFF_WT   8667136                   // bf16 [3][1024][768] = 1,179,648 f32 slots
#define OFF_GQ   9846784
#define OFF_GK   9863168

__device__ __forceinline__ short f2bf(float f) {
  union { float f; unsigned u; } v; v.f = f;
  unsigned r = v.u + 0x7FFF + ((v.u >> 16) & 1);
  return (short)(r >> 16);
}
__device__ __forceinline__ float bf2f(short s) {
  union { unsigned u; float f; } v; v.u = ((unsigned)(unsigned short)s) << 16;
  return v.f;
}

// ---------------- zero O + YACC + SUM ----------------
__global__ __launch_bounds__(256) void k_zero(float4* __restrict__ p) {
  p[(size_t)blockIdx.x * 256 + threadIdx.x] = float4{0.f, 0.f, 0.f, 0.f};
}

// ---------------- cast x -> bf16 ----------------
__global__ __launch_bounds__(256) void k_cast_x(const float* __restrict__ x,
                                                short* __restrict__ xb) {
  int idx = blockIdx.x * 256 + threadIdx.x;  // 393216 float4s
  float4 v = ((const float4*)x)[idx];
  union { short s[4]; float2 f; } u;
  u.s[0] = f2bf(v.x); u.s[1] = f2bf(v.y); u.s[2] = f2bf(v.z); u.s[3] = f2bf(v.w);
  ((float2*)xb)[idx] = u.f;
}

// ---------------- transpose+cast W[768][1024] -> Wt[z][1024][768] bf16 ----------------
__global__ __launch_bounds__(256) void k_w_cast_t(const float* __restrict__ wq,
                                                  const float* __restrict__ wk,
                                                  const float* __restrict__ wv,
                                                  short* __restrict__ Wt) {
  const int c0 = blockIdx.x * 64, k0 = blockIdx.y * 64, z = blockIdx.z;
  const float* Wm = (z == 0) ? wq : (z == 1) ? wk : wv;
  __shared__ float t[64][65];
  const int tid = threadIdx.x;
#pragma unroll
  for (int l = 0; l < 4; ++l) {
    int f = tid + l * 256;
    int r = f >> 4, c4 = (f & 15) * 4;
    *(float4*)&t[r][c4] = *(const float4*)(Wm + (size_t)(k0 + r) * DOUT + c0 + c4);
  }
  __syncthreads();
  int r2 = tid >> 2, q = tid & 3;
  union { short s[16]; float4 f[2]; } buf;
#pragma unroll
  for (int jj = 0; jj < 16; ++jj) buf.s[jj] = f2bf(t[q * 16 + jj][r2]);
  short* dst = Wt + (size_t)z * (1024 * 768) + (size_t)(c0 + r2) * 768 + k0 + q * 16;
  ((float4*)dst)[0] = buf.f[0];
  ((float4*)dst)[1] = buf.f[1];
}

// ---------------- QKV projection (bf16 MFMA): writes Qb/Kb [h][n][d], Vb [n][1024] ----------------
__global__ __launch_bounds__(256) void k_qkv(const short* __restrict__ xb,
                                             const short* __restrict__ Wt,
                                             const float* __restrict__ bq,
                                             const float* __restrict__ bk,
                                             const float* __restrict__ bv,
                                             short* __restrict__ Qb,
                                             short* __restrict__ Kb,
                                             short* __restrict__ Vb) {
  const int n0 = blockIdx.x * 128;  // 0..3071
  const int i0 = blockIdx.y * 128;
  const int mat = n0 >> 10;
  const int cl = n0 & 1023;
  const float* bias = (mat == 0) ? bq : (mat == 1) ? bk : bv;
  const short* Wm = Wt + (size_t)mat * (1024 * 768);
  const int tid = threadIdx.x, lane = tid & 63, wave = tid >> 6;
  const int ln = lane & 15, quad = lane >> 4, q8 = quad * 8;
  f32x4 acc[2][8];
#pragma unroll
  for (int a = 0; a < 2; ++a)
#pragma unroll
    for (int b = 0; b < 8; ++b) acc[a][b] = (f32x4){0.f, 0.f, 0.f, 0.f};
  const short* a0 = xb + (size_t)(i0 + 32 * wave + ln) * DIN + q8;
  const short* a1 = a0 + 16 * DIN;
  const short* bp = Wm + (size_t)(cl + ln) * DIN + q8;
  for (int ks = 0; ks < 24; ++ks) {
    bf16x8 A0 = *(const bf16x8*)(a0 + 32 * ks);
    bf16x8 A1 = *(const bf16x8*)(a1 + 32 * ks);
#pragma unroll
    for (int nt = 0; nt < 8; ++nt) {
      bf16x8 B = *(const bf16x8*)(bp + (size_t)nt * (16 * DIN) + 32 * ks);
      acc[0][nt] = __builtin_amdgcn_mfma_f32_16x16x32_bf16(A0, B, acc[0][nt], 0, 0, 0);
      acc[1][nt] = __builtin_amdgcn_mfma_f32_16x16x32_bf16(A1, B, acc[1][nt], 0, 0, 0);
    }
  }
#pragma unroll
  for (int rt = 0; rt < 2; ++rt)
#pragma unroll
    for (int nt = 0; nt < 8; ++nt) {
      int cg = cl + 16 * nt + ln;
      float bb = bias[cg];
#pragma unroll
      for (int reg = 0; reg < 4; ++reg) {
        int rr = i0 + 32 * wave + 16 * rt + quad * 4 + reg;
        short s = f2bf(acc[rt][nt][reg] + bb);
        if (mat == 2) {
          Vb[(size_t)rr * 1024 + cg] = s;
        } else {
          int h = cg >> 7, d = cg & 127;
          (mat == 0 ? Qb : Kb)[((size_t)h * NN + rr) * HD + d] = s;
        }
      }
    }
}

// ---------------- transpose Vb -> Vt[h][d][n] bf16 ----------------
__global__ __launch_bounds__(256) void k_v_t(const short* __restrict__ Vb,
                                             short* __restrict__ Vt) {
  const int i0 = blockIdx.x * 64, h = blockIdx.y;
  __shared__ __align__(16) short t[64][136];
  const int tid = threadIdx.x;
#pragma unroll
  for (int l = 0; l < 2; ++l) {
    int f = tid + l * 256;
    int r = f >> 3, c8 = (f & 7) * 16;
    const short* src = Vb + (size_t)(i0 + r) * 1024 + h * HD + c8;
    *(bf16x8*)&t[r][c8] = *(const bf16x8*)src;
    *(bf16x8*)&t[r][c8 + 8] = *(const bf16x8*)(src + 8);
  }
  __syncthreads();
  int d = tid >> 1, half = tid & 1;
  union { short s[32]; float4 f[4]; } buf;
#pragma unroll
  for (int ii = 0; ii < 32; ++ii) buf.s[ii] = t[32 * half + ii][d];
  short* dst = Vt + (size_t)h * (HD * NN) + (size_t)d * NN + i0 + 32 * half;
#pragma unroll
  for (int q = 0; q < 4; ++q) ((float4*)dst)[q] = buf.f[q];
}

// ---------------- gating from bf16 Q/K ----------------
__global__ __launch_bounds__(256) void k_gates(const short* __restrict__ Qb,
                                               const short* __restrict__ Kb,
                                               const float* __restrict__ gqw,
                                               const float* __restrict__ gqb,
                                               const float* __restrict__ gkw,
                                               const float* __restrict__ gkb,
                                               float* __restrict__ GQ,
                                               float* __restrict__ GK) {
  const int i = blockIdx.x;
  const int tid = threadIdx.x;
  float aq[NH] = {}, ak[NH] = {};
  for (int d = tid; d < DOUT; d += 256) {
    int h = d >> 7, dd = d & 127;
    float qv = bf2f(Qb[((size_t)h * NN + i) * HD + dd]);
    float kv = bf2f(Kb[((size_t)h * NN + i) * HD + dd]);
#pragma unroll
    for (int h2 = 0; h2 < NH; ++h2) {
      aq[h2] = fmaf(qv, gqw[d * NH + h2], aq[h2]);
      ak[h2] = fmaf(kv, gkw[d * NH + h2], ak[h2]);
    }
  }
  __shared__ float red8[NH][256];
#pragma unroll
  for (int h = 0; h < NH; ++h) red8[h][tid] = aq[h];
  __syncthreads();
  for (int s = 128; s > 0; s >>= 1) {
    if (tid < s) {
#pragma unroll
      for (int h = 0; h < NH; ++h) red8[h][tid] += red8[h][tid + s];
    }
    __syncthreads();
  }
  if (tid < NH) GQ[i * NH + tid] = tanhf(red8[tid][0] + gqb[tid]);
  __syncthreads();
#pragma unroll
  for (int h = 0; h < NH; ++h) red8[h][tid] = ak[h];
  __syncthreads();
  for (int s = 128; s > 0; s >>= 1) {
    if (tid < s) {
#pragma unroll
      for (int h = 0; h < NH; ++h) red8[h][tid] += red8[h][tid + s];
    }
    __syncthreads();
  }
  if (tid < NH) GK[i * NH + tid] = tanhf(red8[tid][0] + gkb[tid]);
}

// ---------------- fused scores + assemble (LDS-staged Q/K pipeline) ----------------
// attn[h,i,j] = S[h,i,j]*(1+gq[i,h]+gk[j,h]) + alpha*S[h,j,i] + beta*motif[h,j,i]
//              + sum_h2 S[h2,i,j]*W[h2,h]
// Main loop: per-head double-buffered LDS staging of Q/K tiles (T14 split: global
// loads -> regs BEFORE the MFMAs, ds_write AFTER, so MFMA lgkm waits never chain
// behind next-tile vmcnt). Fragment reads are ds_read_b128 from padded [32][136]
// rows. Epilogue: 1-deep register pipeline for motif, full-line oL stores (R3's
// write-amp fix), oL aliased onto the dead Q staging buffer (37.1 KB -> 4 blk/CU).
__global__ __launch_bounds__(256, 4) void k_sa(const short* __restrict__ Qb,
                                               const short* __restrict__ Kb,
                                               const int* __restrict__ batch,
                                               const float* __restrict__ motif,
                                               const float* __restrict__ GQ,
                                               const float* __restrict__ GK,
                                               const float* __restrict__ Wh,
                                               const float* __restrict__ alpha_p,
                                               const float* __restrict__ beta_p,
                                               float* __restrict__ ATTN) {
  // ---- XCD patch swizzle: dispatch id -> (bx,by) so each XCD works a 16x16 patch
  const unsigned gid = blockIdx.y * gridDim.x + blockIdx.x;   // dispatch-linear
  const unsigned xcd = gid & 7, idx = gid >> 3;               // idx in [0,512)
  const unsigned P = xcd + 8 * (idx >> 8);                    // patch id [0,16)
  const unsigned r256 = idx & 255;
  const unsigned bx = 16 * (P & 3) + (r256 & 15);
  const unsigned by = 16 * (P >> 2) + (r256 >> 4);
  const int i0 = by * 32, j0 = bx * 32;

  const int tid = threadIdx.x, lane = tid & 63, wave = tid >> 6;
  const int wr = wave >> 1, wc = wave & 1;
  const int ln = lane & 15, quad = lane >> 4, q8 = quad * 8;

  // LDS carve: QK double-buffers + (epilogue-only) oL aliasing Qs[0.. )
  __shared__ __align__(16) char smem[37120];
  auto Qs  = (short (*)[32][136])(smem);            // [2][32][136] bf16
  auto Ks  = (short (*)[32][136])(smem + 17408);    // [2][32][136] bf16
  auto oL  = (float (*)[36])(smem);                 // [32][36] f32 (aliases Qs)
  auto gqL = (float (*)[8])(smem + 34816);          // [32][8]
  auto gkL = (float (*)[8])(smem + 35840);          // [32][8]
  float* sW = (float*)(smem + 36864);               // [64]

  const int rA = 16 * wr + quad * 4;   // output row base within tile (+reg)
  const int cA = 16 * wc + ln;         // output col within tile

  // ---- staging geometry: thread -> (row, 16-short segment) ----
  const int srow = tid >> 3, sseg = (tid & 7) * 16;
  const short* gQ0 = Qb + (size_t)(i0 + srow) * HD + sseg;
  const short* gK0 = Kb + (size_t)(j0 + srow) * HD + sseg;
  const size_t hstep = (size_t)NN * HD;

  // prologue: stage head 0 + gates + Wh
  bf16x8 q0 = *(const bf16x8*)(gQ0);
  bf16x8 q1 = *(const bf16x8*)(gQ0 + 8);
  bf16x8 k0 = *(const bf16x8*)(gK0);
  bf16x8 k1 = *(const bf16x8*)(gK0 + 8);
  if (tid < 64) {
    const int half = tid >> 5, r = tid & 31;
    const float* src = (half ? GK : GQ) + (size_t)((half ? j0 : i0) + r) * NH;
    float4 a = *(const float4*)src;
    float4 b = *(const float4*)(src + 4);
    float* dst = half ? &gkL[r][0] : &gqL[r][0];
    *(float4*)dst = a;
    *(float4*)(dst + 4) = b;
    sW[tid] = Wh[tid];
  }
  const int4 bi4 = *(const int4*)(batch + i0 + rA);
  const int bj = batch[j0 + cA];
  const float alpha = alpha_p[0], beta = beta_p[0];
  *(bf16x8*)&Qs[0][srow][sseg] = q0;
  *(bf16x8*)&Qs[0][srow][sseg + 8] = q1;
  *(bf16x8*)&Ks[0][srow][sseg] = k0;
  *(bf16x8*)&Ks[0][srow][sseg + 8] = k1;
  __syncthreads();

  f32x4 accS[NH], accT[NH];
#pragma unroll
  for (int h = 0; h < NH; ++h) {
    accS[h] = (f32x4){0.f, 0.f, 0.f, 0.f};
    accT[h] = (f32x4){0.f, 0.f, 0.f, 0.f};
  }

#pragma unroll
  for (int h = 0; h < NH; ++h) {
    const int bufc = h & 1;
    bf16x8 nq0, nq1, nk0, nk1;
    if (h < 7) {  // issue next head's global loads FIRST (stay in flight over MFMAs)
      const short* gq_ = gQ0 + (size_t)(h + 1) * hstep;
      const short* gk_ = gK0 + (size_t)(h + 1) * hstep;
      nq0 = *(const bf16x8*)(gq_);
      nq1 = *(const bf16x8*)(gq_ + 8);
      nk0 = *(const bf16x8*)(gk_);
      nk1 = *(const bf16x8*)(gk_ + 8);
    }
#pragma unroll
    for (int ks = 0; ks < 4; ++ks) {
      bf16x8 aS = *(const bf16x8*)&Qs[bufc][16 * wr + ln][ks * 32 + q8];
      bf16x8 bS = *(const bf16x8*)&Ks[bufc][16 * wc + ln][ks * 32 + q8];
      accS[h] = __builtin_amdgcn_mfma_f32_16x16x32_bf16(aS, bS, accS[h], 0, 0, 0);
      bf16x8 aT = *(const bf16x8*)&Ks[bufc][16 * wr + ln][ks * 32 + q8];
      bf16x8 bT = *(const bf16x8*)&Qs[bufc][16 * wc + ln][ks * 32 + q8];
      accT[h] = __builtin_amdgcn_mfma_f32_16x16x32_bf16(aT, bT, accT[h], 0, 0, 0);
    }
    if (h < 7) {  // commit next head's tiles AFTER this head's MFMAs
      *(bf16x8*)&Qs[bufc ^ 1][srow][sseg] = nq0;
      *(bf16x8*)&Qs[bufc ^ 1][srow][sseg + 8] = nq1;
      *(bf16x8*)&Ks[bufc ^ 1][srow][sseg] = nk0;
      *(bf16x8*)&Ks[bufc ^ 1][srow][sseg + 8] = nk1;
    }
    __syncthreads();
  }

  // mask + scale S (mask symmetric: batch[i]==batch[j])
  int okm[4];
  okm[0] = (bi4.x == bj); okm[1] = (bi4.y == bj);
  okm[2] = (bi4.z == bj); okm[3] = (bi4.w == bj);
#pragma unroll
  for (int reg = 0; reg < 4; ++reg)
#pragma unroll
    for (int h = 0; h < NH; ++h)
      accS[h][reg] = okm[reg] ? accS[h][reg] * SCALEF : NEGF;

  // ---- per-head epilogue: motif reg-pipeline, LDS transpose, full-line stores ----
  const int orow = tid >> 3, oslot = (tid & 7) * 4;
  union { float4 v; float f[4]; } moc, mon;
  moc.v = *(const float4*)(motif + ((size_t)(j0 + cA)) * NN + i0 + rA);  // h=0
#pragma unroll
  for (int h = 0; h < NH; ++h) {
    if (h < 7)
      mon.v = *(const float4*)(motif + ((size_t)(h + 1) * NN + j0 + cA) * NN + i0 + rA);
    float w8[NH];
#pragma unroll
    for (int h2 = 0; h2 < NH; ++h2) w8[h2] = sW[h2 * NH + h];
    const float gkj = gkL[cA][h];
#pragma unroll
    for (int reg = 0; reg < 4; ++reg) {
      float tv = okm[reg] ? accT[h][reg] * SCALEF : NEGF;
      float hm = 0.f;
#pragma unroll
      for (int h2 = 0; h2 < NH; ++h2) hm = fmaf(accS[h2][reg], w8[h2], hm);
      float o = accS[h][reg] * (1.f + gqL[rA + reg][h] + gkj) +
                alpha * tv + beta * moc.f[reg] + hm;
      oL[rA + reg][cA] = o;
    }
    __syncthreads();
    float4 ov = *(const float4*)&oL[orow][oslot];
    *(float4*)(ATTN + ((size_t)h * NN + i0 + orow) * NN + j0 + oslot) = ov;
    if (h < 7) __syncthreads();
    moc.v = mon.v;
  }
}

// ---------------- P@V (bf16 MFMA, constant-shift softmax, K-split 4 + atomics) --------
// probs = exp(x-16)/sum(exp(x-16)): shift-invariant softmax, no stats pass needed.
// T14 split: V chunk loads -> regs before MFMAs, ds_write after, 1 barrier/chunk.
__global__ __launch_bounds__(256) void k_pv(const float* __restrict__ ATTN,
                                            const short* __restrict__ Vt,
                                            float* __restrict__ O,
                                            float* __restrict__ SUM) {
  const int i0 = blockIdx.x * 64;
  const int j0 = blockIdx.y * 512;
  const int h = blockIdx.z;
  const int tid = threadIdx.x, lane = tid & 63, wave = tid >> 6;
  const int ln = lane & 15, quad = lane >> 4, q8 = quad * 8;
  __shared__ __align__(16) short Vl[2][128][40];
  const int row = i0 + 16 * wave + ln;
  const size_t rflat = (size_t)h * NN + row;
  const float* arow = ATTN + rflat * NN;
  const short* vbase = Vt + (size_t)h * (HD * NN);
  f32x4 acc[8];
#pragma unroll
  for (int nt = 0; nt < 8; ++nt) acc[nt] = (f32x4){0.f, 0.f, 0.f, 0.f};
  // prefetch first ATTN chunk
  float4 u1 = *(const float4*)(arow + j0 + q8);
  float4 u2 = *(const float4*)(arow + j0 + q8 + 4);
  float rowsum = 0.f;
  // stage 128 d-rows x 32 j-cols: 2 threads per row, 16 shorts per thread
  const int vr = tid >> 1, vh = (tid & 1) * 16;
  *(bf16x8*)&Vl[0][vr][vh] = *(const bf16x8*)(vbase + (size_t)vr * NN + j0 + vh);
  *(bf16x8*)&Vl[0][vr][vh + 8] = *(const bf16x8*)(vbase + (size_t)vr * NN + j0 + vh + 8);
  __syncthreads();
  int buf = 0;
  for (int jk = j0; jk < j0 + 512; jk += 32, buf ^= 1) {
    const bool more = (jk + 32 < j0 + 512);
    bf16x8 nv0, nv1;
    if (more) {  // next V chunk -> regs (issued before all compute)
      nv0 = *(const bf16x8*)(vbase + (size_t)vr * NN + jk + 32 + vh);
      nv1 = *(const bf16x8*)(vbase + (size_t)vr * NN + jk + 32 + vh + 8);
    }
    float4 c1 = u1, c2 = u2;
    if (more) {  // prefetch next ATTN chunk under this step's compute
      u1 = *(const float4*)(arow + jk + 32 + q8);
      u2 = *(const float4*)(arow + jk + 32 + q8 + 4);
    }
    float p0 = __expf(c1.x - EXPSHIFT), p1 = __expf(c1.y - EXPSHIFT);
    float p2 = __expf(c1.z - EXPSHIFT), p3 = __expf(c1.w - EXPSHIFT);
    float p4 = __expf(c2.x - EXPSHIFT), p5 = __expf(c2.y - EXPSHIFT);
    float p6 = __expf(c2.z - EXPSHIFT), p7 = __expf(c2.w - EXPSHIFT);
    rowsum += ((p0 + p1) + (p2 + p3)) + ((p4 + p5) + (p6 + p7));
    bf16x8 a;
    a[0] = f2bf(p0); a[1] = f2bf(p1); a[2] = f2bf(p2); a[3] = f2bf(p3);
    a[4] = f2bf(p4); a[5] = f2bf(p5); a[6] = f2bf(p6); a[7] = f2bf(p7);
#pragma unroll
    for (int nt = 0; nt < 8; ++nt) {
      bf16x8 b = *(const bf16x8*)&Vl[buf][16 * nt + ln][q8];
      acc[nt] = __builtin_amdgcn_mfma_f32_16x16x32_bf16(a, b, acc[nt], 0, 0, 0);
    }
    if (more) {  // commit next V chunk AFTER this chunk's MFMAs
      *(bf16x8*)&Vl[buf ^ 1][vr][vh] = nv0;
      *(bf16x8*)&Vl[buf ^ 1][vr][vh + 8] = nv1;
    }
    __syncthreads();
  }
  // per-row sum: reduce across the 4 quads sharing this row
  rowsum += __shfl_xor(rowsum, 16);
  rowsum += __shfl_xor(rowsum, 32);
  if (lane < 16) atomicAdd(&SUM[rflat], rowsum);
#pragma unroll
  for (int nt = 0; nt < 8; ++nt)
#pragma unroll
    for (int reg = 0; reg < 4; ++reg) {
      int rr = i0 + 16 * wave + quad * 4 + reg;
      atomicAdd(&O[(size_t)rr * DOUT + h * HD + 16 * nt + ln], acc[nt][reg]);
    }
}

// ---------------- out-proj SGEMM f32 (K-split + atomics, softmax-normalizing) --------
__device__ __forceinline__ void mm_inner16(const float (*As)[132],
                                           const float (*Bs)[132],
                                           float (&acc)[8][8], int tx, int ty) {
#pragma unroll
  for (int k = 0; k < 16; ++k) {
    float a[8], b[8];
    *(float4*)&a[0] = *(const float4*)&As[k][ty * 8];
    *(float4*)&a[4] = *(const float4*)&As[k][ty * 8 + 4];
    *(float4*)&b[0] = *(const float4*)&Bs[k][tx * 8];
    *(float4*)&b[4] = *(const float4*)&Bs[k][tx * 8 + 4];
#pragma unroll
    for (int m = 0; m < 8; ++m)
#pragma unroll
      for (int n = 0; n < 8; ++n)
        acc[m][n] = fmaf(a[m], b[n], acc[m][n]);
  }
}

__global__ __launch_bounds__(256) void k_outproj(const float* __restrict__ O,
                                                 const float* __restrict__ wo,
                                                 const float* __restrict__ SUM,
                                                 float* __restrict__ YACC) {
  const int n0 = blockIdx.x * 128;
  const int i0 = blockIdx.y * 128;
  const int kbase = blockIdx.z * 256;
  __shared__ __align__(16) float As[16][132];
  __shared__ __align__(16) float Bs[16][132];
  const int tid = threadIdx.x;
  const int tx = tid & 15, ty = tid >> 4;
  float acc[8][8] = {};
  for (int k0 = kbase; k0 < kbase + 256; k0 += 16) {
#pragma unroll
    for (int l = 0; l < 2; ++l) {
      int f = tid + l * 256;
      int row = f >> 2, kc = (f & 3) * 4;
      float4 va = *(const float4*)(O + (size_t)(i0 + row) * DOUT + k0 + kc);
      float sc = 1.0f / SUM[(size_t)((k0 + kc) >> 7) * NN + i0 + row];
      As[kc + 0][row] = va.x * sc; As[kc + 1][row] = va.y * sc;
      As[kc + 2][row] = va.z * sc; As[kc + 3][row] = va.w * sc;
      int kr = f >> 5, c4 = (f & 31) * 4;
      float4 vb = *(const float4*)(wo + (size_t)(k0 + kr) * DIN + n0 + c4);
      *(float4*)&Bs[kr][c4] = vb;
    }
    __syncthreads();
    mm_inner16(As, Bs, acc, tx, ty);
    __syncthreads();
  }
#pragma unroll
  for (int m = 0; m < 8; ++m)
#pragma unroll
    for (int n = 0; n < 8; ++n)
      atomicAdd(&YACC[(size_t)(i0 + ty * 8 + m) * DIN + n0 + tx * 8 + n], acc[m][n]);
}

// ---------------- bias + residual + LayerNorm ----------------
__global__ __launch_bounds__(256) void k_ln(const float* __restrict__ YACC,
                                            const float* __restrict__ x,
                                            const float* __restrict__ wo_b,
                                            const float* __restrict__ g,
                                            const float* __restrict__ b,
                                            float* __restrict__ y) {
  const int i = blockIdx.x;
  const int tid = threadIdx.x;
  float v[3];
#pragma unroll
  for (int t = 0; t < 3; ++t) {
    int cc = tid + t * 256;
    v[t] = YACC[(size_t)i * DIN + cc] + wo_b[cc] + x[(size_t)i * DIN + cc];
  }
  __shared__ float red[256];
  red[tid] = v[0] + v[1] + v[2];
  __syncthreads();
  for (int s = 128; s > 0; s >>= 1) {
    if (tid < s) red[tid] += red[tid + s];
    __syncthreads();
  }
  const float mu = red[0] * (1.0f / DIN);
  __syncthreads();
  float q = 0.f;
#pragma unroll
  for (int t = 0; t < 3; ++t) {
    float d = v[t] - mu;
    q += d * d;
  }
  red[tid] = q;
  __syncthreads();
  for (int s = 128; s > 0; s >>= 1) {
    if (tid < s) red[tid] += red[tid + s];
    __syncthreads();
  }
  const float rs = rsqrtf(red[0] * (1.0f / DIN) + EPSF);
#pragma unroll
  for (int t = 0; t < 3; ++t) {
    int cc = tid + t * 256;
    y[(size_t)i * DIN + cc] = (v[t] - mu) * rs * g[cc] + b[cc];
  }
}

extern "C" void kernel_launch(void* const* d_in, const int* in_sizes, int n_in,
                              void* d_out, int out_size, void* d_ws, size_t ws_size,
                              hipStream_t stream) {
  (void)in_sizes; (void)n_in; (void)out_size; (void)ws_size;
  const float* x       = (const float*)d_in[0];
  const int*   batch   = (const int*)d_in[1];
  const float* motif   = (const float*)d_in[2];
  const float* wq_w    = (const float*)d_in[3];
  const float* wq_b    = (const float*)d_in[4];
  const float* wk_w    = (const float*)d_in[5];
  const float* wk_b    = (const float*)d_in[6];
  const float* wv_w    = (const float*)d_in[7];
  const float* wv_b    = (const float*)d_in[8];
  const float* wo_w    = (const float*)d_in[9];
  const float* wo_b    = (const float*)d_in[10];
  const float* ln_g    = (const float*)d_in[11];
  const float* ln_b    = (const float*)d_in[12];
  const float* alpha_p = (const float*)d_in[13];
  const float* beta_p  = (const float*)d_in[14];
  const float* gq_w    = (const float*)d_in[15];
  const float* gq_b    = (const float*)d_in[16];
  const float* gk_w    = (const float*)d_in[17];
  const float* gk_b    = (const float*)d_in[18];
  const float* headW   = (const float*)d_in[19];

  float* y    = (float*)d_out;
  float* ATTN = (float*)d_out + (size_t)NN * DIN;
  float* ws   = (float*)d_ws;
  float* O    = ws + OFF_O;
  float* YACC = ws + OFF_YACC;
  float* SUM  = ws + OFF_SUM;
  short* Qb   = (short*)(ws + OFF_Q);
  short* Kb   = (short*)(ws + OFF_K);
  short* Vb   = (short*)(ws + OFF_VB);
  short* Vt   = (short*)(ws + OFF_VT);
  short* xb   = (short*)(ws + OFF_XB);
  short* Wt   = (short*)(ws + OFF_WT);
  float* GQ   = ws + OFF_GQ;
  float* GK   = ws + OFF_GK;

  k_zero<<<3600, 256, 0, stream>>>((float4*)(ws + OFF_O));
  k_cast_x<<<1536, 256, 0, stream>>>(x, xb);
  k_w_cast_t<<<dim3(16, 12, 3), 256, 0, stream>>>(wq_w, wk_w, wv_w, Wt);
  k_qkv<<<dim3(24, 16), 256, 0, stream>>>(xb, Wt, wq_b, wk_b, wv_b, Qb, Kb, Vb);
  k_v_t<<<dim3(32, 8), 256, 0, stream>>>(Vb, Vt);
  k_gates<<<NN, 256, 0, stream>>>(Qb, Kb, gq_w, gq_b, gk_w, gk_b, GQ, GK);
  k_sa<<<dim3(64, 64), 256, 0, stream>>>(Qb, Kb, batch, motif, GQ, GK, headW,
                                         alpha_p, beta_p, ATTN);
  k_pv<<<dim3(32, 4, NH), 256, 0, stream>>>(ATTN, Vt, O, SUM);
  k_outproj<<<dim3(6, 16, 4), 256, 0, stream>>>(O, wo_w, SUM, YACC);
  k_ln<<<NN, 256, 0, stream>>>(YACC, x, wo_b, ln_g, ln_b, y);
}

// Round 5
// 613.570 us; speedup vs baseline: 1.4585x; 1.1758x over previous
//
#include <hip/hip_runtime.h>

#define NN    2048
#define DIN   768
#define DOUT  1024
#define NH    8
#define HD    128
#define SCALEF 0.08838834764831845f
#define NEGF  (-1.0e9f)
#define EPSF  1e-5f
#define EXPSHIFT 16.0f

typedef __attribute__((ext_vector_type(4))) float f32x4;
typedef __attribute__((ext_vector_type(8))) short bf16x8;

// workspace layout (float-slot offsets)
#define OFF_OBF  0                         // bf16 O [2048][1024]   = 1,048,576 f32 slots
#define OFF_WOT  1048576                   // bf16 wo^T [768][1024] =   393,216 f32 slots
#define OFF_YACC 1441792                   // f32 [2048][768]       = 1,572,864 slots (ends 3,014,656)
#define OFF_Q    3686400                   // bf16 [8][2048][128] = 1,048,576 f32 slots
#define OFF_K    4734976
#define OFF_VB   5783552                   // bf16 [2048][1024]
#define OFF_VT   6832128                   // bf16 [8][128][2048]
#define OFF_XB   7880704                   // bf16 [2048][768]
#define OFF_WT   8667136                   // bf16 [3][1024][768]
#define OFF_GQ   9846784
#define OFF_GK   9863168

__device__ __forceinline__ short f2bf(float f) {
  union { float f; unsigned u; } v; v.f = f;
  unsigned r = v.u + 0x7FFF + ((v.u >> 16) & 1);
  return (short)(r >> 16);
}
__device__ __forceinline__ float bf2f(short s) {
  union { unsigned u; float f; } v; v.u = ((unsigned)(unsigned short)s) << 16;
  return v.f;
}

// ---------------- cast x -> bf16 ----------------
__global__ __launch_bounds__(256) void k_cast_x(const float* __restrict__ x,
                                                short* __restrict__ xb) {
  int idx = blockIdx.x * 256 + threadIdx.x;  // 393216 float4s
  float4 v = ((const float4*)x)[idx];
  union { short s[4]; float2 f; } u;
  u.s[0] = f2bf(v.x); u.s[1] = f2bf(v.y); u.s[2] = f2bf(v.z); u.s[3] = f2bf(v.w);
  ((float2*)xb)[idx] = u.f;
}

// ---------------- transpose+cast W[768][1024] -> Wt[z][1024][768] bf16 ----------------
__global__ __launch_bounds__(256) void k_w_cast_t(const float* __restrict__ wq,
                                                  const float* __restrict__ wk,
                                                  const float* __restrict__ wv,
                                                  short* __restrict__ Wt) {
  const int c0 = blockIdx.x * 64, k0 = blockIdx.y * 64, z = blockIdx.z;
  const float* Wm = (z == 0) ? wq : (z == 1) ? wk : wv;
  __shared__ float t[64][65];
  const int tid = threadIdx.x;
#pragma unroll
  for (int l = 0; l < 4; ++l) {
    int f = tid + l * 256;
    int r = f >> 4, c4 = (f & 15) * 4;
    *(float4*)&t[r][c4] = *(const float4*)(Wm + (size_t)(k0 + r) * DOUT + c0 + c4);
  }
  __syncthreads();
  int r2 = tid >> 2, q = tid & 3;
  union { short s[16]; float4 f[2]; } buf;
#pragma unroll
  for (int jj = 0; jj < 16; ++jj) buf.s[jj] = f2bf(t[q * 16 + jj][r2]);
  short* dst = Wt + (size_t)z * (1024 * 768) + (size_t)(c0 + r2) * 768 + k0 + q * 16;
  ((float4*)dst)[0] = buf.f[0];
  ((float4*)dst)[1] = buf.f[1];
}

// ---------------- transpose+cast wo[1024][768] -> wot[768][1024] bf16 ----------------
__global__ __launch_bounds__(256) void k_wo_t(const float* __restrict__ wo,
                                              short* __restrict__ wot) {
  const int c0 = blockIdx.x * 64;   // over 768 (12 tiles)
  const int k0 = blockIdx.y * 64;   // over 1024 (16 tiles)
  __shared__ float t[64][65];
  const int tid = threadIdx.x;
#pragma unroll
  for (int l = 0; l < 4; ++l) {
    int f = tid + l * 256;
    int r = f >> 4, c4 = (f & 15) * 4;
    *(float4*)&t[r][c4] = *(const float4*)(wo + (size_t)(k0 + r) * DIN + c0 + c4);
  }
  __syncthreads();
  int r2 = tid >> 2, q = tid & 3;
  union { short s[16]; float4 f[2]; } buf;
#pragma unroll
  for (int jj = 0; jj < 16; ++jj) buf.s[jj] = f2bf(t[q * 16 + jj][r2]);
  short* dst = wot + (size_t)(c0 + r2) * DOUT + k0 + q * 16;
  ((float4*)dst)[0] = buf.f[0];
  ((float4*)dst)[1] = buf.f[1];
}

// ---------------- QKV projection (bf16 MFMA): writes Qb/Kb [h][n][d], Vb [n][1024] ----------------
__global__ __launch_bounds__(256) void k_qkv(const short* __restrict__ xb,
                                             const short* __restrict__ Wt,
                                             const float* __restrict__ bq,
                                             const float* __restrict__ bk,
                                             const float* __restrict__ bv,
                                             short* __restrict__ Qb,
                                             short* __restrict__ Kb,
                                             short* __restrict__ Vb) {
  const int n0 = blockIdx.x * 128;  // 0..3071
  const int i0 = blockIdx.y * 128;
  const int mat = n0 >> 10;
  const int cl = n0 & 1023;
  const float* bias = (mat == 0) ? bq : (mat == 1) ? bk : bv;
  const short* Wm = Wt + (size_t)mat * (1024 * 768);
  const int tid = threadIdx.x, lane = tid & 63, wave = tid >> 6;
  const int ln = lane & 15, quad = lane >> 4, q8 = quad * 8;
  f32x4 acc[2][8];
#pragma unroll
  for (int a = 0; a < 2; ++a)
#pragma unroll
    for (int b = 0; b < 8; ++b) acc[a][b] = (f32x4){0.f, 0.f, 0.f, 0.f};
  const short* a0 = xb + (size_t)(i0 + 32 * wave + ln) * DIN + q8;
  const short* a1 = a0 + 16 * DIN;
  const short* bp = Wm + (size_t)(cl + ln) * DIN + q8;
  for (int ks = 0; ks < 24; ++ks) {
    bf16x8 A0 = *(const bf16x8*)(a0 + 32 * ks);
    bf16x8 A1 = *(const bf16x8*)(a1 + 32 * ks);
#pragma unroll
    for (int nt = 0; nt < 8; ++nt) {
      bf16x8 B = *(const bf16x8*)(bp + (size_t)nt * (16 * DIN) + 32 * ks);
      acc[0][nt] = __builtin_amdgcn_mfma_f32_16x16x32_bf16(A0, B, acc[0][nt], 0, 0, 0);
      acc[1][nt] = __builtin_amdgcn_mfma_f32_16x16x32_bf16(A1, B, acc[1][nt], 0, 0, 0);
    }
  }
#pragma unroll
  for (int rt = 0; rt < 2; ++rt)
#pragma unroll
    for (int nt = 0; nt < 8; ++nt) {
      int cg = cl + 16 * nt + ln;
      float bb = bias[cg];
#pragma unroll
      for (int reg = 0; reg < 4; ++reg) {
        int rr = i0 + 32 * wave + 16 * rt + quad * 4 + reg;
        short s = f2bf(acc[rt][nt][reg] + bb);
        if (mat == 2) {
          Vb[(size_t)rr * 1024 + cg] = s;
        } else {
          int h = cg >> 7, d = cg & 127;
          (mat == 0 ? Qb : Kb)[((size_t)h * NN + rr) * HD + d] = s;
        }
      }
    }
}

// ---------------- transpose Vb -> Vt[h][d][n] bf16 ----------------
__global__ __launch_bounds__(256) void k_v_t(const short* __restrict__ Vb,
                                             short* __restrict__ Vt) {
  const int i0 = blockIdx.x * 64, h = blockIdx.y;
  __shared__ __align__(16) short t[64][136];
  const int tid = threadIdx.x;
#pragma unroll
  for (int l = 0; l < 2; ++l) {
    int f = tid + l * 256;
    int r = f >> 3, c8 = (f & 7) * 16;
    const short* src = Vb + (size_t)(i0 + r) * 1024 + h * HD + c8;
    *(bf16x8*)&t[r][c8] = *(const bf16x8*)src;
    *(bf16x8*)&t[r][c8 + 8] = *(const bf16x8*)(src + 8);
  }
  __syncthreads();
  int d = tid >> 1, half = tid & 1;
  union { short s[32]; float4 f[4]; } buf;
#pragma unroll
  for (int ii = 0; ii < 32; ++ii) buf.s[ii] = t[32 * half + ii][d];
  short* dst = Vt + (size_t)h * (HD * NN) + (size_t)d * NN + i0 + 32 * half;
#pragma unroll
  for (int q = 0; q < 4; ++q) ((float4*)dst)[q] = buf.f[q];
}

// ---------------- gating from bf16 Q/K ----------------
__global__ __launch_bounds__(256) void k_gates(const short* __restrict__ Qb,
                                               const short* __restrict__ Kb,
                                               const float* __restrict__ gqw,
                                               const float* __restrict__ gqb,
                                               const float* __restrict__ gkw,
                                               const float* __restrict__ gkb,
                                               float* __restrict__ GQ,
                                               float* __restrict__ GK) {
  const int i = blockIdx.x;
  const int tid = threadIdx.x;
  float aq[NH] = {}, ak[NH] = {};
  for (int d = tid; d < DOUT; d += 256) {
    int h = d >> 7, dd = d & 127;
    float qv = bf2f(Qb[((size_t)h * NN + i) * HD + dd]);
    float kv = bf2f(Kb[((size_t)h * NN + i) * HD + dd]);
#pragma unroll
    for (int h2 = 0; h2 < NH; ++h2) {
      aq[h2] = fmaf(qv, gqw[d * NH + h2], aq[h2]);
      ak[h2] = fmaf(kv, gkw[d * NH + h2], ak[h2]);
    }
  }
  __shared__ float red8[NH][256];
#pragma unroll
  for (int h = 0; h < NH; ++h) red8[h][tid] = aq[h];
  __syncthreads();
  for (int s = 128; s > 0; s >>= 1) {
    if (tid < s) {
#pragma unroll
      for (int h = 0; h < NH; ++h) red8[h][tid] += red8[h][tid + s];
    }
    __syncthreads();
  }
  if (tid < NH) GQ[i * NH + tid] = tanhf(red8[tid][0] + gqb[tid]);
  __syncthreads();
#pragma unroll
  for (int h = 0; h < NH; ++h) red8[h][tid] = ak[h];
  __syncthreads();
  for (int s = 128; s > 0; s >>= 1) {
    if (tid < s) {
#pragma unroll
      for (int h = 0; h < NH; ++h) red8[h][tid] += red8[h][tid + s];
    }
    __syncthreads();
  }
  if (tid < NH) GK[i * NH + tid] = tanhf(red8[tid][0] + gkb[tid]);
}

// ---------------- fused scores + assemble (LDS-staged Q/K pipeline) ----------------
__global__ __launch_bounds__(256, 4) void k_sa(const short* __restrict__ Qb,
                                               const short* __restrict__ Kb,
                                               const int* __restrict__ batch,
                                               const float* __restrict__ motif,
                                               const float* __restrict__ GQ,
                                               const float* __restrict__ GK,
                                               const float* __restrict__ Wh,
                                               const float* __restrict__ alpha_p,
                                               const float* __restrict__ beta_p,
                                               float* __restrict__ ATTN) {
  // ---- XCD patch swizzle: dispatch id -> (bx,by) so each XCD works a 16x16 patch
  const unsigned gid = blockIdx.y * gridDim.x + blockIdx.x;   // dispatch-linear
  const unsigned xcd = gid & 7, idx = gid >> 3;               // idx in [0,512)
  const unsigned P = xcd + 8 * (idx >> 8);                    // patch id [0,16)
  const unsigned r256 = idx & 255;
  const unsigned bx = 16 * (P & 3) + (r256 & 15);
  const unsigned by = 16 * (P >> 2) + (r256 >> 4);
  const int i0 = by * 32, j0 = bx * 32;

  const int tid = threadIdx.x, lane = tid & 63, wave = tid >> 6;
  const int wr = wave >> 1, wc = wave & 1;
  const int ln = lane & 15, quad = lane >> 4, q8 = quad * 8;

  // LDS carve: QK double-buffers + (epilogue-only) oL aliasing Qs[0.. )
  __shared__ __align__(16) char smem[37120];
  auto Qs  = (short (*)[32][136])(smem);            // [2][32][136] bf16
  auto Ks  = (short (*)[32][136])(smem + 17408);    // [2][32][136] bf16
  auto oL  = (float (*)[36])(smem);                 // [32][36] f32 (aliases Qs)
  auto gqL = (float (*)[8])(smem + 34816);          // [32][8]
  auto gkL = (float (*)[8])(smem + 35840);          // [32][8]
  float* sW = (float*)(smem + 36864);               // [64]

  const int rA = 16 * wr + quad * 4;   // output row base within tile (+reg)
  const int cA = 16 * wc + ln;         // output col within tile

  // ---- staging geometry: thread -> (row, 16-short segment) ----
  const int srow = tid >> 3, sseg = (tid & 7) * 16;
  const short* gQ0 = Qb + (size_t)(i0 + srow) * HD + sseg;
  const short* gK0 = Kb + (size_t)(j0 + srow) * HD + sseg;
  const size_t hstep = (size_t)NN * HD;

  // prologue: stage head 0 + gates + Wh
  bf16x8 q0 = *(const bf16x8*)(gQ0);
  bf16x8 q1 = *(const bf16x8*)(gQ0 + 8);
  bf16x8 k0 = *(const bf16x8*)(gK0);
  bf16x8 k1 = *(const bf16x8*)(gK0 + 8);
  if (tid < 64) {
    const int half = tid >> 5, r = tid & 31;
    const float* src = (half ? GK : GQ) + (size_t)((half ? j0 : i0) + r) * NH;
    float4 a = *(const float4*)src;
    float4 b = *(const float4*)(src + 4);
    float* dst = half ? &gkL[r][0] : &gqL[r][0];
    *(float4*)dst = a;
    *(float4*)(dst + 4) = b;
    sW[tid] = Wh[tid];
  }
  const int4 bi4 = *(const int4*)(batch + i0 + rA);
  const int bj = batch[j0 + cA];
  const float alpha = alpha_p[0], beta = beta_p[0];
  *(bf16x8*)&Qs[0][srow][sseg] = q0;
  *(bf16x8*)&Qs[0][srow][sseg + 8] = q1;
  *(bf16x8*)&Ks[0][srow][sseg] = k0;
  *(bf16x8*)&Ks[0][srow][sseg + 8] = k1;
  __syncthreads();

  f32x4 accS[NH], accT[NH];
#pragma unroll
  for (int h = 0; h < NH; ++h) {
    accS[h] = (f32x4){0.f, 0.f, 0.f, 0.f};
    accT[h] = (f32x4){0.f, 0.f, 0.f, 0.f};
  }

#pragma unroll
  for (int h = 0; h < NH; ++h) {
    const int bufc = h & 1;
    bf16x8 nq0, nq1, nk0, nk1;
    if (h < 7) {  // issue next head's global loads FIRST (stay in flight over MFMAs)
      const short* gq_ = gQ0 + (size_t)(h + 1) * hstep;
      const short* gk_ = gK0 + (size_t)(h + 1) * hstep;
      nq0 = *(const bf16x8*)(gq_);
      nq1 = *(const bf16x8*)(gq_ + 8);
      nk0 = *(const bf16x8*)(gk_);
      nk1 = *(const bf16x8*)(gk_ + 8);
    }
#pragma unroll
    for (int ks = 0; ks < 4; ++ks) {
      bf16x8 aS = *(const bf16x8*)&Qs[bufc][16 * wr + ln][ks * 32 + q8];
      bf16x8 bS = *(const bf16x8*)&Ks[bufc][16 * wc + ln][ks * 32 + q8];
      accS[h] = __builtin_amdgcn_mfma_f32_16x16x32_bf16(aS, bS, accS[h], 0, 0, 0);
      bf16x8 aT = *(const bf16x8*)&Ks[bufc][16 * wr + ln][ks * 32 + q8];
      bf16x8 bT = *(const bf16x8*)&Qs[bufc][16 * wc + ln][ks * 32 + q8];
      accT[h] = __builtin_amdgcn_mfma_f32_16x16x32_bf16(aT, bT, accT[h], 0, 0, 0);
    }
    if (h < 7) {  // commit next head's tiles AFTER this head's MFMAs
      *(bf16x8*)&Qs[bufc ^ 1][srow][sseg] = nq0;
      *(bf16x8*)&Qs[bufc ^ 1][srow][sseg + 8] = nq1;
      *(bf16x8*)&Ks[bufc ^ 1][srow][sseg] = nk0;
      *(bf16x8*)&Ks[bufc ^ 1][srow][sseg + 8] = nk1;
    }
    __syncthreads();
  }

  // mask + scale S (mask symmetric: batch[i]==batch[j])
  int okm[4];
  okm[0] = (bi4.x == bj); okm[1] = (bi4.y == bj);
  okm[2] = (bi4.z == bj); okm[3] = (bi4.w == bj);
#pragma unroll
  for (int reg = 0; reg < 4; ++reg)
#pragma unroll
    for (int h = 0; h < NH; ++h)
      accS[h][reg] = okm[reg] ? accS[h][reg] * SCALEF : NEGF;

  // ---- per-head epilogue: motif reg-pipeline, LDS transpose, full-line stores ----
  const int orow = tid >> 3, oslot = (tid & 7) * 4;
  union { float4 v; float f[4]; } moc, mon;
  moc.v = *(const float4*)(motif + ((size_t)(j0 + cA)) * NN + i0 + rA);  // h=0
#pragma unroll
  for (int h = 0; h < NH; ++h) {
    if (h < 7)
      mon.v = *(const float4*)(motif + ((size_t)(h + 1) * NN + j0 + cA) * NN + i0 + rA);
    float w8[NH];
#pragma unroll
    for (int h2 = 0; h2 < NH; ++h2) w8[h2] = sW[h2 * NH + h];
    const float gkj = gkL[cA][h];
#pragma unroll
    for (int reg = 0; reg < 4; ++reg) {
      float tv = okm[reg] ? accT[h][reg] * SCALEF : NEGF;
      float hm = 0.f;
#pragma unroll
      for (int h2 = 0; h2 < NH; ++h2) hm = fmaf(accS[h2][reg], w8[h2], hm);
      float o = accS[h][reg] * (1.f + gqL[rA + reg][h] + gkj) +
                alpha * tv + beta * moc.f[reg] + hm;
      oL[rA + reg][cA] = o;
    }
    __syncthreads();
    float4 ov = *(const float4*)&oL[orow][oslot];
    *(float4*)(ATTN + ((size_t)h * NN + i0 + orow) * NN + j0 + oslot) = ov;
    if (h < 7) __syncthreads();
    moc.v = mon.v;
  }
}

// ---------------- P@V: full-row blocks, in-kernel softmax-normalize, bf16 O --------
// probs = exp(x-16)/sum_row exp(x-16). One block per (head, 64 rows) covering the
// FULL j-range -> exact rowsum in-block, NO atomics, O written once as bf16.
// head = blockIdx.x & 7 -> one head per XCD (round-robin dispatch): that head's
// V (512KB) stays L2-resident instead of being re-fetched by 32 blocks.
__global__ __launch_bounds__(256) void k_pv(const float* __restrict__ ATTN,
                                            const short* __restrict__ Vt,
                                            short* __restrict__ Obf) {
  const int b = blockIdx.x;       // 0..255
  const int h = b & 7;            // head -> XCD
  const int i0 = (b >> 3) * 64;   // row strip
  const int tid = threadIdx.x, lane = tid & 63, wave = tid >> 6;
  const int ln = lane & 15, quad = lane >> 4, q8 = quad * 8;
  __shared__ __align__(16) short Vl[2][128][40];
  const int row = i0 + 16 * wave + ln;
  const float* arow = ATTN + ((size_t)h * NN + row) * NN;
  const short* vbase = Vt + (size_t)h * (HD * NN);
  f32x4 acc[8];
#pragma unroll
  for (int nt = 0; nt < 8; ++nt) acc[nt] = (f32x4){0.f, 0.f, 0.f, 0.f};
  // prefetch first ATTN chunk
  float4 u1 = *(const float4*)(arow + q8);
  float4 u2 = *(const float4*)(arow + q8 + 4);
  float rowsum = 0.f;
  // stage 128 d-rows x 32 j-cols: 2 threads per row, 16 shorts per thread
  const int vr = tid >> 1, vh = (tid & 1) * 16;
  *(bf16x8*)&Vl[0][vr][vh] = *(const bf16x8*)(vbase + (size_t)vr * NN + vh);
  *(bf16x8*)&Vl[0][vr][vh + 8] = *(const bf16x8*)(vbase + (size_t)vr * NN + vh + 8);
  __syncthreads();
  int buf = 0;
  for (int jk = 0; jk < NN; jk += 32, buf ^= 1) {
    const bool more = (jk + 32 < NN);
    bf16x8 nv0, nv1;
    if (more) {  // next V chunk -> regs (issued before all compute)
      nv0 = *(const bf16x8*)(vbase + (size_t)vr * NN + jk + 32 + vh);
      nv1 = *(const bf16x8*)(vbase + (size_t)vr * NN + jk + 32 + vh + 8);
    }
    float4 c1 = u1, c2 = u2;
    if (more) {  // prefetch next ATTN chunk under this step's compute
      u1 = *(const float4*)(arow + jk + 32 + q8);
      u2 = *(const float4*)(arow + jk + 32 + q8 + 4);
    }
    float p0 = __expf(c1.x - EXPSHIFT), p1 = __expf(c1.y - EXPSHIFT);
    float p2 = __expf(c1.z - EXPSHIFT), p3 = __expf(c1.w - EXPSHIFT);
    float p4 = __expf(c2.x - EXPSHIFT), p5 = __expf(c2.y - EXPSHIFT);
    float p6 = __expf(c2.z - EXPSHIFT), p7 = __expf(c2.w - EXPSHIFT);
    rowsum += ((p0 + p1) + (p2 + p3)) + ((p4 + p5) + (p6 + p7));
    bf16x8 a;
    a[0] = f2bf(p0); a[1] = f2bf(p1); a[2] = f2bf(p2); a[3] = f2bf(p3);
    a[4] = f2bf(p4); a[5] = f2bf(p5); a[6] = f2bf(p6); a[7] = f2bf(p7);
#pragma unroll
    for (int nt = 0; nt < 8; ++nt) {
      bf16x8 bb = *(const bf16x8*)&Vl[buf][16 * nt + ln][q8];
      acc[nt] = __builtin_amdgcn_mfma_f32_16x16x32_bf16(a, bb, acc[nt], 0, 0, 0);
    }
    if (more) {  // commit next V chunk AFTER this chunk's MFMAs
      *(bf16x8*)&Vl[buf ^ 1][vr][vh] = nv0;
      *(bf16x8*)&Vl[buf ^ 1][vr][vh + 8] = nv1;
    }
    __syncthreads();
  }
  // full rowsum: reduce across the 4 quads sharing this row (lanes same ln)
  rowsum += __shfl_xor(rowsum, 16);
  rowsum += __shfl_xor(rowsum, 32);
  const float inv = 1.0f / rowsum;  // for row (16*wave + ln)
  float invr[4];
#pragma unroll
  for (int reg = 0; reg < 4; ++reg)
    invr[reg] = __shfl(inv, quad * 4 + reg);  // inv for acc row quad*4+reg
  // normalize -> bf16 -> LDS (reuse Vl) -> coalesced 256B row-segment stores
  short* oS = (short*)Vl;  // flat [64][136]
#pragma unroll
  for (int nt = 0; nt < 8; ++nt)
#pragma unroll
    for (int reg = 0; reg < 4; ++reg)
      oS[(16 * wave + quad * 4 + reg) * 136 + 16 * nt + ln] =
          f2bf(acc[nt][reg] * invr[reg]);
  __syncthreads();
  const int orow = tid >> 2, oseg = (tid & 3) * 32;
  short* dst = Obf + (size_t)(i0 + orow) * DOUT + h * HD + oseg;
  const short* srcl = oS + orow * 136 + oseg;
#pragma unroll
  for (int q = 0; q < 4; ++q)
    *(bf16x8*)(dst + q * 8) = *(const bf16x8*)(srcl + q * 8);
}

// ---------------- out-proj bf16 MFMA GEMM: Y = Obf @ wo (K=1024 in-block) --------
__global__ __launch_bounds__(256) void k_outproj(const short* __restrict__ Obf,
                                                 const short* __restrict__ wot,
                                                 float* __restrict__ YACC) {
  const int n0 = blockIdx.x * 128;  // 768 cols -> 6
  const int i0 = blockIdx.y * 64;   // 2048 rows -> 32
  const int tid = threadIdx.x, lane = tid & 63, wave = tid >> 6;
  const int ln = lane & 15, quad = lane >> 4, q8 = quad * 8;
  f32x4 acc[8];
#pragma unroll
  for (int nt = 0; nt < 8; ++nt) acc[nt] = (f32x4){0.f, 0.f, 0.f, 0.f};
  const short* a0 = Obf + (size_t)(i0 + 16 * wave + ln) * DOUT + q8;
  const short* bp = wot + (size_t)(n0 + ln) * DOUT + q8;
  for (int ks = 0; ks < 32; ++ks) {
    bf16x8 A0 = *(const bf16x8*)(a0 + 32 * ks);
#pragma unroll
    for (int nt = 0; nt < 8; ++nt) {
      bf16x8 B = *(const bf16x8*)(bp + (size_t)nt * (16 * DOUT) + 32 * ks);
      acc[nt] = __builtin_amdgcn_mfma_f32_16x16x32_bf16(A0, B, acc[nt], 0, 0, 0);
    }
  }
#pragma unroll
  for (int nt = 0; nt < 8; ++nt) {
    int cg = n0 + 16 * nt + ln;
#pragma unroll
    for (int reg = 0; reg < 4; ++reg) {
      int rr = i0 + 16 * wave + quad * 4 + reg;
      YACC[(size_t)rr * DIN + cg] = acc[nt][reg];
    }
  }
}

// ---------------- bias + residual + LayerNorm ----------------
__global__ __launch_bounds__(256) void k_ln(const float* __restrict__ YACC,
                                            const float* __restrict__ x,
                                            const float* __restrict__ wo_b,
                                            const float* __restrict__ g,
                                            const float* __restrict__ b,
                                            float* __restrict__ y) {
  const int i = blockIdx.x;
  const int tid = threadIdx.x;
  float v[3];
#pragma unroll
  for (int t = 0; t < 3; ++t) {
    int cc = tid + t * 256;
    v[t] = YACC[(size_t)i * DIN + cc] + wo_b[cc] + x[(size_t)i * DIN + cc];
  }
  __shared__ float red[256];
  red[tid] = v[0] + v[1] + v[2];
  __syncthreads();
  for (int s = 128; s > 0; s >>= 1) {
    if (tid < s) red[tid] += red[tid + s];
    __syncthreads();
  }
  const float mu = red[0] * (1.0f / DIN);
  __syncthreads();
  float q = 0.f;
#pragma unroll
  for (int t = 0; t < 3; ++t) {
    float d = v[t] - mu;
    q += d * d;
  }
  red[tid] = q;
  __syncthreads();
  for (int s = 128; s > 0; s >>= 1) {
    if (tid < s) red[tid] += red[tid + s];
    __syncthreads();
  }
  const float rs = rsqrtf(red[0] * (1.0f / DIN) + EPSF);
#pragma unroll
  for (int t = 0; t < 3; ++t) {
    int cc = tid + t * 256;
    y[(size_t)i * DIN + cc] = (v[t] - mu) * rs * g[cc] + b[cc];
  }
}

extern "C" void kernel_launch(void* const* d_in, const int* in_sizes, int n_in,
                              void* d_out, int out_size, void* d_ws, size_t ws_size,
                              hipStream_t stream) {
  (void)in_sizes; (void)n_in; (void)out_size; (void)ws_size;
  const float* x       = (const float*)d_in[0];
  const int*   batch   = (const int*)d_in[1];
  const float* motif   = (const float*)d_in[2];
  const float* wq_w    = (const float*)d_in[3];
  const float* wq_b    = (const float*)d_in[4];
  const float* wk_w    = (const float*)d_in[5];
  const float* wk_b    = (const float*)d_in[6];
  const float* wv_w    = (const float*)d_in[7];
  const float* wv_b    = (const float*)d_in[8];
  const float* wo_w    = (const float*)d_in[9];
  const float* wo_b    = (const float*)d_in[10];
  const float* ln_g    = (const float*)d_in[11];
  const float* ln_b    = (const float*)d_in[12];
  const float* alpha_p = (const float*)d_in[13];
  const float* beta_p  = (const float*)d_in[14];
  const float* gq_w    = (const float*)d_in[15];
  const float* gq_b    = (const float*)d_in[16];
  const float* gk_w    = (const float*)d_in[17];
  const float* gk_b    = (const float*)d_in[18];
  const float* headW   = (const float*)d_in[19];

  float* y    = (float*)d_out;
  float* ATTN = (float*)d_out + (size_t)NN * DIN;
  float* ws   = (float*)d_ws;
  short* Obf  = (short*)(ws + OFF_OBF);
  short* wot  = (short*)(ws + OFF_WOT);
  float* YACC = ws + OFF_YACC;
  short* Qb   = (short*)(ws + OFF_Q);
  short* Kb   = (short*)(ws + OFF_K);
  short* Vb   = (short*)(ws + OFF_VB);
  short* Vt   = (short*)(ws + OFF_VT);
  short* xb   = (short*)(ws + OFF_XB);
  short* Wt   = (short*)(ws + OFF_WT);
  float* GQ   = ws + OFF_GQ;
  float* GK   = ws + OFF_GK;

  k_cast_x<<<1536, 256, 0, stream>>>(x, xb);
  k_w_cast_t<<<dim3(16, 12, 3), 256, 0, stream>>>(wq_w, wk_w, wv_w, Wt);
  k_wo_t<<<dim3(12, 16), 256, 0, stream>>>(wo_w, wot);
  k_qkv<<<dim3(24, 16), 256, 0, stream>>>(xb, Wt, wq_b, wk_b, wv_b, Qb, Kb, Vb);
  k_v_t<<<dim3(32, 8), 256, 0, stream>>>(Vb, Vt);
  k_gates<<<NN, 256, 0, stream>>>(Qb, Kb, gq_w, gq_b, gk_w, gk_b, GQ, GK);
  k_sa<<<dim3(64, 64), 256, 0, stream>>>(Qb, Kb, batch, motif, GQ, GK, headW,
                                         alpha_p, beta_p, ATTN);
  k_pv<<<256, 256, 0, stream>>>(ATTN, Vt, Obf);
  k_outproj<<<dim3(6, 32), 256, 0, stream>>>(Obf, wot, YACC);
  k_ln<<<NN, 256, 0, stream>>>(YACC, x, wo_b, ln_g, ln_b, y);
}

// Round 6
// 552.657 us; speedup vs baseline: 1.6193x; 1.1102x over previous
//
#include <hip/hip_runtime.h>

#define NN    2048
#define DIN   768
#define DOUT  1024
#define NH    8
#define HD    128
#define SCALEF 0.08838834764831845f
#define NEGF  (-1.0e9f)
#define EPSF  1e-5f
#define EXPSHIFT 16.0f

typedef __attribute__((ext_vector_type(4))) float f32x4;
typedef __attribute__((ext_vector_type(8))) short bf16x8;

// workspace layout (float-slot offsets)
#define OFF_OBF  0                         // bf16 O [2048][1024]
#define OFF_WOT  1048576                   // bf16 wo^T [768][1024]
#define OFF_YACC 1441792                   // f32 [2048][768]
#define OFF_Q    3686400                   // bf16 [8][2048][128]
#define OFF_K    4734976
#define OFF_VB   5783552                   // bf16 [2048][1024]
#define OFF_VT   6832128                   // bf16 [8][128][2048]
#define OFF_XB   7880704                   // bf16 [2048][768]
#define OFF_WT   8667136                   // bf16 [3][1024][768]
#define OFF_GQ   9846784
#define OFF_GK   9863168

__device__ __forceinline__ short f2bf(float f) {
  union { float f; unsigned u; } v; v.f = f;
  unsigned r = v.u + 0x7FFF + ((v.u >> 16) & 1);
  return (short)(r >> 16);
}
__device__ __forceinline__ float bf2f(short s) {
  union { unsigned u; float f; } v; v.u = ((unsigned)(unsigned short)s) << 16;
  return v.f;
}

// ---------------- fused preprocessing: cast_x | w_cast_t | wo_t ----------------
__global__ __launch_bounds__(256) void k_prep(const float* __restrict__ x,
                                              short* __restrict__ xb,
                                              const float* __restrict__ wq,
                                              const float* __restrict__ wk,
                                              const float* __restrict__ wv,
                                              short* __restrict__ Wt,
                                              const float* __restrict__ wo,
                                              short* __restrict__ wot) {
  const int bid = blockIdx.x;
  const int tid = threadIdx.x;
  if (bid < 1536) {  // cast x -> bf16
    int idx = bid * 256 + tid;
    float4 v = ((const float4*)x)[idx];
    union { short s[4]; float2 f; } u;
    u.s[0] = f2bf(v.x); u.s[1] = f2bf(v.y); u.s[2] = f2bf(v.z); u.s[3] = f2bf(v.w);
    ((float2*)xb)[idx] = u.f;
    return;
  }
  __shared__ float t[64][65];
  if (bid < 2112) {  // W[768][1024] -> Wt[z][1024][768] bf16
    const int w = bid - 1536;
    const int z = w / 192, rem = w % 192;
    const int c0 = (rem % 16) * 64, k0 = (rem / 16) * 64;
    const float* Wm = (z == 0) ? wq : (z == 1) ? wk : wv;
#pragma unroll
    for (int l = 0; l < 4; ++l) {
      int f = tid + l * 256;
      int r = f >> 4, c4 = (f & 15) * 4;
      *(float4*)&t[r][c4] = *(const float4*)(Wm + (size_t)(k0 + r) * DOUT + c0 + c4);
    }
    __syncthreads();
    int r2 = tid >> 2, q = tid & 3;
    union { short s[16]; float4 f[2]; } buf;
#pragma unroll
    for (int jj = 0; jj < 16; ++jj) buf.s[jj] = f2bf(t[q * 16 + jj][r2]);
    short* dst = Wt + (size_t)z * (1024 * 768) + (size_t)(c0 + r2) * 768 + k0 + q * 16;
    ((float4*)dst)[0] = buf.f[0];
    ((float4*)dst)[1] = buf.f[1];
  } else {  // wo[1024][768] -> wot[768][1024] bf16
    const int w = bid - 2112;
    const int c0 = (w % 12) * 64, k0 = (w / 12) * 64;
#pragma unroll
    for (int l = 0; l < 4; ++l) {
      int f = tid + l * 256;
      int r = f >> 4, c4 = (f & 15) * 4;
      *(float4*)&t[r][c4] = *(const float4*)(wo + (size_t)(k0 + r) * DIN + c0 + c4);
    }
    __syncthreads();
    int r2 = tid >> 2, q = tid & 3;
    union { short s[16]; float4 f[2]; } buf;
#pragma unroll
    for (int jj = 0; jj < 16; ++jj) buf.s[jj] = f2bf(t[q * 16 + jj][r2]);
    short* dst = wot + (size_t)(c0 + r2) * DOUT + k0 + q * 16;
    ((float4*)dst)[0] = buf.f[0];
    ((float4*)dst)[1] = buf.f[1];
  }
}

// ---------------- QKV projection (bf16 MFMA) ----------------
__global__ __launch_bounds__(256) void k_qkv(const short* __restrict__ xb,
                                             const short* __restrict__ Wt,
                                             const float* __restrict__ bq,
                                             const float* __restrict__ bk,
                                             const float* __restrict__ bv,
                                             short* __restrict__ Qb,
                                             short* __restrict__ Kb,
                                             short* __restrict__ Vb) {
  const int n0 = blockIdx.x * 128;  // 0..3071
  const int i0 = blockIdx.y * 128;
  const int mat = n0 >> 10;
  const int cl = n0 & 1023;
  const float* bias = (mat == 0) ? bq : (mat == 1) ? bk : bv;
  const short* Wm = Wt + (size_t)mat * (1024 * 768);
  const int tid = threadIdx.x, lane = tid & 63, wave = tid >> 6;
  const int ln = lane & 15, quad = lane >> 4, q8 = quad * 8;
  f32x4 acc[2][8];
#pragma unroll
  for (int a = 0; a < 2; ++a)
#pragma unroll
    for (int b = 0; b < 8; ++b) acc[a][b] = (f32x4){0.f, 0.f, 0.f, 0.f};
  const short* a0 = xb + (size_t)(i0 + 32 * wave + ln) * DIN + q8;
  const short* a1 = a0 + 16 * DIN;
  const short* bp = Wm + (size_t)(cl + ln) * DIN + q8;
  for (int ks = 0; ks < 24; ++ks) {
    bf16x8 A0 = *(const bf16x8*)(a0 + 32 * ks);
    bf16x8 A1 = *(const bf16x8*)(a1 + 32 * ks);
#pragma unroll
    for (int nt = 0; nt < 8; ++nt) {
      bf16x8 B = *(const bf16x8*)(bp + (size_t)nt * (16 * DIN) + 32 * ks);
      acc[0][nt] = __builtin_amdgcn_mfma_f32_16x16x32_bf16(A0, B, acc[0][nt], 0, 0, 0);
      acc[1][nt] = __builtin_amdgcn_mfma_f32_16x16x32_bf16(A1, B, acc[1][nt], 0, 0, 0);
    }
  }
#pragma unroll
  for (int rt = 0; rt < 2; ++rt)
#pragma unroll
    for (int nt = 0; nt < 8; ++nt) {
      int cg = cl + 16 * nt + ln;
      float bb = bias[cg];
#pragma unroll
      for (int reg = 0; reg < 4; ++reg) {
        int rr = i0 + 32 * wave + 16 * rt + quad * 4 + reg;
        short s = f2bf(acc[rt][nt][reg] + bb);
        if (mat == 2) {
          Vb[(size_t)rr * 1024 + cg] = s;
        } else {
          int h = cg >> 7, d = cg & 127;
          (mat == 0 ? Qb : Kb)[((size_t)h * NN + rr) * HD + d] = s;
        }
      }
    }
}

// ---------------- fused: gates (bid<2048) | Vb->Vt transpose (bid>=2048) --------
__global__ __launch_bounds__(256) void k_vtg(const short* __restrict__ Qb,
                                             const short* __restrict__ Kb,
                                             const float* __restrict__ gqw,
                                             const float* __restrict__ gqb,
                                             const float* __restrict__ gkw,
                                             const float* __restrict__ gkb,
                                             float* __restrict__ GQ,
                                             float* __restrict__ GK,
                                             const short* __restrict__ Vb,
                                             short* __restrict__ Vt) {
  const int bid = blockIdx.x;
  const int tid = threadIdx.x;
  __shared__ __align__(16) char smem[17408];
  if (bid < 2048) {  // gates
    auto red8 = (float (*)[256])(smem);  // [8][256]
    const int i = bid;
    float aq[NH] = {}, ak[NH] = {};
    for (int d = tid; d < DOUT; d += 256) {
      int h = d >> 7, dd = d & 127;
      float qv = bf2f(Qb[((size_t)h * NN + i) * HD + dd]);
      float kv = bf2f(Kb[((size_t)h * NN + i) * HD + dd]);
#pragma unroll
      for (int h2 = 0; h2 < NH; ++h2) {
        aq[h2] = fmaf(qv, gqw[d * NH + h2], aq[h2]);
        ak[h2] = fmaf(kv, gkw[d * NH + h2], ak[h2]);
      }
    }
#pragma unroll
    for (int h = 0; h < NH; ++h) red8[h][tid] = aq[h];
    __syncthreads();
    for (int s = 128; s > 0; s >>= 1) {
      if (tid < s) {
#pragma unroll
        for (int h = 0; h < NH; ++h) red8[h][tid] += red8[h][tid + s];
      }
      __syncthreads();
    }
    if (tid < NH) GQ[i * NH + tid] = tanhf(red8[tid][0] + gqb[tid]);
    __syncthreads();
#pragma unroll
    for (int h = 0; h < NH; ++h) red8[h][tid] = ak[h];
    __syncthreads();
    for (int s = 128; s > 0; s >>= 1) {
      if (tid < s) {
#pragma unroll
        for (int h = 0; h < NH; ++h) red8[h][tid] += red8[h][tid + s];
      }
      __syncthreads();
    }
    if (tid < NH) GK[i * NH + tid] = tanhf(red8[tid][0] + gkb[tid]);
  } else {  // Vb -> Vt[h][d][n]
    auto t = (short (*)[136])(smem);  // [64][136]
    const int w = bid - 2048;
    const int i0 = (w & 31) * 64, h = w >> 5;
#pragma unroll
    for (int l = 0; l < 2; ++l) {
      int f = tid + l * 256;
      int r = f >> 3, c8 = (f & 7) * 16;
      const short* src = Vb + (size_t)(i0 + r) * 1024 + h * HD + c8;
      *(bf16x8*)&t[r][c8] = *(const bf16x8*)src;
      *(bf16x8*)&t[r][c8 + 8] = *(const bf16x8*)(src + 8);
    }
    __syncthreads();
    int d = tid >> 1, half = tid & 1;
    union { short s[32]; float4 f[4]; } buf;
#pragma unroll
    for (int ii = 0; ii < 32; ++ii) buf.s[ii] = t[32 * half + ii][d];
    short* dst = Vt + (size_t)h * (HD * NN) + (size_t)d * NN + i0 + 32 * half;
#pragma unroll
    for (int q = 0; q < 4; ++q) ((float4*)dst)[q] = buf.f[q];
  }
}

// ---------------- fused scores + assemble (2-head-ahead LDS pipeline) ----------------
__global__ __launch_bounds__(256, 4) void k_sa(const short* __restrict__ Qb,
                                               const short* __restrict__ Kb,
                                               const int* __restrict__ batch,
                                               const float* __restrict__ motif,
                                               const float* __restrict__ GQ,
                                               const float* __restrict__ GK,
                                               const float* __restrict__ Wh,
                                               const float* __restrict__ alpha_p,
                                               const float* __restrict__ beta_p,
                                               float* __restrict__ ATTN) {
  // XCD patch swizzle: 16x16 block patches per XCD
  const unsigned gid = blockIdx.y * gridDim.x + blockIdx.x;
  const unsigned xcd = gid & 7, idx = gid >> 3;
  const unsigned P = xcd + 8 * (idx >> 8);
  const unsigned r256 = idx & 255;
  const unsigned bx = 16 * (P & 3) + (r256 & 15);
  const unsigned by = 16 * (P >> 2) + (r256 >> 4);
  const int i0 = by * 32, j0 = bx * 32;

  const int tid = threadIdx.x, lane = tid & 63, wave = tid >> 6;
  const int wr = wave >> 1, wc = wave & 1;
  const int ln = lane & 15, quad = lane >> 4, q8 = quad * 8;

  __shared__ __align__(16) char smem[38400];
  auto Qs  = (short (*)[32][136])(smem);            // [2][32][136] bf16
  auto Ks  = (short (*)[32][136])(smem + 17408);    // [2][32][136] bf16
  auto oL  = (float (*)[36])(smem);                 // [32][36] f32 (aliases Qs)
  auto gqL = (float (*)[12])(smem + 34816);         // [32][12]
  auto gkL = (float (*)[12])(smem + 36352);         // [32][12]
  float* sW = (float*)(smem + 37888);               // [64]

  const int rA = 16 * wr + quad * 4;
  const int cA = 16 * wc + ln;

  const int srow = tid >> 3, sseg = (tid & 7) * 16;
  const short* gQ0 = Qb + (size_t)(i0 + srow) * HD + sseg;
  const short* gK0 = Kb + (size_t)(j0 + srow) * HD + sseg;
  const size_t hstep = (size_t)NN * HD;

  // prologue: stage head0 to LDS, preload head1 into regs (stays in flight 1 iter)
  {
    bf16x8 q0 = *(const bf16x8*)(gQ0);
    bf16x8 q1 = *(const bf16x8*)(gQ0 + 8);
    bf16x8 k0 = *(const bf16x8*)(gK0);
    bf16x8 k1 = *(const bf16x8*)(gK0 + 8);
    *(bf16x8*)&Qs[0][srow][sseg] = q0;
    *(bf16x8*)&Qs[0][srow][sseg + 8] = q1;
    *(bf16x8*)&Ks[0][srow][sseg] = k0;
    *(bf16x8*)&Ks[0][srow][sseg + 8] = k1;
  }
  bf16x8 cq0 = *(const bf16x8*)(gQ0 + hstep);
  bf16x8 cq1 = *(const bf16x8*)(gQ0 + hstep + 8);
  bf16x8 ck0 = *(const bf16x8*)(gK0 + hstep);
  bf16x8 ck1 = *(const bf16x8*)(gK0 + hstep + 8);
  if (tid < 64) {
    const int half = tid >> 5, r = tid & 31;
    const float* src = (half ? GK : GQ) + (size_t)((half ? j0 : i0) + r) * NH;
    float4 a = *(const float4*)src;
    float4 b = *(const float4*)(src + 4);
    float* dst = half ? &gkL[r][0] : &gqL[r][0];
    *(float4*)dst = a;
    *(float4*)(dst + 4) = b;
    sW[tid] = Wh[tid];
  }
  const int4 bi4 = *(const int4*)(batch + i0 + rA);
  const int bj = batch[j0 + cA];
  const float alpha = alpha_p[0], beta = beta_p[0];
  __syncthreads();

  f32x4 accS[NH], accT[NH];
#pragma unroll
  for (int h = 0; h < NH; ++h) {
    accS[h] = (f32x4){0.f, 0.f, 0.f, 0.f};
    accT[h] = (f32x4){0.f, 0.f, 0.f, 0.f};
  }

#pragma unroll
  for (int h = 0; h < NH; ++h) {
    const int bufc = h & 1;
    bf16x8 nq0, nq1, nk0, nk1;
    if (h < 6) {  // issue head h+2's loads (in flight for ~1 full iteration)
      const short* gq_ = gQ0 + (size_t)(h + 2) * hstep;
      const short* gk_ = gK0 + (size_t)(h + 2) * hstep;
      nq0 = *(const bf16x8*)(gq_);
      nq1 = *(const bf16x8*)(gq_ + 8);
      nk0 = *(const bf16x8*)(gk_);
      nk1 = *(const bf16x8*)(gk_ + 8);
    }
#pragma unroll
    for (int ks = 0; ks < 4; ++ks) {
      bf16x8 aS = *(const bf16x8*)&Qs[bufc][16 * wr + ln][ks * 32 + q8];
      bf16x8 bS = *(const bf16x8*)&Ks[bufc][16 * wc + ln][ks * 32 + q8];
      accS[h] = __builtin_amdgcn_mfma_f32_16x16x32_bf16(aS, bS, accS[h], 0, 0, 0);
      bf16x8 aT = *(const bf16x8*)&Ks[bufc][16 * wr + ln][ks * 32 + q8];
      bf16x8 bT = *(const bf16x8*)&Qs[bufc][16 * wc + ln][ks * 32 + q8];
      accT[h] = __builtin_amdgcn_mfma_f32_16x16x32_bf16(aT, bT, accT[h], 0, 0, 0);
    }
    if (h < 7) {  // commit head h+1 (loaded last iteration) to the other buffer
      *(bf16x8*)&Qs[bufc ^ 1][srow][sseg] = cq0;
      *(bf16x8*)&Qs[bufc ^ 1][srow][sseg + 8] = cq1;
      *(bf16x8*)&Ks[bufc ^ 1][srow][sseg] = ck0;
      *(bf16x8*)&Ks[bufc ^ 1][srow][sseg + 8] = ck1;
    }
    __syncthreads();
    if (h < 6) { cq0 = nq0; cq1 = nq1; ck0 = nk0; ck1 = nk1; }
  }

  // mask + scale S
  int okm[4];
  okm[0] = (bi4.x == bj); okm[1] = (bi4.y == bj);
  okm[2] = (bi4.z == bj); okm[3] = (bi4.w == bj);
#pragma unroll
  for (int reg = 0; reg < 4; ++reg)
#pragma unroll
    for (int h = 0; h < NH; ++h)
      accS[h][reg] = okm[reg] ? accS[h][reg] * SCALEF : NEGF;

  // per-head epilogue: motif 2-ahead reg pipeline, LDS transpose, full-line stores
  const int orow = tid >> 3, oslot = (tid & 7) * 4;
  union { float4 v; float f[4]; } moc, mon, mo2;
  moc.v = *(const float4*)(motif + ((size_t)(j0 + cA)) * NN + i0 + rA);
  mon.v = *(const float4*)(motif + ((size_t)(NN + j0 + cA)) * NN + i0 + rA);
#pragma unroll
  for (int h = 0; h < NH; ++h) {
    if (h < 6)
      mo2.v = *(const float4*)(motif + ((size_t)(h + 2) * NN + j0 + cA) * NN + i0 + rA);
    float w8[NH];
#pragma unroll
    for (int h2 = 0; h2 < NH; ++h2) w8[h2] = sW[h2 * NH + h];
    const float gkj = gkL[cA][h];
#pragma unroll
    for (int reg = 0; reg < 4; ++reg) {
      float tv = okm[reg] ? accT[h][reg] * SCALEF : NEGF;
      float hm = 0.f;
#pragma unroll
      for (int h2 = 0; h2 < NH; ++h2) hm = fmaf(accS[h2][reg], w8[h2], hm);
      float o = accS[h][reg] * (1.f + gqL[rA + reg][h] + gkj) +
                alpha * tv + beta * moc.f[reg] + hm;
      oL[rA + reg][cA] = o;
    }
    __syncthreads();
    float4 ov = *(const float4*)&oL[orow][oslot];
    *(float4*)(ATTN + ((size_t)h * NN + i0 + orow) * NN + j0 + oslot) = ov;
    if (h < 7) __syncthreads();
    moc.v = mon.v;
    mon.v = mo2.v;
  }
}

// ---------------- P@V: 16-row strips x 4 j-quarter waves, barrier-free loop --------
// probs = exp(x-16)/rowsum. 1024 blocks (4/CU, 16 waves/CU). Each wave owns a
// 512-col j-quarter: A from ATTN, B fragments DIRECT from L2-resident Vt (no LDS
// staging, no loop barriers). Cross-wave acc+rowsum combine once at the end.
__global__ __launch_bounds__(256) void k_pv(const float* __restrict__ ATTN,
                                            const short* __restrict__ Vt,
                                            short* __restrict__ Obf) {
  const int bid = blockIdx.x;      // 0..1023
  const int h = bid & 7;           // head -> XCD (V stays L2-resident)
  const int i0 = (bid >> 3) * 16;  // 128 strips
  const int tid = threadIdx.x, lane = tid & 63, wave = tid >> 6;
  const int ln = lane & 15, quad = lane >> 4, q8 = quad * 8;
  __shared__ float accL[4][16][140];
  __shared__ float SUML[4][16];
  const int jbase = wave * 512;
  const float* arow = ATTN + ((size_t)h * NN + i0 + ln) * NN + jbase;
  const short* vbase = Vt + (size_t)h * (HD * NN) + jbase;
  f32x4 acc[8];
#pragma unroll
  for (int nt = 0; nt < 8; ++nt) acc[nt] = (f32x4){0.f, 0.f, 0.f, 0.f};
  float rowsum = 0.f;
  for (int c = 0; c < 16; ++c) {
    const int jk = c * 32;
    float4 u1 = *(const float4*)(arow + jk + q8);
    float4 u2 = *(const float4*)(arow + jk + q8 + 4);
    float p0 = __expf(u1.x - EXPSHIFT), p1 = __expf(u1.y - EXPSHIFT);
    float p2 = __expf(u1.z - EXPSHIFT), p3 = __expf(u1.w - EXPSHIFT);
    float p4 = __expf(u2.x - EXPSHIFT), p5 = __expf(u2.y - EXPSHIFT);
    float p6 = __expf(u2.z - EXPSHIFT), p7 = __expf(u2.w - EXPSHIFT);
    rowsum += ((p0 + p1) + (p2 + p3)) + ((p4 + p5) + (p6 + p7));
    bf16x8 a;
    a[0] = f2bf(p0); a[1] = f2bf(p1); a[2] = f2bf(p2); a[3] = f2bf(p3);
    a[4] = f2bf(p4); a[5] = f2bf(p5); a[6] = f2bf(p6); a[7] = f2bf(p7);
#pragma unroll
    for (int nt = 0; nt < 8; ++nt) {
      bf16x8 b = *(const bf16x8*)(vbase + (size_t)(16 * nt + ln) * NN + jk + q8);
      acc[nt] = __builtin_amdgcn_mfma_f32_16x16x32_bf16(a, b, acc[nt], 0, 0, 0);
    }
  }
  // per-lane rowsum is a partial for row (i0+ln) over this wave's quarter
  rowsum += __shfl_xor(rowsum, 16);
  rowsum += __shfl_xor(rowsum, 32);
  if (lane < 16) SUML[wave][ln] = rowsum;
#pragma unroll
  for (int nt = 0; nt < 8; ++nt)
#pragma unroll
    for (int reg = 0; reg < 4; ++reg)
      accL[wave][quad * 4 + reg][16 * nt + ln] = acc[nt][reg];
  __syncthreads();
  // combine 4 wave-partials, normalize, write bf16 (coalesced 256B/row)
  const int r = tid >> 4, d0 = (tid & 15) * 8;
  const float inv = 1.0f / (SUML[0][r] + SUML[1][r] + SUML[2][r] + SUML[3][r]);
  union { short s[8]; bf16x8 v; } ob;
#pragma unroll
  for (int e = 0; e < 8; ++e) {
    float s = accL[0][r][d0 + e] + accL[1][r][d0 + e] +
              accL[2][r][d0 + e] + accL[3][r][d0 + e];
    ob.s[e] = f2bf(s * inv);
  }
  *(bf16x8*)(Obf + (size_t)(i0 + r) * DOUT + h * HD + d0) = ob.v;
}

// ---------------- out-proj bf16 MFMA GEMM: Y = Obf @ wo (K=1024 in-block) --------
__global__ __launch_bounds__(256) void k_outproj(const short* __restrict__ Obf,
                                                 const short* __restrict__ wot,
                                                 float* __restrict__ YACC) {
  const int n0 = blockIdx.x * 128;  // 768 cols -> 6
  const int i0 = blockIdx.y * 64;   // 2048 rows -> 32
  const int tid = threadIdx.x, lane = tid & 63, wave = tid >> 6;
  const int ln = lane & 15, quad = lane >> 4, q8 = quad * 8;
  f32x4 acc[8];
#pragma unroll
  for (int nt = 0; nt < 8; ++nt) acc[nt] = (f32x4){0.f, 0.f, 0.f, 0.f};
  const short* a0 = Obf + (size_t)(i0 + 16 * wave + ln) * DOUT + q8;
  const short* bp = wot + (size_t)(n0 + ln) * DOUT + q8;
  for (int ks = 0; ks < 32; ++ks) {
    bf16x8 A0 = *(const bf16x8*)(a0 + 32 * ks);
#pragma unroll
    for (int nt = 0; nt < 8; ++nt) {
      bf16x8 B = *(const bf16x8*)(bp + (size_t)nt * (16 * DOUT) + 32 * ks);
      acc[nt] = __builtin_amdgcn_mfma_f32_16x16x32_bf16(A0, B, acc[nt], 0, 0, 0);
    }
  }
#pragma unroll
  for (int nt = 0; nt < 8; ++nt) {
    int cg = n0 + 16 * nt + ln;
#pragma unroll
    for (int reg = 0; reg < 4; ++reg) {
      int rr = i0 + 16 * wave + quad * 4 + reg;
      YACC[(size_t)rr * DIN + cg] = acc[nt][reg];
    }
  }
}

// ---------------- bias + residual + LayerNorm ----------------
__global__ __launch_bounds__(256) void k_ln(const float* __restrict__ YACC,
                                            const float* __restrict__ x,
                                            const float* __restrict__ wo_b,
                                            const float* __restrict__ g,
                                            const float* __restrict__ b,
                                            float* __restrict__ y) {
  const int i = blockIdx.x;
  const int tid = threadIdx.x;
  float v[3];
#pragma unroll
  for (int t = 0; t < 3; ++t) {
    int cc = tid + t * 256;
    v[t] = YACC[(size_t)i * DIN + cc] + wo_b[cc] + x[(size_t)i * DIN + cc];
  }
  __shared__ float red[256];
  red[tid] = v[0] + v[1] + v[2];
  __syncthreads();
  for (int s = 128; s > 0; s >>= 1) {
    if (tid < s) red[tid] += red[tid + s];
    __syncthreads();
  }
  const float mu = red[0] * (1.0f / DIN);
  __syncthreads();
  float q = 0.f;
#pragma unroll
  for (int t = 0; t < 3; ++t) {
    float d = v[t] - mu;
    q += d * d;
  }
  red[tid] = q;
  __syncthreads();
  for (int s = 128; s > 0; s >>= 1) {
    if (tid < s) red[tid] += red[tid + s];
    __syncthreads();
  }
  const float rs = rsqrtf(red[0] * (1.0f / DIN) + EPSF);
#pragma unroll
  for (int t = 0; t < 3; ++t) {
    int cc = tid + t * 256;
    y[(size_t)i * DIN + cc] = (v[t] - mu) * rs * g[cc] + b[cc];
  }
}

extern "C" void kernel_launch(void* const* d_in, const int* in_sizes, int n_in,
                              void* d_out, int out_size, void* d_ws, size_t ws_size,
                              hipStream_t stream) {
  (void)in_sizes; (void)n_in; (void)out_size; (void)ws_size;
  const float* x       = (const float*)d_in[0];
  const int*   batch   = (const int*)d_in[1];
  const float* motif   = (const float*)d_in[2];
  const float* wq_w    = (const float*)d_in[3];
  const float* wq_b    = (const float*)d_in[4];
  const float* wk_w    = (const float*)d_in[5];
  const float* wk_b    = (const float*)d_in[6];
  const float* wv_w    = (const float*)d_in[7];
  const float* wv_b    = (const float*)d_in[8];
  const float* wo_w    = (const float*)d_in[9];
  const float* wo_b    = (const float*)d_in[10];
  const float* ln_g    = (const float*)d_in[11];
  const float* ln_b    = (const float*)d_in[12];
  const float* alpha_p = (const float*)d_in[13];
  const float* beta_p  = (const float*)d_in[14];
  const float* gq_w    = (const float*)d_in[15];
  const float* gq_b    = (const float*)d_in[16];
  const float* gk_w    = (const float*)d_in[17];
  const float* gk_b    = (const float*)d_in[18];
  const float* headW   = (const float*)d_in[19];

  float* y    = (float*)d_out;
  float* ATTN = (float*)d_out + (size_t)NN * DIN;
  float* ws   = (float*)d_ws;
  short* Obf  = (short*)(ws + OFF_OBF);
  short* wot  = (short*)(ws + OFF_WOT);
  float* YACC = ws + OFF_YACC;
  short* Qb   = (short*)(ws + OFF_Q);
  short* Kb   = (short*)(ws + OFF_K);
  short* Vb   = (short*)(ws + OFF_VB);
  short* Vt   = (short*)(ws + OFF_VT);
  short* xb   = (short*)(ws + OFF_XB);
  short* Wt   = (short*)(ws + OFF_WT);
  float* GQ   = ws + OFF_GQ;
  float* GK   = ws + OFF_GK;

  k_prep<<<2304, 256, 0, stream>>>(x, xb, wq_w, wk_w, wv_w, Wt, wo_w, wot);
  k_qkv<<<dim3(24, 16), 256, 0, stream>>>(xb, Wt, wq_b, wk_b, wv_b, Qb, Kb, Vb);
  k_vtg<<<2304, 256, 0, stream>>>(Qb, Kb, gq_w, gq_b, gk_w, gk_b, GQ, GK, Vb, Vt);
  k_sa<<<dim3(64, 64), 256, 0, stream>>>(Qb, Kb, batch, motif, GQ, GK, headW,
                                         alpha_p, beta_p, ATTN);
  k_pv<<<1024, 256, 0, stream>>>(ATTN, Vt, Obf);
  k_outproj<<<dim3(6, 32), 256, 0, stream>>>(Obf, wot, YACC);
  k_ln<<<NN, 256, 0, stream>>>(YACC, x, wo_b, ln_g, ln_b, y);
}

// Round 7
// 454.478 us; speedup vs baseline: 1.9691x; 1.2160x over previous
//
#include <hip/hip_runtime.h>

#define NN    2048
#define DIN   768
#define DOUT  1024
#define NH    8
#define HD    128
#define SCALEF 0.08838834764831845f
#define NEGF  (-1.0e9f)
#define EPSF  1e-5f
#define EXPSHIFT 16.0f

typedef __attribute__((ext_vector_type(4))) float f32x4;
typedef __attribute__((ext_vector_type(8))) short bf16x8;

// workspace layout (float-slot offsets)
#define OFF_OBF  0                         // bf16 O [2048][1024]
#define OFF_WOT  1048576                   // bf16 wo^T [768][1024]
#define OFF_YACC 1441792                   // f32 [2048][768]
#define OFF_Q    3686400                   // bf16 [8][2048][128]
#define OFF_K    4734976
#define OFF_VB   5783552                   // bf16 [2048][1024]
#define OFF_VT   6832128                   // bf16 [8][128][2048]
#define OFF_XB   7880704                   // bf16 [2048][768]
#define OFF_WT   8667136                   // bf16 [3][1024][768]
#define OFF_GQ   9846784
#define OFF_GK   9863168

__device__ __forceinline__ short f2bf(float f) {
  union { float f; unsigned u; } v; v.f = f;
  unsigned r = v.u + 0x7FFF + ((v.u >> 16) & 1);
  return (short)(r >> 16);
}
__device__ __forceinline__ float bf2f(short s) {
  union { unsigned u; float f; } v; v.u = ((unsigned)(unsigned short)s) << 16;
  return v.f;
}

// ---------------- fused preprocessing: cast_x | w_cast_t | wo_t ----------------
__global__ __launch_bounds__(256) void k_prep(const float* __restrict__ x,
                                              short* __restrict__ xb,
                                              const float* __restrict__ wq,
                                              const float* __restrict__ wk,
                                              const float* __restrict__ wv,
                                              short* __restrict__ Wt,
                                              const float* __restrict__ wo,
                                              short* __restrict__ wot) {
  const int bid = blockIdx.x;
  const int tid = threadIdx.x;
  if (bid < 1536) {  // cast x -> bf16
    int idx = bid * 256 + tid;
    float4 v = ((const float4*)x)[idx];
    union { short s[4]; float2 f; } u;
    u.s[0] = f2bf(v.x); u.s[1] = f2bf(v.y); u.s[2] = f2bf(v.z); u.s[3] = f2bf(v.w);
    ((float2*)xb)[idx] = u.f;
    return;
  }
  __shared__ float t[64][65];
  if (bid < 2112) {  // W[768][1024] -> Wt[z][1024][768] bf16
    const int w = bid - 1536;
    const int z = w / 192, rem = w % 192;
    const int c0 = (rem % 16) * 64, k0 = (rem / 16) * 64;
    const float* Wm = (z == 0) ? wq : (z == 1) ? wk : wv;
#pragma unroll
    for (int l = 0; l < 4; ++l) {
      int f = tid + l * 256;
      int r = f >> 4, c4 = (f & 15) * 4;
      *(float4*)&t[r][c4] = *(const float4*)(Wm + (size_t)(k0 + r) * DOUT + c0 + c4);
    }
    __syncthreads();
    int r2 = tid >> 2, q = tid & 3;
    union { short s[16]; float4 f[2]; } buf;
#pragma unroll
    for (int jj = 0; jj < 16; ++jj) buf.s[jj] = f2bf(t[q * 16 + jj][r2]);
    short* dst = Wt + (size_t)z * (1024 * 768) + (size_t)(c0 + r2) * 768 + k0 + q * 16;
    ((float4*)dst)[0] = buf.f[0];
    ((float4*)dst)[1] = buf.f[1];
  } else {  // wo[1024][768] -> wot[768][1024] bf16
    const int w = bid - 2112;
    const int c0 = (w % 12) * 64, k0 = (w / 12) * 64;
#pragma unroll
    for (int l = 0; l < 4; ++l) {
      int f = tid + l * 256;
      int r = f >> 4, c4 = (f & 15) * 4;
      *(float4*)&t[r][c4] = *(const float4*)(wo + (size_t)(k0 + r) * DIN + c0 + c4);
    }
    __syncthreads();
    int r2 = tid >> 2, q = tid & 3;
    union { short s[16]; float4 f[2]; } buf;
#pragma unroll
    for (int jj = 0; jj < 16; ++jj) buf.s[jj] = f2bf(t[q * 16 + jj][r2]);
    short* dst = wot + (size_t)(c0 + r2) * DOUT + k0 + q * 16;
    ((float4*)dst)[0] = buf.f[0];
    ((float4*)dst)[1] = buf.f[1];
  }
}

// ---------------- QKV projection: 64x128 tiles, LDS-staged B panel ----------------
__global__ __launch_bounds__(256) void k_qkv(const short* __restrict__ xb,
                                             const short* __restrict__ Wt,
                                             const float* __restrict__ bq,
                                             const float* __restrict__ bk,
                                             const float* __restrict__ bv,
                                             short* __restrict__ Qb,
                                             short* __restrict__ Kb,
                                             short* __restrict__ Vb) {
  const int n0 = blockIdx.x * 128;  // 0..2944 over 3072
  const int i0 = blockIdx.y * 64;   // 0..1984
  const int mat = n0 >> 10;
  const int cl = n0 & 1023;
  const float* bias = (mat == 0) ? bq : (mat == 1) ? bk : bv;
  const short* Wm = Wt + (size_t)mat * (1024 * 768);
  const int tid = threadIdx.x, lane = tid & 63, wave = tid >> 6;
  const int ln = lane & 15, quad = lane >> 4, q8 = quad * 8;
  __shared__ __align__(16) short Bs[2][128][56];  // stride 112B: 16B-aligned, 2-way max
  // staging geometry: thread -> (row, 16-short half)
  const int brow = tid >> 1, bseg = (tid & 1) * 16;
  const short* gB = Wm + (size_t)(cl + brow) * DIN + bseg;
  // prologue: stage ks=0, preload ks=1 to regs
  {
    bf16x8 b0 = *(const bf16x8*)(gB);
    bf16x8 b1 = *(const bf16x8*)(gB + 8);
    *(bf16x8*)&Bs[0][brow][bseg] = b0;
    *(bf16x8*)&Bs[0][brow][bseg + 8] = b1;
  }
  bf16x8 cb0 = *(const bf16x8*)(gB + 32);
  bf16x8 cb1 = *(const bf16x8*)(gB + 40);
  __syncthreads();
  f32x4 acc[8];
#pragma unroll
  for (int nt = 0; nt < 8; ++nt) acc[nt] = (f32x4){0.f, 0.f, 0.f, 0.f};
  const short* a0 = xb + (size_t)(i0 + 16 * wave + ln) * DIN + q8;
  for (int ks = 0; ks < 24; ++ks) {
    const int bufc = ks & 1;
    bf16x8 nb0, nb1;
    if (ks < 22) {
      nb0 = *(const bf16x8*)(gB + 32 * (ks + 2));
      nb1 = *(const bf16x8*)(gB + 32 * (ks + 2) + 8);
    }
    bf16x8 A0 = *(const bf16x8*)(a0 + 32 * ks);
#pragma unroll
    for (int nt = 0; nt < 8; ++nt) {
      bf16x8 B = *(const bf16x8*)&Bs[bufc][16 * nt + ln][q8];
      acc[nt] = __builtin_amdgcn_mfma_f32_16x16x32_bf16(A0, B, acc[nt], 0, 0, 0);
    }
    if (ks < 23) {
      *(bf16x8*)&Bs[bufc ^ 1][brow][bseg] = cb0;
      *(bf16x8*)&Bs[bufc ^ 1][brow][bseg + 8] = cb1;
    }
    __syncthreads();
    if (ks < 22) { cb0 = nb0; cb1 = nb1; }
  }
#pragma unroll
  for (int nt = 0; nt < 8; ++nt) {
    int cg = cl + 16 * nt + ln;
    float bb = bias[cg];
#pragma unroll
    for (int reg = 0; reg < 4; ++reg) {
      int rr = i0 + 16 * wave + quad * 4 + reg;
      short s = f2bf(acc[nt][reg] + bb);
      if (mat == 2) {
        Vb[(size_t)rr * 1024 + cg] = s;
      } else {
        int h = cg >> 7, d = cg & 127;
        (mat == 0 ? Qb : Kb)[((size_t)h * NN + rr) * HD + d] = s;
      }
    }
  }
}

// ---------------- fused: gates (bid<2048, shuffle-reduce) | Vb->Vt (bid>=2048) ------
__global__ __launch_bounds__(256) void k_vtg(const short* __restrict__ Qb,
                                             const short* __restrict__ Kb,
                                             const float* __restrict__ gqw,
                                             const float* __restrict__ gqb,
                                             const float* __restrict__ gkw,
                                             const float* __restrict__ gkb,
                                             float* __restrict__ GQ,
                                             float* __restrict__ GK,
                                             const short* __restrict__ Vb,
                                             short* __restrict__ Vt) {
  const int bid = blockIdx.x;
  const int tid = threadIdx.x;
  __shared__ __align__(16) char smem[17408];
  if (bid < 2048) {  // gates
    const int i = bid;
    const int lane = tid & 63, wave = tid >> 6;
    float aq[NH] = {}, ak[NH] = {};
    for (int d = tid; d < DOUT; d += 256) {
      int h = d >> 7, dd = d & 127;
      float qv = bf2f(Qb[((size_t)h * NN + i) * HD + dd]);
      float kv = bf2f(Kb[((size_t)h * NN + i) * HD + dd]);
      float4 ga = *(const float4*)(gqw + (size_t)d * NH);
      float4 gb = *(const float4*)(gqw + (size_t)d * NH + 4);
      float4 ha = *(const float4*)(gkw + (size_t)d * NH);
      float4 hb = *(const float4*)(gkw + (size_t)d * NH + 4);
      aq[0] = fmaf(qv, ga.x, aq[0]); aq[1] = fmaf(qv, ga.y, aq[1]);
      aq[2] = fmaf(qv, ga.z, aq[2]); aq[3] = fmaf(qv, ga.w, aq[3]);
      aq[4] = fmaf(qv, gb.x, aq[4]); aq[5] = fmaf(qv, gb.y, aq[5]);
      aq[6] = fmaf(qv, gb.z, aq[6]); aq[7] = fmaf(qv, gb.w, aq[7]);
      ak[0] = fmaf(kv, ha.x, ak[0]); ak[1] = fmaf(kv, ha.y, ak[1]);
      ak[2] = fmaf(kv, ha.z, ak[2]); ak[3] = fmaf(kv, ha.w, ak[3]);
      ak[4] = fmaf(kv, hb.x, ak[4]); ak[5] = fmaf(kv, hb.y, ak[5]);
      ak[6] = fmaf(kv, hb.z, ak[6]); ak[7] = fmaf(kv, hb.w, ak[7]);
    }
#pragma unroll
    for (int h = 0; h < NH; ++h) {
#pragma unroll
      for (int off = 1; off < 64; off <<= 1) {
        aq[h] += __shfl_xor(aq[h], off);
        ak[h] += __shfl_xor(ak[h], off);
      }
    }
    auto part = (float (*)[16])(smem);  // [4][16]
    if (lane == 0) {
#pragma unroll
      for (int h = 0; h < NH; ++h) {
        part[wave][h] = aq[h];
        part[wave][8 + h] = ak[h];
      }
    }
    __syncthreads();
    if (tid < 16) {
      float s = part[0][tid] + part[1][tid] + part[2][tid] + part[3][tid];
      if (tid < 8) GQ[(size_t)i * NH + tid] = tanhf(s + gqb[tid]);
      else GK[(size_t)i * NH + tid - 8] = tanhf(s + gkb[tid - 8]);
    }
  } else {  // Vb -> Vt[h][d][n]
    auto t = (short (*)[136])(smem);  // [64][136]
    const int w = bid - 2048;
    const int i0 = (w & 31) * 64, h = w >> 5;
#pragma unroll
    for (int l = 0; l < 2; ++l) {
      int f = tid + l * 256;
      int r = f >> 3, c8 = (f & 7) * 16;
      const short* src = Vb + (size_t)(i0 + r) * 1024 + h * HD + c8;
      *(bf16x8*)&t[r][c8] = *(const bf16x8*)src;
      *(bf16x8*)&t[r][c8 + 8] = *(const bf16x8*)(src + 8);
    }
    __syncthreads();
    int d = tid >> 1, half = tid & 1;
    union { short s[32]; float4 f[4]; } buf;
#pragma unroll
    for (int ii = 0; ii < 32; ++ii) buf.s[ii] = t[32 * half + ii][d];
    short* dst = Vt + (size_t)h * (HD * NN) + (size_t)d * NN + i0 + 32 * half;
#pragma unroll
    for (int q = 0; q < 4; ++q) ((float4*)dst)[q] = buf.f[q];
  }
}

// ---------------- fused scores + assemble (2-head-ahead LDS pipeline) ----------------
__global__ __launch_bounds__(256, 4) void k_sa(const short* __restrict__ Qb,
                                               const short* __restrict__ Kb,
                                               const int* __restrict__ batch,
                                               const float* __restrict__ motif,
                                               const float* __restrict__ GQ,
                                               const float* __restrict__ GK,
                                               const float* __restrict__ Wh,
                                               const float* __restrict__ alpha_p,
                                               const float* __restrict__ beta_p,
                                               float* __restrict__ ATTN) {
  // XCD patch swizzle: 16x16 block patches per XCD
  const unsigned gid = blockIdx.y * gridDim.x + blockIdx.x;
  const unsigned xcd = gid & 7, idx = gid >> 3;
  const unsigned P = xcd + 8 * (idx >> 8);
  const unsigned r256 = idx & 255;
  const unsigned bx = 16 * (P & 3) + (r256 & 15);
  const unsigned by = 16 * (P >> 2) + (r256 >> 4);
  const int i0 = by * 32, j0 = bx * 32;

  const int tid = threadIdx.x, lane = tid & 63, wave = tid >> 6;
  const int wr = wave >> 1, wc = wave & 1;
  const int ln = lane & 15, quad = lane >> 4, q8 = quad * 8;

  __shared__ __align__(16) char smem[38400];
  auto Qs  = (short (*)[32][136])(smem);            // [2][32][136] bf16
  auto Ks  = (short (*)[32][136])(smem + 17408);    // [2][32][136] bf16
  auto oL  = (float (*)[36])(smem);                 // [32][36] f32 (aliases Qs)
  auto gqL = (float (*)[12])(smem + 34816);         // [32][12]
  auto gkL = (float (*)[12])(smem + 36352);         // [32][12]
  float* sW = (float*)(smem + 37888);               // [64]

  const int rA = 16 * wr + quad * 4;
  const int cA = 16 * wc + ln;

  const int srow = tid >> 3, sseg = (tid & 7) * 16;
  const short* gQ0 = Qb + (size_t)(i0 + srow) * HD + sseg;
  const short* gK0 = Kb + (size_t)(j0 + srow) * HD + sseg;
  const size_t hstep = (size_t)NN * HD;

  // prologue: stage head0 to LDS, preload head1 into regs (stays in flight 1 iter)
  {
    bf16x8 q0 = *(const bf16x8*)(gQ0);
    bf16x8 q1 = *(const bf16x8*)(gQ0 + 8);
    bf16x8 k0 = *(const bf16x8*)(gK0);
    bf16x8 k1 = *(const bf16x8*)(gK0 + 8);
    *(bf16x8*)&Qs[0][srow][sseg] = q0;
    *(bf16x8*)&Qs[0][srow][sseg + 8] = q1;
    *(bf16x8*)&Ks[0][srow][sseg] = k0;
    *(bf16x8*)&Ks[0][srow][sseg + 8] = k1;
  }
  bf16x8 cq0 = *(const bf16x8*)(gQ0 + hstep);
  bf16x8 cq1 = *(const bf16x8*)(gQ0 + hstep + 8);
  bf16x8 ck0 = *(const bf16x8*)(gK0 + hstep);
  bf16x8 ck1 = *(const bf16x8*)(gK0 + hstep + 8);
  if (tid < 64) {
    const int half = tid >> 5, r = tid & 31;
    const float* src = (half ? GK : GQ) + (size_t)((half ? j0 : i0) + r) * NH;
    float4 a = *(const float4*)src;
    float4 b = *(const float4*)(src + 4);
    float* dst = half ? &gkL[r][0] : &gqL[r][0];
    *(float4*)dst = a;
    *(float4*)(dst + 4) = b;
    sW[tid] = Wh[tid];
  }
  const int4 bi4 = *(const int4*)(batch + i0 + rA);
  const int bj = batch[j0 + cA];
  const float alpha = alpha_p[0], beta = beta_p[0];
  __syncthreads();

  f32x4 accS[NH], accT[NH];
#pragma unroll
  for (int h = 0; h < NH; ++h) {
    accS[h] = (f32x4){0.f, 0.f, 0.f, 0.f};
    accT[h] = (f32x4){0.f, 0.f, 0.f, 0.f};
  }

#pragma unroll
  for (int h = 0; h < NH; ++h) {
    const int bufc = h & 1;
    bf16x8 nq0, nq1, nk0, nk1;
    if (h < 6) {  // issue head h+2's loads (in flight for ~1 full iteration)
      const short* gq_ = gQ0 + (size_t)(h + 2) * hstep;
      const short* gk_ = gK0 + (size_t)(h + 2) * hstep;
      nq0 = *(const bf16x8*)(gq_);
      nq1 = *(const bf16x8*)(gq_ + 8);
      nk0 = *(const bf16x8*)(gk_);
      nk1 = *(const bf16x8*)(gk_ + 8);
    }
#pragma unroll
    for (int ks = 0; ks < 4; ++ks) {
      bf16x8 aS = *(const bf16x8*)&Qs[bufc][16 * wr + ln][ks * 32 + q8];
      bf16x8 bS = *(const bf16x8*)&Ks[bufc][16 * wc + ln][ks * 32 + q8];
      accS[h] = __builtin_amdgcn_mfma_f32_16x16x32_bf16(aS, bS, accS[h], 0, 0, 0);
      bf16x8 aT = *(const bf16x8*)&Ks[bufc][16 * wr + ln][ks * 32 + q8];
      bf16x8 bT = *(const bf16x8*)&Qs[bufc][16 * wc + ln][ks * 32 + q8];
      accT[h] = __builtin_amdgcn_mfma_f32_16x16x32_bf16(aT, bT, accT[h], 0, 0, 0);
    }
    if (h < 7) {  // commit head h+1 (loaded last iteration) to the other buffer
      *(bf16x8*)&Qs[bufc ^ 1][srow][sseg] = cq0;
      *(bf16x8*)&Qs[bufc ^ 1][srow][sseg + 8] = cq1;
      *(bf16x8*)&Ks[bufc ^ 1][srow][sseg] = ck0;
      *(bf16x8*)&Ks[bufc ^ 1][srow][sseg + 8] = ck1;
    }
    __syncthreads();
    if (h < 6) { cq0 = nq0; cq1 = nq1; ck0 = nk0; ck1 = nk1; }
  }

  // mask + scale S
  int okm[4];
  okm[0] = (bi4.x == bj); okm[1] = (bi4.y == bj);
  okm[2] = (bi4.z == bj); okm[3] = (bi4.w == bj);
#pragma unroll
  for (int reg = 0; reg < 4; ++reg)
#pragma unroll
    for (int h = 0; h < NH; ++h)
      accS[h][reg] = okm[reg] ? accS[h][reg] * SCALEF : NEGF;

  // per-head epilogue: motif 2-ahead reg pipeline, LDS transpose, full-line stores
  const int orow = tid >> 3, oslot = (tid & 7) * 4;
  union { float4 v; float f[4]; } moc, mon, mo2;
  moc.v = *(const float4*)(motif + ((size_t)(j0 + cA)) * NN + i0 + rA);
  mon.v = *(const float4*)(motif + ((size_t)(NN + j0 + cA)) * NN + i0 + rA);
#pragma unroll
  for (int h = 0; h < NH; ++h) {
    if (h < 6)
      mo2.v = *(const float4*)(motif + ((size_t)(h + 2) * NN + j0 + cA) * NN + i0 + rA);
    float w8[NH];
#pragma unroll
    for (int h2 = 0; h2 < NH; ++h2) w8[h2] = sW[h2 * NH + h];
    const float gkj = gkL[cA][h];
#pragma unroll
    for (int reg = 0; reg < 4; ++reg) {
      float tv = okm[reg] ? accT[h][reg] * SCALEF : NEGF;
      float hm = 0.f;
#pragma unroll
      for (int h2 = 0; h2 < NH; ++h2) hm = fmaf(accS[h2][reg], w8[h2], hm);
      float o = accS[h][reg] * (1.f + gqL[rA + reg][h] + gkj) +
                alpha * tv + beta * moc.f[reg] + hm;
      oL[rA + reg][cA] = o;
    }
    __syncthreads();
    float4 ov = *(const float4*)&oL[orow][oslot];
    *(float4*)(ATTN + ((size_t)h * NN + i0 + orow) * NN + j0 + oslot) = ov;
    if (h < 7) __syncthreads();
    moc.v = mon.v;
    mon.v = mo2.v;
  }
}

// ---------------- P@V: 16-row strips x 4 j-quarter waves, barrier-free loop --------
__global__ __launch_bounds__(256) void k_pv(const float* __restrict__ ATTN,
                                            const short* __restrict__ Vt,
                                            short* __restrict__ Obf) {
  const int bid = blockIdx.x;      // 0..1023
  const int h = bid & 7;           // head -> XCD (V stays L2-resident)
  const int i0 = (bid >> 3) * 16;  // 128 strips
  const int tid = threadIdx.x, lane = tid & 63, wave = tid >> 6;
  const int ln = lane & 15, quad = lane >> 4, q8 = quad * 8;
  __shared__ float accL[4][16][140];
  __shared__ float SUML[4][16];
  const int jbase = wave * 512;
  const float* arow = ATTN + ((size_t)h * NN + i0 + ln) * NN + jbase;
  const short* vbase = Vt + (size_t)h * (HD * NN) + jbase;
  f32x4 acc[8];
#pragma unroll
  for (int nt = 0; nt < 8; ++nt) acc[nt] = (f32x4){0.f, 0.f, 0.f, 0.f};
  float rowsum = 0.f;
  for (int c = 0; c < 16; ++c) {
    const int jk = c * 32;
    float4 u1 = *(const float4*)(arow + jk + q8);
    float4 u2 = *(const float4*)(arow + jk + q8 + 4);
    float p0 = __expf(u1.x - EXPSHIFT), p1 = __expf(u1.y - EXPSHIFT);
    float p2 = __expf(u1.z - EXPSHIFT), p3 = __expf(u1.w - EXPSHIFT);
    float p4 = __expf(u2.x - EXPSHIFT), p5 = __expf(u2.y - EXPSHIFT);
    float p6 = __expf(u2.z - EXPSHIFT), p7 = __expf(u2.w - EXPSHIFT);
    rowsum += ((p0 + p1) + (p2 + p3)) + ((p4 + p5) + (p6 + p7));
    bf16x8 a;
    a[0] = f2bf(p0); a[1] = f2bf(p1); a[2] = f2bf(p2); a[3] = f2bf(p3);
    a[4] = f2bf(p4); a[5] = f2bf(p5); a[6] = f2bf(p6); a[7] = f2bf(p7);
#pragma unroll
    for (int nt = 0; nt < 8; ++nt) {
      bf16x8 b = *(const bf16x8*)(vbase + (size_t)(16 * nt + ln) * NN + jk + q8);
      acc[nt] = __builtin_amdgcn_mfma_f32_16x16x32_bf16(a, b, acc[nt], 0, 0, 0);
    }
  }
  rowsum += __shfl_xor(rowsum, 16);
  rowsum += __shfl_xor(rowsum, 32);
  if (lane < 16) SUML[wave][ln] = rowsum;
#pragma unroll
  for (int nt = 0; nt < 8; ++nt)
#pragma unroll
    for (int reg = 0; reg < 4; ++reg)
      accL[wave][quad * 4 + reg][16 * nt + ln] = acc[nt][reg];
  __syncthreads();
  const int r = tid >> 4, d0 = (tid & 15) * 8;
  const float inv = 1.0f / (SUML[0][r] + SUML[1][r] + SUML[2][r] + SUML[3][r]);
  union { short s[8]; bf16x8 v; } ob;
#pragma unroll
  for (int e = 0; e < 8; ++e) {
    float s = accL[0][r][d0 + e] + accL[1][r][d0 + e] +
              accL[2][r][d0 + e] + accL[3][r][d0 + e];
    ob.s[e] = f2bf(s * inv);
  }
  *(bf16x8*)(Obf + (size_t)(i0 + r) * DOUT + h * HD + d0) = ob.v;
}

// ---------------- out-proj: 64x64 tiles, LDS-staged B panel ----------------
__global__ __launch_bounds__(256) void k_outproj(const short* __restrict__ Obf,
                                                 const short* __restrict__ wot,
                                                 float* __restrict__ YACC) {
  const int n0 = blockIdx.x * 64;   // 768 cols -> 12
  const int i0 = blockIdx.y * 64;   // 2048 rows -> 32
  const int tid = threadIdx.x, lane = tid & 63, wave = tid >> 6;
  const int ln = lane & 15, quad = lane >> 4, q8 = quad * 8;
  __shared__ __align__(16) short Bs[2][64][56];
  const int brow = tid >> 2, bseg = (tid & 3) * 8;  // 64 rows x 4 segs of 16B
  const short* gB = wot + (size_t)(n0 + brow) * DOUT + bseg;
  {
    bf16x8 b0 = *(const bf16x8*)(gB);
    *(bf16x8*)&Bs[0][brow][bseg] = b0;
  }
  bf16x8 cb0 = *(const bf16x8*)(gB + 32);
  __syncthreads();
  f32x4 acc[4];
#pragma unroll
  for (int nt = 0; nt < 4; ++nt) acc[nt] = (f32x4){0.f, 0.f, 0.f, 0.f};
  const short* a0 = Obf + (size_t)(i0 + 16 * wave + ln) * DOUT + q8;
  for (int ks = 0; ks < 32; ++ks) {
    const int bufc = ks & 1;
    bf16x8 nb0;
    if (ks < 30) nb0 = *(const bf16x8*)(gB + 32 * (ks + 2));
    bf16x8 A0 = *(const bf16x8*)(a0 + 32 * ks);
#pragma unroll
    for (int nt = 0; nt < 4; ++nt) {
      bf16x8 B = *(const bf16x8*)&Bs[bufc][16 * nt + ln][q8];
      acc[nt] = __builtin_amdgcn_mfma_f32_16x16x32_bf16(A0, B, acc[nt], 0, 0, 0);
    }
    if (ks < 31) *(bf16x8*)&Bs[bufc ^ 1][brow][bseg] = cb0;
    __syncthreads();
    if (ks < 30) cb0 = nb0;
  }
#pragma unroll
  for (int nt = 0; nt < 4; ++nt) {
    int cg = n0 + 16 * nt + ln;
#pragma unroll
    for (int reg = 0; reg < 4; ++reg) {
      int rr = i0 + 16 * wave + quad * 4 + reg;
      YACC[(size_t)rr * DIN + cg] = acc[nt][reg];
    }
  }
}

// ---------------- bias + residual + LayerNorm (shuffle-reduce, 2 barriers) --------
__global__ __launch_bounds__(256) void k_ln(const float* __restrict__ YACC,
                                            const float* __restrict__ x,
                                            const float* __restrict__ wo_b,
                                            const float* __restrict__ g,
                                            const float* __restrict__ b,
                                            float* __restrict__ y) {
  const int i = blockIdx.x;
  const int tid = threadIdx.x;
  const int lane = tid & 63, wave = tid >> 6;
  float v[3];
#pragma unroll
  for (int t = 0; t < 3; ++t) {
    int cc = tid + t * 256;
    v[t] = YACC[(size_t)i * DIN + cc] + wo_b[cc] + x[(size_t)i * DIN + cc];
  }
  __shared__ float p1[4], p2[4];
  float s = v[0] + v[1] + v[2];
#pragma unroll
  for (int off = 1; off < 64; off <<= 1) s += __shfl_xor(s, off);
  if (lane == 0) p1[wave] = s;
  __syncthreads();
  const float mu = (p1[0] + p1[1] + p1[2] + p1[3]) * (1.0f / DIN);
  float q = 0.f;
#pragma unroll
  for (int t = 0; t < 3; ++t) {
    float d = v[t] - mu;
    q += d * d;
  }
#pragma unroll
  for (int off = 1; off < 64; off <<= 1) q += __shfl_xor(q, off);
  if (lane == 0) p2[wave] = q;
  __syncthreads();
  const float rs = rsqrtf((p2[0] + p2[1] + p2[2] + p2[3]) * (1.0f / DIN) + EPSF);
#pragma unroll
  for (int t = 0; t < 3; ++t) {
    int cc = tid + t * 256;
    y[(size_t)i * DIN + cc] = (v[t] - mu) * rs * g[cc] + b[cc];
  }
}

extern "C" void kernel_launch(void* const* d_in, const int* in_sizes, int n_in,
                              void* d_out, int out_size, void* d_ws, size_t ws_size,
                              hipStream_t stream) {
  (void)in_sizes; (void)n_in; (void)out_size; (void)ws_size;
  const float* x       = (const float*)d_in[0];
  const int*   batch   = (const int*)d_in[1];
  const float* motif   = (const float*)d_in[2];
  const float* wq_w    = (const float*)d_in[3];
  const float* wq_b    = (const float*)d_in[4];
  const float* wk_w    = (const float*)d_in[5];
  const float* wk_b    = (const float*)d_in[6];
  const float* wv_w    = (const float*)d_in[7];
  const float* wv_b    = (const float*)d_in[8];
  const float* wo_w    = (const float*)d_in[9];
  const float* wo_b    = (const float*)d_in[10];
  const float* ln_g    = (const float*)d_in[11];
  const float* ln_b    = (const float*)d_in[12];
  const float* alpha_p = (const float*)d_in[13];
  const float* beta_p  = (const float*)d_in[14];
  const float* gq_w    = (const float*)d_in[15];
  const float* gq_b    = (const float*)d_in[16];
  const float* gk_w    = (const float*)d_in[17];
  const float* gk_b    = (const float*)d_in[18];
  const float* headW   = (const float*)d_in[19];

  float* y    = (float*)d_out;
  float* ATTN = (float*)d_out + (size_t)NN * DIN;
  float* ws   = (float*)d_ws;
  short* Obf  = (short*)(ws + OFF_OBF);
  short* wot  = (short*)(ws + OFF_WOT);
  float* YACC = ws + OFF_YACC;
  short* Qb   = (short*)(ws + OFF_Q);
  short* Kb   = (short*)(ws + OFF_K);
  short* Vb   = (short*)(ws + OFF_VB);
  short* Vt   = (short*)(ws + OFF_VT);
  short* xb   = (short*)(ws + OFF_XB);
  short* Wt   = (short*)(ws + OFF_WT);
  float* GQ   = ws + OFF_GQ;
  float* GK   = ws + OFF_GK;

  k_prep<<<2304, 256, 0, stream>>>(x, xb, wq_w, wk_w, wv_w, Wt, wo_w, wot);
  k_qkv<<<dim3(24, 32), 256, 0, stream>>>(xb, Wt, wq_b, wk_b, wv_b, Qb, Kb, Vb);
  k_vtg<<<2304, 256, 0, stream>>>(Qb, Kb, gq_w, gq_b, gk_w, gk_b, GQ, GK, Vb, Vt);
  k_sa<<<dim3(64, 64), 256, 0, stream>>>(Qb, Kb, batch, motif, GQ, GK, headW,
                                         alpha_p, beta_p, ATTN);
  k_pv<<<1024, 256, 0, stream>>>(ATTN, Vt, Obf);
  k_outproj<<<dim3(12, 32), 256, 0, stream>>>(Obf, wot, YACC);
  k_ln<<<NN, 256, 0, stream>>>(YACC, x, wo_b, ln_g, ln_b, y);
}